// Round 13
// baseline (720.650 us; speedup 1.0000x reference)
//
#include <hip/hip_runtime.h>
#include <hip/hip_bf16.h>
#include <math.h>

// Problem constants
#define BB 4
#define LL 2048
#define DD 512
#define HH 8
#define NLAYER 4
#define VV 258
#define WW 8
#define HDIM 64
#define MM (BB * LL)   // 8192 rows
#define VPAD 384       // logits weight rows padded to tile multiple

// 0.125 * log2(e): QK^T scale, folded into Q at the qkv-GEMM epilogue
#define C8 0.18033688f

typedef __attribute__((ext_vector_type(8))) short short8v;
typedef __attribute__((ext_vector_type(4))) float float4v;

typedef __attribute__((address_space(3))) unsigned int lds_u32;
typedef const __attribute__((address_space(1))) unsigned int glb_u32;

__device__ __forceinline__ unsigned short f2bf(float x) {
    unsigned int u = __float_as_uint(x);
    unsigned int r = (u + 0x7fffu + ((u >> 16) & 1u)) >> 16;
    return (unsigned short)r;
}
__device__ __forceinline__ float bf2f(unsigned short u) {
    return __uint_as_float((unsigned)u << 16);
}

__device__ __forceinline__ unsigned lds_addr(const void* p) {
    return (unsigned)(size_t)(__attribute__((address_space(3))) const void*)p;
}

// ---------------------------------------------------------------------------
// Fused weight conversion: all four layer-weight arrays + padded out_w,
// one dispatch. Output regions are contiguous in ws: wq|wa|w1|w2|wob.
// ---------------------------------------------------------------------------
#define E0 (NLAYER * 3 * DD * DD)          // 3,145,728
#define E1 (E0 + NLAYER * DD * DD)         // 4,194,304
#define E2 (E1 + NLAYER * 4 * DD * DD)     // 8,388,608
#define E3 (E2 + NLAYER * 4 * DD * DD)     // 12,582,912
#define E4 (E3 + VPAD * DD)                // 12,779,520

__global__ __launch_bounds__(256)
void cvt_all_kernel(const float* __restrict__ qkv_w, const float* __restrict__ ao_w,
                    const float* __restrict__ ff1_w, const float* __restrict__ ff2_w,
                    const float* __restrict__ out_w, unsigned short* __restrict__ dst)
{
    int i = (blockIdx.x * 256 + threadIdx.x) * 4;
    float4 v;
    if (i < E0)      v = *reinterpret_cast<const float4*>(qkv_w + i);
    else if (i < E1) v = *reinterpret_cast<const float4*>(ao_w + (i - E0));
    else if (i < E2) v = *reinterpret_cast<const float4*>(ff1_w + (i - E1));
    else if (i < E3) v = *reinterpret_cast<const float4*>(ff2_w + (i - E2));
    else {
        int idx = i - E3;
        if ((idx >> 9) < VV) v = *reinterpret_cast<const float4*>(out_w + idx);
        else                 v = (float4){0.f, 0.f, 0.f, 0.f};
    }
    uint2 pk;
    pk.x = (unsigned)f2bf(v.x) | ((unsigned)f2bf(v.y) << 16);
    pk.y = (unsigned)f2bf(v.z) | ((unsigned)f2bf(v.w) << 16);
    *reinterpret_cast<uint2*>(dst + i) = pk;
}

// ---------------------------------------------------------------------------
// Kernel 1: fused token embedding + entropy feature + LN1(layer 0)
// One wave per row, 4 rows/block. Writes h (bf16 residual) and g (bf16 LN'd).
// Entropy: window x[b,l:l+8] for l <= L-W; values >= 256 contribute nothing.
// ---------------------------------------------------------------------------
__global__ __launch_bounds__(256)
void embed_ln_kernel(const int* __restrict__ x,
                     const float* __restrict__ emb,
                     const float* __restrict__ ent_w,
                     const float* __restrict__ ent_b,
                     const float* __restrict__ ln_s,
                     const float* __restrict__ ln_b,
                     unsigned short* __restrict__ h,
                     unsigned short* __restrict__ g)
{
    int w = threadIdx.x >> 6, lane = threadIdx.x & 63;
    int row = blockIdx.x * 4 + w;
    int b = row / LL, l = row % LL;

    float ent = 0.f;
    if (l <= LL - WW) {
        int win[WW];
        #pragma unroll
        for (int i = 0; i < WW; i++) win[i] = x[b * LL + l + i];
        float s = 0.f;
        #pragma unroll
        for (int i = 0; i < WW; i++) {
            if (win[i] < 256) {
                int c = 0;
                #pragma unroll
                for (int j = 0; j < WW; j++) c += (win[j] == win[i]) ? 1 : 0;
                s += log2f((float)c * 0.125f + 1e-10f);
            }
        }
        ent = -s * 0.125f;
    }

    int tok = x[row];
    const float* erow = emb + (size_t)tok * DD + lane * 8;
    float v[8], ew[8], eb[8];
    *reinterpret_cast<float4*>(v)      = *reinterpret_cast<const float4*>(erow);
    *reinterpret_cast<float4*>(v + 4)  = *reinterpret_cast<const float4*>(erow + 4);
    *reinterpret_cast<float4*>(ew)     = *reinterpret_cast<const float4*>(ent_w + lane * 8);
    *reinterpret_cast<float4*>(ew + 4) = *reinterpret_cast<const float4*>(ent_w + lane * 8 + 4);
    *reinterpret_cast<float4*>(eb)     = *reinterpret_cast<const float4*>(ent_b + lane * 8);
    *reinterpret_cast<float4*>(eb + 4) = *reinterpret_cast<const float4*>(ent_b + lane * 8 + 4);

    float sum = 0.f, sq = 0.f;
    #pragma unroll
    for (int i = 0; i < 8; i++) {
        v[i] = v[i] + ent * ew[i] + eb[i];
        sum += v[i]; sq += v[i] * v[i];
    }
    unsigned int hpk[4];
    #pragma unroll
    for (int i = 0; i < 4; i++)
        hpk[i] = (unsigned)f2bf(v[2*i]) | ((unsigned)f2bf(v[2*i+1]) << 16);
    *reinterpret_cast<uint4*>(h + (size_t)row * DD + lane * 8) =
        *reinterpret_cast<const uint4*>(hpk);

    #pragma unroll
    for (int off = 32; off > 0; off >>= 1) {
        sum += __shfl_xor(sum, off);
        sq  += __shfl_xor(sq, off);
    }
    float mu = sum * (1.f / DD);
    float var = sq * (1.f / DD) - mu * mu;
    float rstd = rsqrtf(var + 1e-5f);

    float s8[8], bi[8];
    *reinterpret_cast<float4*>(s8)     = *reinterpret_cast<const float4*>(ln_s + lane * 8);
    *reinterpret_cast<float4*>(s8 + 4) = *reinterpret_cast<const float4*>(ln_s + lane * 8 + 4);
    *reinterpret_cast<float4*>(bi)     = *reinterpret_cast<const float4*>(ln_b + lane * 8);
    *reinterpret_cast<float4*>(bi + 4) = *reinterpret_cast<const float4*>(ln_b + lane * 8 + 4);

    unsigned int pk[4];
    #pragma unroll
    for (int i = 0; i < 4; i++) {
        unsigned short lo = f2bf((v[2*i]   - mu) * rstd * s8[2*i]   + bi[2*i]);
        unsigned short hi = f2bf((v[2*i+1] - mu) * rstd * s8[2*i+1] + bi[2*i+1]);
        pk[i] = (unsigned)lo | ((unsigned)hi << 16);
    }
    *reinterpret_cast<uint4*>(g + (size_t)row * DD + lane * 8) =
        *reinterpret_cast<const uint4*>(pk);
}

// ---------------------------------------------------------------------------
// Kernel 2: LayerNorm (bf16 in, bf16 out). One wave per row, 4 rows/block.
// ---------------------------------------------------------------------------
__global__ __launch_bounds__(256)
void ln_kernel(const unsigned short* __restrict__ h,
               const float* __restrict__ scale,
               const float* __restrict__ bias,
               unsigned short* __restrict__ g)
{
    int w = threadIdx.x >> 6, lane = threadIdx.x & 63;
    int row = blockIdx.x * 4 + w;

    uint4 raw = *reinterpret_cast<const uint4*>(h + (size_t)row * DD + lane * 8);
    const unsigned* rw = reinterpret_cast<const unsigned*>(&raw);
    float v[8];
    #pragma unroll
    for (int i = 0; i < 4; i++) {
        v[2*i]   = __uint_as_float(rw[i] << 16);
        v[2*i+1] = __uint_as_float(rw[i] & 0xffff0000u);
    }

    float sum = 0.f, sq = 0.f;
    #pragma unroll
    for (int i = 0; i < 8; i++) { sum += v[i]; sq += v[i] * v[i]; }
    #pragma unroll
    for (int off = 32; off > 0; off >>= 1) {
        sum += __shfl_xor(sum, off);
        sq  += __shfl_xor(sq, off);
    }
    float mu = sum * (1.f / DD);
    float var = sq * (1.f / DD) - mu * mu;
    float rstd = rsqrtf(var + 1e-5f);

    float s[8], bi[8];
    *reinterpret_cast<float4*>(s)      = *reinterpret_cast<const float4*>(scale + lane * 8);
    *reinterpret_cast<float4*>(s + 4)  = *reinterpret_cast<const float4*>(scale + lane * 8 + 4);
    *reinterpret_cast<float4*>(bi)     = *reinterpret_cast<const float4*>(bias + lane * 8);
    *reinterpret_cast<float4*>(bi + 4) = *reinterpret_cast<const float4*>(bias + lane * 8 + 4);

    unsigned int pk[4];
    #pragma unroll
    for (int i = 0; i < 4; i++) {
        unsigned short lo = f2bf((v[2*i]   - mu) * rstd * s[2*i]   + bi[2*i]);
        unsigned short hi = f2bf((v[2*i+1] - mu) * rstd * s[2*i+1] + bi[2*i+1]);
        pk[i] = (unsigned)lo | ((unsigned)hi << 16);
    }
    *reinterpret_cast<uint4*>(g + (size_t)row * DD + lane * 8) =
        *reinterpret_cast<const uint4*>(pk);
}

// ---------------------------------------------------------------------------
// Kernel 3: MFMA GEMM  C[M,N] = A[M,K](bf16) * W[N,K]^T(bf16)
// Tile MT x 128 (MT=128: 256 thr / 4 waves; MT=64: 128 thr / 2 waves).
// Double-buffered LDS + global_load_lds with counted vmcnt. Pre-swizzled
// source (seg^row) pairs with read XOR swizzle. Epilogue: +bias, tanh-GELU
// (exp2+rcp form, |err| < 4e-4 vs exact erf), +resid(bf16); QSCALE
// multiplies cols n<DD by C8. OMODE: 0 = f32 out, 1 = bf16 out.
// ---------------------------------------------------------------------------
template<bool HAS_BIAS, bool GELU, bool RESID, bool QSCALE, int OMODE, int MT>
__global__ __launch_bounds__(MT * 2)
void gemm_mfma(const unsigned short* __restrict__ A,
               const unsigned short* __restrict__ W,
               const float* __restrict__ bias,
               const unsigned short* __restrict__ resid,
               void* __restrict__ Cv,
               int Nn, int Kk)
{
    constexpr int NW = MT / 32;          // waves per block (4 or 2)
    constexpr int BLOADS = 512 / MT;     // B-stage loads per thread (4 or 8)
    constexpr int VMN = 4 + BLOADS;      // outstanding loads for one buffer

    __shared__ unsigned short As[2][MT * 64];
    __shared__ unsigned short Bs[2][128 * 64];

    int t = threadIdx.x;
    int w = t >> 6, lane = t & 63;
    int wr = (MT == 128) ? (w >> 1) : 0;
    int wc = (MT == 128) ? (w & 1) : w;
    int l15 = lane & 15, l4 = lane >> 4;
    int m0 = blockIdx.y * MT, n0 = blockIdx.x * 128;

    int lrow = lane >> 3;              // 0..7 : row within the wave's 8-row slab
    int segp = (lane & 7) ^ lrow;      // pre-swizzled 16B-segment for global fetch

    float4v acc[4][4];
    #pragma unroll
    for (int i = 0; i < 4; i++)
        #pragma unroll
        for (int j = 0; j < 4; j++)
            acc[i][j] = (float4v){0.f, 0.f, 0.f, 0.f};

    #define STAGE(buf, k0) do {                                                   \
        _Pragma("unroll")                                                         \
        for (int i_ = 0; i_ < 4; i_++) {                                          \
            int r_ = i_ * (NW * 8) + w * 8 + lrow;                                \
            __builtin_amdgcn_global_load_lds(                                     \
                (glb_u32*)(A + (size_t)(m0 + r_) * Kk + (k0) + segp * 8),         \
                (lds_u32*)(As[buf] + i_ * (NW * 512) + w * 512), 16, 0, 0);       \
        }                                                                         \
        _Pragma("unroll")                                                         \
        for (int i_ = 0; i_ < BLOADS; i_++) {                                     \
            int r_ = i_ * (NW * 8) + w * 8 + lrow;                                \
            __builtin_amdgcn_global_load_lds(                                     \
                (glb_u32*)(W + (size_t)(n0 + r_) * Kk + (k0) + segp * 8),         \
                (lds_u32*)(Bs[buf] + i_ * (NW * 512) + w * 512), 16, 0, 0);       \
        } } while (0)

    int nk = Kk >> 6;
    STAGE(0, 0);
    for (int kt = 0; kt < nk; kt++) {
        int cur = kt & 1;
        if (kt + 1 < nk) {
            STAGE(cur ^ 1, (kt + 1) << 6);
            __builtin_amdgcn_sched_barrier(0);
            if constexpr (VMN == 8)  asm volatile("s_waitcnt vmcnt(8)");
            else                     asm volatile("s_waitcnt vmcnt(12)");
            __builtin_amdgcn_sched_barrier(0);
        } else {
            __builtin_amdgcn_sched_barrier(0);
            asm volatile("s_waitcnt vmcnt(0)");
            __builtin_amdgcn_sched_barrier(0);
        }
        __builtin_amdgcn_s_barrier();

        const char* asb = (const char*)As[cur];
        const char* bsb = (const char*)Bs[cur];
        #pragma unroll
        for (int kc = 0; kc < 2; kc++) {
            short8v af[4], bfr[4];
            #pragma unroll
            for (int mf = 0; mf < 4; mf++) {
                int row = wr * 64 + mf * 16 + l15;
                int off = (row * 128 + kc * 64 + l4 * 16) ^ ((row & 7) << 4);
                af[mf] = *reinterpret_cast<const short8v*>(asb + off);
            }
            #pragma unroll
            for (int nf = 0; nf < 4; nf++) {
                int row = wc * 64 + nf * 16 + l15;
                int off = (row * 128 + kc * 64 + l4 * 16) ^ ((row & 7) << 4);
                bfr[nf] = *reinterpret_cast<const short8v*>(bsb + off);
            }
            #pragma unroll
            for (int mf = 0; mf < 4; mf++)
                #pragma unroll
                for (int nf = 0; nf < 4; nf++)
                    acc[mf][nf] = __builtin_amdgcn_mfma_f32_16x16x32_bf16(
                        af[mf], bfr[nf], acc[mf][nf], 0, 0, 0);
        }
        __builtin_amdgcn_s_barrier();
    }
    #undef STAGE

    #pragma unroll
    for (int mf = 0; mf < 4; mf++)
        #pragma unroll
        for (int nf = 0; nf < 4; nf++)
            #pragma unroll
            for (int r = 0; r < 4; r++) {
                int m = m0 + wr * 64 + mf * 16 + l4 * 4 + r;
                int n = n0 + wc * 64 + nf * 16 + l15;
                if (n < Nn) {
                    float v = acc[mf][nf][r];
                    if (HAS_BIAS) v += bias[n];
                    if (GELU) {
                        // tanh-form GELU: v * e / (e+1), e = exp2(K*(v + c*v^3))
                        float a = 0.044715f * v * v;
                        float u = fminf(fmaf(a, v, v) * 2.3022077f, 80.f);
                        float e = __builtin_amdgcn_exp2f(u);
                        v = v * e * __builtin_amdgcn_rcpf(e + 1.f);
                    }
                    if (RESID)    v += bf2f(resid[(size_t)m * Nn + n]);
                    if (QSCALE && n < DD) v *= C8;   // Q columns only
                    if (OMODE == 1)
                        ((unsigned short*)Cv)[(size_t)m * Nn + n] = f2bf(v);
                    else
                        ((float*)Cv)[(size_t)m * Nn + n] = v;
                }
            }
}

// ---------------------------------------------------------------------------
// Kernel 4: MFMA flash attention (bf16 qkv in, bf16 o out)
// 256 blocks (8 qtile x 8 head x 4 batch, XCD-swizzled) = 1 block/CU;
// 8 waves x 32 q-rows (two q-tiles A/B per wave). The shared K b128 reads and
// V tr-reads serve BOTH q-tiles -> LDS read traffic halves vs 16-q waves
// (attn was LDS-pipe bound). KB=128 double-buffered via global_load_lds;
// swapped QK^T; Q pre-scaled by 0.125*log2e; K rows staged kappa-PERMUTED so
// the QK^T C-frag IS the PV A-frag after cvt_pk (no P LDS round-trip).
// ---------------------------------------------------------------------------
__global__ __launch_bounds__(512, 2)
void attn_mfma(const unsigned short* __restrict__ qkv, unsigned short* __restrict__ o)
{
    __shared__ unsigned short Kl[2][128 * 64];  // [row][d] swizzled, 16 KB each
    __shared__ unsigned short Vs[2][128 * 64];  // subtiled, 16 KB each
    __shared__ float Scl[8][2][16];             // per-wave per-qtile broadcast

    int t = threadIdx.x, w = t >> 6, lane = t & 63;
    int l15 = lane & 15, l4 = lane >> 4;

    // XCD-swizzled block decode (256 = 8 XCD * 32)
    int flat = blockIdx.x;
    int swz = (flat & 7) * 32 + (flat >> 3);
    int qt = swz & 7, hh = (swz >> 3) & 7, b = swz >> 6;

    int q0 = qt * 256 + w * 32;
    const int RS = 3 * DD; // 1536

    // Q fragments for both q-tiles (B-operand of swapped QK^T); pre-scaled
    short8v qfA[2], qfB[2];
    #pragma unroll
    for (int dh = 0; dh < 2; dh++) {
        size_t addrA = (size_t)(b * LL + q0 + l15) * RS + hh * HDIM + dh * 32 + l4 * 8;
        qfA[dh] = *reinterpret_cast<const short8v*>(qkv + addrA);
        qfB[dh] = *reinterpret_cast<const short8v*>(qkv + addrA + 16 * RS);
    }

    float4v oA[4], oB[4];
    #pragma unroll
    for (int dt = 0; dt < 4; dt++) {
        oA[dt] = (float4v){0.f, 0.f, 0.f, 0.f};
        oB[dt] = (float4v){0.f, 0.f, 0.f, 0.f};
    }
    float lA = 0.f, lB = 0.f;   // per-lane partial over own keys

    // staging: K rows permuted (LDS row rho holds key kappa(rho)) so that
    // lane (q=l15, l4) ends up holding keys {8*l4+0..7, 32+8*l4+0..7}.
    int lrow8 = lane >> 3;                       // 0..7
    int ksegp = (lane & 7) ^ lrow8;
    int rho = w * 8 + lrow8;                     // LDS K-row this lane fills
    int kappa = ((rho >> 5) << 5) | (((rho >> 4) & 1) << 2)
              | (((rho >> 2) & 3) << 3) | (rho & 3);
    int vrow = ((t >> 5) << 2) | ((t >> 1) & 3);
    int vseg = (((t >> 3) & 3) << 1) | (t & 1);
    const unsigned short* kgl = qkv + (size_t)(b * LL + kappa) * RS
                              + hh * HDIM + DD + ksegp * 8;
    const unsigned short* vgl = qkv + (size_t)(b * LL + vrow) * RS
                              + hh * HDIM + 2 * DD + vseg * 8;
    const int halfstep = 64 * RS;   // +64 keys (second half of the 128-tile)
    const int step = 128 * RS;

    #define ASTAGE(buf) do {                                                      \
        __builtin_amdgcn_global_load_lds((glb_u32*)kgl,                           \
            (lds_u32*)(Kl[buf] + w * 512), 16, 0, 0);                             \
        __builtin_amdgcn_global_load_lds((glb_u32*)(kgl + halfstep),              \
            (lds_u32*)(Kl[buf] + 4096 + w * 512), 16, 0, 0);                      \
        __builtin_amdgcn_global_load_lds((glb_u32*)vgl,                           \
            (lds_u32*)(Vs[buf] + w * 512), 16, 0, 0);                             \
        __builtin_amdgcn_global_load_lds((glb_u32*)(vgl + halfstep),              \
            (lds_u32*)(Vs[buf] + 4096 + w * 512), 16, 0, 0);                      \
        kgl += step; vgl += step; } while (0)

    // per-lane tr-read base (bytes within one Vs 64-key half)
    unsigned vtrbase = lds_addr(Vs) + ((lane >> 4) << 10)
                     + (((lane >> 2) & 3) << 5) + ((lane & 3) << 3);

    // prologue: stage tile 0 into buf 0
    ASTAGE(0);
    asm volatile("s_waitcnt vmcnt(0)");
    __syncthreads();

    for (int kb = 0; kb < LL / 128; kb++) {
        int cur = kb & 1;
        if (kb + 1 < LL / 128) ASTAGE(cur ^ 1);   // async DMA into other buffer

        #pragma unroll
        for (int hf = 0; hf < 2; hf++) {
            const char* klc = (const char*)Kl[cur] + hf * 8192;
            unsigned vb = vtrbase + cur * 16384 + hf * 8192;

            // S^T = K Q^T for both q-tiles; K-frags shared
            float4v sA[4], sB[4];
            __builtin_amdgcn_s_setprio(1);
            #pragma unroll
            for (int nt = 0; nt < 4; nt++) {
                sA[nt] = (float4v){0.f, 0.f, 0.f, 0.f};
                sB[nt] = (float4v){0.f, 0.f, 0.f, 0.f};
                #pragma unroll
                for (int dh = 0; dh < 2; dh++) {
                    int row = nt * 16 + l15;
                    int off = (row * 128 + dh * 64 + l4 * 16) ^ ((row & 7) << 4);
                    short8v kf = *reinterpret_cast<const short8v*>(klc + off);
                    sA[nt] = __builtin_amdgcn_mfma_f32_16x16x32_bf16(kf, qfA[dh], sA[nt], 0, 0, 0);
                    sB[nt] = __builtin_amdgcn_mfma_f32_16x16x32_bf16(kf, qfB[dh], sB[nt], 0, 0, 0);
                }
            }
            __builtin_amdgcn_s_setprio(0);

            // issue all V tr-reads now; latency hides under the exp section
            unsigned long long a0, a1, a2, a3, a4, a5, a6, a7;
            unsigned long long b0, b1, b2, b3, b4, b5, b6, b7;
            unsigned ab0 = vb, ab1 = vb + 4096;
            asm volatile("ds_read_b64_tr_b16 %0, %1" : "=v"(a0) : "v"(ab0));
            asm volatile("ds_read_b64_tr_b16 %0, %1" : "=v"(a1) : "v"(ab0 + 512));
            asm volatile("ds_read_b64_tr_b16 %0, %1" : "=v"(a2) : "v"(ab0 + 128));
            asm volatile("ds_read_b64_tr_b16 %0, %1" : "=v"(a3) : "v"(ab0 + 640));
            asm volatile("ds_read_b64_tr_b16 %0, %1" : "=v"(a4) : "v"(ab0 + 256));
            asm volatile("ds_read_b64_tr_b16 %0, %1" : "=v"(a5) : "v"(ab0 + 768));
            asm volatile("ds_read_b64_tr_b16 %0, %1" : "=v"(a6) : "v"(ab0 + 384));
            asm volatile("ds_read_b64_tr_b16 %0, %1" : "=v"(a7) : "v"(ab0 + 896));
            asm volatile("ds_read_b64_tr_b16 %0, %1" : "=v"(b0) : "v"(ab1));
            asm volatile("ds_read_b64_tr_b16 %0, %1" : "=v"(b1) : "v"(ab1 + 512));
            asm volatile("ds_read_b64_tr_b16 %0, %1" : "=v"(b2) : "v"(ab1 + 128));
            asm volatile("ds_read_b64_tr_b16 %0, %1" : "=v"(b3) : "v"(ab1 + 640));
            asm volatile("ds_read_b64_tr_b16 %0, %1" : "=v"(b4) : "v"(ab1 + 256));
            asm volatile("ds_read_b64_tr_b16 %0, %1" : "=v"(b5) : "v"(ab1 + 768));
            asm volatile("ds_read_b64_tr_b16 %0, %1" : "=v"(b6) : "v"(ab1 + 384));
            asm volatile("ds_read_b64_tr_b16 %0, %1" : "=v"(b7) : "v"(ab1 + 896));

            // P = exp2(s); cvt_pk assembles the PV A-frags directly in-lane.
            union { unsigned u[4]; short8v v; } pf0A, pf1A, pf0B, pf1B;
            {
                float p0 = __builtin_amdgcn_exp2f(sA[0][0]);
                float p1 = __builtin_amdgcn_exp2f(sA[0][1]);
                float p2 = __builtin_amdgcn_exp2f(sA[0][2]);
                float p3 = __builtin_amdgcn_exp2f(sA[0][3]);
                float p4 = __builtin_amdgcn_exp2f(sA[1][0]);
                float p5 = __builtin_amdgcn_exp2f(sA[1][1]);
                float p6 = __builtin_amdgcn_exp2f(sA[1][2]);
                float p7 = __builtin_amdgcn_exp2f(sA[1][3]);
                asm("v_cvt_pk_bf16_f32 %0, %1, %2" : "=v"(pf0A.u[0]) : "v"(p0), "v"(p1));
                asm("v_cvt_pk_bf16_f32 %0, %1, %2" : "=v"(pf0A.u[1]) : "v"(p2), "v"(p3));
                asm("v_cvt_pk_bf16_f32 %0, %1, %2" : "=v"(pf0A.u[2]) : "v"(p4), "v"(p5));
                asm("v_cvt_pk_bf16_f32 %0, %1, %2" : "=v"(pf0A.u[3]) : "v"(p6), "v"(p7));
                float q0_ = __builtin_amdgcn_exp2f(sA[2][0]);
                float q1_ = __builtin_amdgcn_exp2f(sA[2][1]);
                float q2_ = __builtin_amdgcn_exp2f(sA[2][2]);
                float q3_ = __builtin_amdgcn_exp2f(sA[2][3]);
                float q4_ = __builtin_amdgcn_exp2f(sA[3][0]);
                float q5_ = __builtin_amdgcn_exp2f(sA[3][1]);
                float q6_ = __builtin_amdgcn_exp2f(sA[3][2]);
                float q7_ = __builtin_amdgcn_exp2f(sA[3][3]);
                asm("v_cvt_pk_bf16_f32 %0, %1, %2" : "=v"(pf1A.u[0]) : "v"(q0_), "v"(q1_));
                asm("v_cvt_pk_bf16_f32 %0, %1, %2" : "=v"(pf1A.u[1]) : "v"(q2_), "v"(q3_));
                asm("v_cvt_pk_bf16_f32 %0, %1, %2" : "=v"(pf1A.u[2]) : "v"(q4_), "v"(q5_));
                asm("v_cvt_pk_bf16_f32 %0, %1, %2" : "=v"(pf1A.u[3]) : "v"(q6_), "v"(q7_));
                lA += ((p0 + p1) + (p2 + p3)) + ((p4 + p5) + (p6 + p7))
                    + ((q0_ + q1_) + (q2_ + q3_)) + ((q4_ + q5_) + (q6_ + q7_));
            }
            {
                float p0 = __builtin_amdgcn_exp2f(sB[0][0]);
                float p1 = __builtin_amdgcn_exp2f(sB[0][1]);
                float p2 = __builtin_amdgcn_exp2f(sB[0][2]);
                float p3 = __builtin_amdgcn_exp2f(sB[0][3]);
                float p4 = __builtin_amdgcn_exp2f(sB[1][0]);
                float p5 = __builtin_amdgcn_exp2f(sB[1][1]);
                float p6 = __builtin_amdgcn_exp2f(sB[1][2]);
                float p7 = __builtin_amdgcn_exp2f(sB[1][3]);
                asm("v_cvt_pk_bf16_f32 %0, %1, %2" : "=v"(pf0B.u[0]) : "v"(p0), "v"(p1));
                asm("v_cvt_pk_bf16_f32 %0, %1, %2" : "=v"(pf0B.u[1]) : "v"(p2), "v"(p3));
                asm("v_cvt_pk_bf16_f32 %0, %1, %2" : "=v"(pf0B.u[2]) : "v"(p4), "v"(p5));
                asm("v_cvt_pk_bf16_f32 %0, %1, %2" : "=v"(pf0B.u[3]) : "v"(p6), "v"(p7));
                float q0_ = __builtin_amdgcn_exp2f(sB[2][0]);
                float q1_ = __builtin_amdgcn_exp2f(sB[2][1]);
                float q2_ = __builtin_amdgcn_exp2f(sB[2][2]);
                float q3_ = __builtin_amdgcn_exp2f(sB[2][3]);
                float q4_ = __builtin_amdgcn_exp2f(sB[3][0]);
                float q5_ = __builtin_amdgcn_exp2f(sB[3][1]);
                float q6_ = __builtin_amdgcn_exp2f(sB[3][2]);
                float q7_ = __builtin_amdgcn_exp2f(sB[3][3]);
                asm("v_cvt_pk_bf16_f32 %0, %1, %2" : "=v"(pf1B.u[0]) : "v"(q0_), "v"(q1_));
                asm("v_cvt_pk_bf16_f32 %0, %1, %2" : "=v"(pf1B.u[1]) : "v"(q2_), "v"(q3_));
                asm("v_cvt_pk_bf16_f32 %0, %1, %2" : "=v"(pf1B.u[2]) : "v"(q4_), "v"(q5_));
                asm("v_cvt_pk_bf16_f32 %0, %1, %2" : "=v"(pf1B.u[3]) : "v"(q6_), "v"(q7_));
                lB += ((p0 + p1) + (p2 + p3)) + ((p4 + p5) + (p6 + p7))
                    + ((q0_ + q1_) + (q2_ + q3_)) + ((q4_ + q5_) + (q6_ + q7_));
            }

            // O += P V : V-frags shared between both q-tiles
            union { unsigned long long q[2]; short8v v; } u0, u1, u2, u3;
            asm volatile("s_waitcnt lgkmcnt(8)");
            __builtin_amdgcn_sched_barrier(0);
            __builtin_amdgcn_s_setprio(1);
            u0.q[0] = a0; u0.q[1] = a1;
            u1.q[0] = a2; u1.q[1] = a3;
            oA[0] = __builtin_amdgcn_mfma_f32_16x16x32_bf16(pf0A.v, u0.v, oA[0], 0, 0, 0);
            oB[0] = __builtin_amdgcn_mfma_f32_16x16x32_bf16(pf0B.v, u0.v, oB[0], 0, 0, 0);
            oA[1] = __builtin_amdgcn_mfma_f32_16x16x32_bf16(pf0A.v, u1.v, oA[1], 0, 0, 0);
            oB[1] = __builtin_amdgcn_mfma_f32_16x16x32_bf16(pf0B.v, u1.v, oB[1], 0, 0, 0);
            asm volatile("s_waitcnt lgkmcnt(4)");
            __builtin_amdgcn_sched_barrier(0);
            u2.q[0] = a4; u2.q[1] = a5;
            u3.q[0] = a6; u3.q[1] = a7;
            oA[2] = __builtin_amdgcn_mfma_f32_16x16x32_bf16(pf0A.v, u2.v, oA[2], 0, 0, 0);
            oB[2] = __builtin_amdgcn_mfma_f32_16x16x32_bf16(pf0B.v, u2.v, oB[2], 0, 0, 0);
            oA[3] = __builtin_amdgcn_mfma_f32_16x16x32_bf16(pf0A.v, u3.v, oA[3], 0, 0, 0);
            oB[3] = __builtin_amdgcn_mfma_f32_16x16x32_bf16(pf0B.v, u3.v, oB[3], 0, 0, 0);
            asm volatile("s_waitcnt lgkmcnt(0)");
            __builtin_amdgcn_sched_barrier(0);
            u0.q[0] = b0; u0.q[1] = b1;
            u1.q[0] = b2; u1.q[1] = b3;
            u2.q[0] = b4; u2.q[1] = b5;
            u3.q[0] = b6; u3.q[1] = b7;
            oA[0] = __builtin_amdgcn_mfma_f32_16x16x32_bf16(pf1A.v, u0.v, oA[0], 0, 0, 0);
            oB[0] = __builtin_amdgcn_mfma_f32_16x16x32_bf16(pf1B.v, u0.v, oB[0], 0, 0, 0);
            oA[1] = __builtin_amdgcn_mfma_f32_16x16x32_bf16(pf1A.v, u1.v, oA[1], 0, 0, 0);
            oB[1] = __builtin_amdgcn_mfma_f32_16x16x32_bf16(pf1B.v, u1.v, oB[1], 0, 0, 0);
            oA[2] = __builtin_amdgcn_mfma_f32_16x16x32_bf16(pf1A.v, u2.v, oA[2], 0, 0, 0);
            oB[2] = __builtin_amdgcn_mfma_f32_16x16x32_bf16(pf1B.v, u2.v, oB[2], 0, 0, 0);
            oA[3] = __builtin_amdgcn_mfma_f32_16x16x32_bf16(pf1A.v, u3.v, oA[3], 0, 0, 0);
            oB[3] = __builtin_amdgcn_mfma_f32_16x16x32_bf16(pf1B.v, u3.v, oB[3], 0, 0, 0);
            __builtin_amdgcn_s_setprio(0);
        }

        // own DMAs for next tile must land before the barrier releases readers
        asm volatile("s_waitcnt vmcnt(0)");
        __syncthreads();
    }
    #undef ASTAGE

    // epilogue: reduce l across the 4 copies, broadcast 1/l per q-tile
    float ltA = lA, ltB = lB;
    ltA += __shfl_xor(ltA, 16); ltA += __shfl_xor(ltA, 32);
    ltB += __shfl_xor(ltB, 16); ltB += __shfl_xor(ltB, 32);
    if (l4 == 0) { Scl[w][0][l15] = 1.f / ltA; Scl[w][1][l15] = 1.f / ltB; }
    float4 ivA = *reinterpret_cast<const float4*>(&Scl[w][0][l4 * 4]);
    float4 ivB = *reinterpret_cast<const float4*>(&Scl[w][1][l4 * 4]);
    float invA[4] = {ivA.x, ivA.y, ivA.z, ivA.w};
    float invB[4] = {ivB.x, ivB.y, ivB.z, ivB.w};
    #pragma unroll
    for (int r = 0; r < 4; r++) {
        int qgA = q0 + l4 * 4 + r;
        #pragma unroll
        for (int dt = 0; dt < 4; dt++) {
            o[(size_t)(b * LL + qgA) * DD + hh * HDIM + dt * 16 + l15] =
                f2bf(oA[dt][r] * invA[r]);
            o[(size_t)(b * LL + qgA + 16) * DD + hh * HDIM + dt * 16 + l15] =
                f2bf(oB[dt][r] * invB[r]);
        }
    }
}

// ---------------------------------------------------------------------------
// Driver
// ---------------------------------------------------------------------------
extern "C" void kernel_launch(void* const* d_in, const int* in_sizes, int n_in,
                              void* d_out, int out_size, void* d_ws, size_t ws_size,
                              hipStream_t stream)
{
    const float* emb    = (const float*)d_in[0];
    const float* ent_w  = (const float*)d_in[1];
    const float* ent_b  = (const float*)d_in[2];
    const float* qkv_w  = (const float*)d_in[3];
    const float* qkv_b  = (const float*)d_in[4];
    const float* ao_w   = (const float*)d_in[5];
    const float* ao_b   = (const float*)d_in[6];
    const float* ln1_s  = (const float*)d_in[7];
    const float* ln1_b  = (const float*)d_in[8];
    const float* ln2_s  = (const float*)d_in[9];
    const float* ln2_b  = (const float*)d_in[10];
    const float* ff1_w  = (const float*)d_in[11];
    const float* ff1_b  = (const float*)d_in[12];
    const float* ff2_w  = (const float*)d_in[13];
    const float* ff2_b  = (const float*)d_in[14];
    const float* out_w  = (const float*)d_in[15];
    const int*   x      = (const int*)d_in[16];
    // d_in[17] = patch_lengths : dead code in the reference

    float* out = (float*)d_out;

    const int NQW = NLAYER * 3 * DD * DD;
    const int NAW = NLAYER * DD * DD;
    const int NF1 = NLAYER * 4 * DD * DD;
    const int NF2 = NLAYER * DD * 4 * DD;

    char* p = (char*)d_ws;
    unsigned short* wq  = (unsigned short*)p; p += (size_t)NQW * 2;
    unsigned short* wa  = (unsigned short*)p; p += (size_t)NAW * 2;
    unsigned short* w1  = (unsigned short*)p; p += (size_t)NF1 * 2;
    unsigned short* w2  = (unsigned short*)p; p += (size_t)NF2 * 2;
    unsigned short* wob = (unsigned short*)p; p += (size_t)VPAD * DD * 2;
    unsigned short* h   = (unsigned short*)p; p += (size_t)MM * DD * 2;   // bf16 residual
    unsigned short* gb  = (unsigned short*)p; p += (size_t)MM * DD * 2;
    unsigned short* ob  = (unsigned short*)p; p += (size_t)MM * DD * 2;
    unsigned short* bb  = (unsigned short*)p; p += (size_t)MM * 4 * DD * 2; // qkv / ffn

    dim3 blk(256);

    // all weight conversions in one dispatch (wq..wob contiguous)
    cvt_all_kernel<<<E4 / 1024, blk, 0, stream>>>(qkv_w, ao_w, ff1_w, ff2_w, out_w, wq);

    // fused embedding + entropy + LN1(layer 0): writes h (bf16) and gb
    embed_ln_kernel<<<MM / 4, blk, 0, stream>>>(x, emb, ent_w, ent_b,
                                                ln1_s, ln1_b, h, gb);

    for (int layer = 0; layer < NLAYER; layer++) {
        const unsigned short* qw = wq + (size_t)layer * 3 * DD * DD;
        const unsigned short* aw = wa + (size_t)layer * DD * DD;
        const unsigned short* f1 = w1 + (size_t)layer * 4 * DD * DD;
        const unsigned short* f2 = w2 + (size_t)layer * DD * 4 * DD;
        const float* qb  = qkv_b + (size_t)layer * 3 * DD;
        const float* ab  = ao_b  + (size_t)layer * DD;
        const float* l1s = ln1_s + (size_t)layer * DD;
        const float* l1b = ln1_b + (size_t)layer * DD;
        const float* l2s = ln2_s + (size_t)layer * DD;
        const float* l2b = ln2_b + (size_t)layer * DD;
        const float* f1b = ff1_b + (size_t)layer * 4 * DD;
        const float* f2b = ff2_b + (size_t)layer * DD;

        // LN1 (layer 0 fused into embed_ln_kernel)
        if (layer > 0)
            ln_kernel<<<MM / 4, blk, 0, stream>>>(h, l1s, l1b, gb);

        // qkv = gb @ qw^T + qb -> bb (bf16) [MM,1536], Q cols pre-scaled by C8
        {
            dim3 grid((3 * DD) / 128, MM / 128);
            gemm_mfma<true, false, false, true, 1, 128><<<grid, 256, 0, stream>>>(
                gb, qw, qb, nullptr, bb, 3 * DD, DD);
        }

        // attention: bb -> ob (bf16)
        attn_mfma<<<256, 512, 0, stream>>>(bb, ob);

        // h = h + ob @ aw^T + ab  (bf16 out; MT=64 -> 512 blocks)
        {
            dim3 grid(DD / 128, MM / 64);
            gemm_mfma<true, false, true, false, 1, 64><<<grid, 128, 0, stream>>>(
                ob, aw, ab, h, h, DD, DD);
        }

        // LN2: h -> gb
        ln_kernel<<<MM / 4, blk, 0, stream>>>(h, l2s, l2b, gb);

        // ffn1: bb = gelu(gb @ f1^T + f1b) (bf16) [MM,2048]
        {
            dim3 grid((4 * DD) / 128, MM / 128);
            gemm_mfma<true, true, false, false, 1, 128><<<grid, 256, 0, stream>>>(
                gb, f1, f1b, nullptr, bb, 4 * DD, DD);
        }

        // ffn2: h = h + bb @ f2^T + f2b  (bf16 out; MT=64)
        {
            dim3 grid(DD / 128, MM / 64);
            gemm_mfma<true, false, true, false, 1, 64><<<grid, 128, 0, stream>>>(
                bb, f2, f2b, h, h, DD, 4 * DD);
        }
    }

    // logits = h @ wob^T [MM, 258] via MFMA on padded weight (MT=64)
    {
        dim3 grid(VPAD / 128, MM / 64);
        gemm_mfma<false, false, false, false, 0, 64><<<grid, 128, 0, stream>>>(
            h, wob, nullptr, nullptr, out, VV, DD);
    }
}

// Round 14
// 713.185 us; speedup vs baseline: 1.0105x; 1.0105x over previous
//
#include <hip/hip_runtime.h>
#include <hip/hip_bf16.h>
#include <math.h>

// Problem constants
#define BB 4
#define LL 2048
#define DD 512
#define HH 8
#define NLAYER 4
#define VV 258
#define WW 8
#define HDIM 64
#define MM (BB * LL)   // 8192 rows
#define VPAD 384       // logits weight rows padded to tile multiple

// 0.125 * log2(e): QK^T scale, folded into Q at the qkv-GEMM epilogue
#define C8 0.18033688f

typedef __attribute__((ext_vector_type(8))) short short8v;
typedef __attribute__((ext_vector_type(4))) float float4v;

typedef __attribute__((address_space(3))) unsigned int lds_u32;
typedef const __attribute__((address_space(1))) unsigned int glb_u32;

__device__ __forceinline__ unsigned short f2bf(float x) {
    unsigned int u = __float_as_uint(x);
    unsigned int r = (u + 0x7fffu + ((u >> 16) & 1u)) >> 16;
    return (unsigned short)r;
}
__device__ __forceinline__ float bf2f(unsigned short u) {
    return __uint_as_float((unsigned)u << 16);
}

__device__ __forceinline__ unsigned lds_addr(const void* p) {
    return (unsigned)(size_t)(__attribute__((address_space(3))) const void*)p;
}

// ---------------------------------------------------------------------------
// Fused weight conversion: all four layer-weight arrays + padded out_w,
// one dispatch. Output regions are contiguous in ws: wq|wa|w1|w2|wob.
// ---------------------------------------------------------------------------
#define E0 (NLAYER * 3 * DD * DD)          // 3,145,728
#define E1 (E0 + NLAYER * DD * DD)         // 4,194,304
#define E2 (E1 + NLAYER * 4 * DD * DD)     // 8,388,608
#define E3 (E2 + NLAYER * 4 * DD * DD)     // 12,582,912
#define E4 (E3 + VPAD * DD)                // 12,779,520

__global__ __launch_bounds__(256)
void cvt_all_kernel(const float* __restrict__ qkv_w, const float* __restrict__ ao_w,
                    const float* __restrict__ ff1_w, const float* __restrict__ ff2_w,
                    const float* __restrict__ out_w, unsigned short* __restrict__ dst)
{
    int i = (blockIdx.x * 256 + threadIdx.x) * 4;
    float4 v;
    if (i < E0)      v = *reinterpret_cast<const float4*>(qkv_w + i);
    else if (i < E1) v = *reinterpret_cast<const float4*>(ao_w + (i - E0));
    else if (i < E2) v = *reinterpret_cast<const float4*>(ff1_w + (i - E1));
    else if (i < E3) v = *reinterpret_cast<const float4*>(ff2_w + (i - E2));
    else {
        int idx = i - E3;
        if ((idx >> 9) < VV) v = *reinterpret_cast<const float4*>(out_w + idx);
        else                 v = (float4){0.f, 0.f, 0.f, 0.f};
    }
    uint2 pk;
    pk.x = (unsigned)f2bf(v.x) | ((unsigned)f2bf(v.y) << 16);
    pk.y = (unsigned)f2bf(v.z) | ((unsigned)f2bf(v.w) << 16);
    *reinterpret_cast<uint2*>(dst + i) = pk;
}

// ---------------------------------------------------------------------------
// Kernel 1: fused token embedding + entropy feature + LN1(layer 0)
// One wave per row, 4 rows/block. Writes h (bf16 residual) and g (bf16 LN'd).
// Entropy: window x[b,l:l+8] for l <= L-W; values >= 256 contribute nothing.
// ---------------------------------------------------------------------------
__global__ __launch_bounds__(256)
void embed_ln_kernel(const int* __restrict__ x,
                     const float* __restrict__ emb,
                     const float* __restrict__ ent_w,
                     const float* __restrict__ ent_b,
                     const float* __restrict__ ln_s,
                     const float* __restrict__ ln_b,
                     unsigned short* __restrict__ h,
                     unsigned short* __restrict__ g)
{
    int w = threadIdx.x >> 6, lane = threadIdx.x & 63;
    int row = blockIdx.x * 4 + w;
    int b = row / LL, l = row % LL;

    float ent = 0.f;
    if (l <= LL - WW) {
        int win[WW];
        #pragma unroll
        for (int i = 0; i < WW; i++) win[i] = x[b * LL + l + i];
        float s = 0.f;
        #pragma unroll
        for (int i = 0; i < WW; i++) {
            if (win[i] < 256) {
                int c = 0;
                #pragma unroll
                for (int j = 0; j < WW; j++) c += (win[j] == win[i]) ? 1 : 0;
                s += log2f((float)c * 0.125f + 1e-10f);
            }
        }
        ent = -s * 0.125f;
    }

    int tok = x[row];
    const float* erow = emb + (size_t)tok * DD + lane * 8;
    float v[8], ew[8], eb[8];
    *reinterpret_cast<float4*>(v)      = *reinterpret_cast<const float4*>(erow);
    *reinterpret_cast<float4*>(v + 4)  = *reinterpret_cast<const float4*>(erow + 4);
    *reinterpret_cast<float4*>(ew)     = *reinterpret_cast<const float4*>(ent_w + lane * 8);
    *reinterpret_cast<float4*>(ew + 4) = *reinterpret_cast<const float4*>(ent_w + lane * 8 + 4);
    *reinterpret_cast<float4*>(eb)     = *reinterpret_cast<const float4*>(ent_b + lane * 8);
    *reinterpret_cast<float4*>(eb + 4) = *reinterpret_cast<const float4*>(ent_b + lane * 8 + 4);

    float sum = 0.f, sq = 0.f;
    #pragma unroll
    for (int i = 0; i < 8; i++) {
        v[i] = v[i] + ent * ew[i] + eb[i];
        sum += v[i]; sq += v[i] * v[i];
    }
    unsigned int hpk[4];
    #pragma unroll
    for (int i = 0; i < 4; i++)
        hpk[i] = (unsigned)f2bf(v[2*i]) | ((unsigned)f2bf(v[2*i+1]) << 16);
    *reinterpret_cast<uint4*>(h + (size_t)row * DD + lane * 8) =
        *reinterpret_cast<const uint4*>(hpk);

    #pragma unroll
    for (int off = 32; off > 0; off >>= 1) {
        sum += __shfl_xor(sum, off);
        sq  += __shfl_xor(sq, off);
    }
    float mu = sum * (1.f / DD);
    float var = sq * (1.f / DD) - mu * mu;
    float rstd = rsqrtf(var + 1e-5f);

    float s8[8], bi[8];
    *reinterpret_cast<float4*>(s8)     = *reinterpret_cast<const float4*>(ln_s + lane * 8);
    *reinterpret_cast<float4*>(s8 + 4) = *reinterpret_cast<const float4*>(ln_s + lane * 8 + 4);
    *reinterpret_cast<float4*>(bi)     = *reinterpret_cast<const float4*>(ln_b + lane * 8);
    *reinterpret_cast<float4*>(bi + 4) = *reinterpret_cast<const float4*>(ln_b + lane * 8 + 4);

    unsigned int pk[4];
    #pragma unroll
    for (int i = 0; i < 4; i++) {
        unsigned short lo = f2bf((v[2*i]   - mu) * rstd * s8[2*i]   + bi[2*i]);
        unsigned short hi = f2bf((v[2*i+1] - mu) * rstd * s8[2*i+1] + bi[2*i+1]);
        pk[i] = (unsigned)lo | ((unsigned)hi << 16);
    }
    *reinterpret_cast<uint4*>(g + (size_t)row * DD + lane * 8) =
        *reinterpret_cast<const uint4*>(pk);
}

// ---------------------------------------------------------------------------
// Kernel 2: LayerNorm (bf16 in, bf16 out). One wave per row, 4 rows/block.
// ---------------------------------------------------------------------------
__global__ __launch_bounds__(256)
void ln_kernel(const unsigned short* __restrict__ h,
               const float* __restrict__ scale,
               const float* __restrict__ bias,
               unsigned short* __restrict__ g)
{
    int w = threadIdx.x >> 6, lane = threadIdx.x & 63;
    int row = blockIdx.x * 4 + w;

    uint4 raw = *reinterpret_cast<const uint4*>(h + (size_t)row * DD + lane * 8);
    const unsigned* rw = reinterpret_cast<const unsigned*>(&raw);
    float v[8];
    #pragma unroll
    for (int i = 0; i < 4; i++) {
        v[2*i]   = __uint_as_float(rw[i] << 16);
        v[2*i+1] = __uint_as_float(rw[i] & 0xffff0000u);
    }

    float sum = 0.f, sq = 0.f;
    #pragma unroll
    for (int i = 0; i < 8; i++) { sum += v[i]; sq += v[i] * v[i]; }
    #pragma unroll
    for (int off = 32; off > 0; off >>= 1) {
        sum += __shfl_xor(sum, off);
        sq  += __shfl_xor(sq, off);
    }
    float mu = sum * (1.f / DD);
    float var = sq * (1.f / DD) - mu * mu;
    float rstd = rsqrtf(var + 1e-5f);

    float s[8], bi[8];
    *reinterpret_cast<float4*>(s)      = *reinterpret_cast<const float4*>(scale + lane * 8);
    *reinterpret_cast<float4*>(s + 4)  = *reinterpret_cast<const float4*>(scale + lane * 8 + 4);
    *reinterpret_cast<float4*>(bi)     = *reinterpret_cast<const float4*>(bias + lane * 8);
    *reinterpret_cast<float4*>(bi + 4) = *reinterpret_cast<const float4*>(bias + lane * 8 + 4);

    unsigned int pk[4];
    #pragma unroll
    for (int i = 0; i < 4; i++) {
        unsigned short lo = f2bf((v[2*i]   - mu) * rstd * s[2*i]   + bi[2*i]);
        unsigned short hi = f2bf((v[2*i+1] - mu) * rstd * s[2*i+1] + bi[2*i+1]);
        pk[i] = (unsigned)lo | ((unsigned)hi << 16);
    }
    *reinterpret_cast<uint4*>(g + (size_t)row * DD + lane * 8) =
        *reinterpret_cast<const uint4*>(pk);
}

// ---------------------------------------------------------------------------
// Kernel 3: MFMA GEMM  C[M,N] = A[M,K](bf16) * W[N,K]^T(bf16)
// Tile MT x 128 (MT=128: 256 thr / 4 waves; MT=64: 128 thr / 2 waves).
// Double-buffered LDS + global_load_lds with counted vmcnt. Pre-swizzled
// source (seg^row) pairs with read XOR swizzle. Epilogue: +bias, tanh-GELU
// (exp2+rcp form, |err| < 4e-4 vs exact erf), +resid(bf16); QSCALE
// multiplies cols n<DD by C8. OMODE: 0 = f32 out, 1 = bf16 out.
// ---------------------------------------------------------------------------
template<bool HAS_BIAS, bool GELU, bool RESID, bool QSCALE, int OMODE, int MT>
__global__ __launch_bounds__(MT * 2)
void gemm_mfma(const unsigned short* __restrict__ A,
               const unsigned short* __restrict__ W,
               const float* __restrict__ bias,
               const unsigned short* __restrict__ resid,
               void* __restrict__ Cv,
               int Nn, int Kk)
{
    constexpr int NW = MT / 32;          // waves per block (4 or 2)
    constexpr int BLOADS = 512 / MT;     // B-stage loads per thread (4 or 8)
    constexpr int VMN = 4 + BLOADS;      // outstanding loads for one buffer

    __shared__ unsigned short As[2][MT * 64];
    __shared__ unsigned short Bs[2][128 * 64];

    int t = threadIdx.x;
    int w = t >> 6, lane = t & 63;
    int wr = (MT == 128) ? (w >> 1) : 0;
    int wc = (MT == 128) ? (w & 1) : w;
    int l15 = lane & 15, l4 = lane >> 4;
    int m0 = blockIdx.y * MT, n0 = blockIdx.x * 128;

    int lrow = lane >> 3;              // 0..7 : row within the wave's 8-row slab
    int segp = (lane & 7) ^ lrow;      // pre-swizzled 16B-segment for global fetch

    float4v acc[4][4];
    #pragma unroll
    for (int i = 0; i < 4; i++)
        #pragma unroll
        for (int j = 0; j < 4; j++)
            acc[i][j] = (float4v){0.f, 0.f, 0.f, 0.f};

    #define STAGE(buf, k0) do {                                                   \
        _Pragma("unroll")                                                         \
        for (int i_ = 0; i_ < 4; i_++) {                                          \
            int r_ = i_ * (NW * 8) + w * 8 + lrow;                                \
            __builtin_amdgcn_global_load_lds(                                     \
                (glb_u32*)(A + (size_t)(m0 + r_) * Kk + (k0) + segp * 8),         \
                (lds_u32*)(As[buf] + i_ * (NW * 512) + w * 512), 16, 0, 0);       \
        }                                                                         \
        _Pragma("unroll")                                                         \
        for (int i_ = 0; i_ < BLOADS; i_++) {                                     \
            int r_ = i_ * (NW * 8) + w * 8 + lrow;                                \
            __builtin_amdgcn_global_load_lds(                                     \
                (glb_u32*)(W + (size_t)(n0 + r_) * Kk + (k0) + segp * 8),         \
                (lds_u32*)(Bs[buf] + i_ * (NW * 512) + w * 512), 16, 0, 0);       \
        } } while (0)

    int nk = Kk >> 6;
    STAGE(0, 0);
    for (int kt = 0; kt < nk; kt++) {
        int cur = kt & 1;
        if (kt + 1 < nk) {
            STAGE(cur ^ 1, (kt + 1) << 6);
            __builtin_amdgcn_sched_barrier(0);
            if constexpr (VMN == 8)  asm volatile("s_waitcnt vmcnt(8)");
            else                     asm volatile("s_waitcnt vmcnt(12)");
            __builtin_amdgcn_sched_barrier(0);
        } else {
            __builtin_amdgcn_sched_barrier(0);
            asm volatile("s_waitcnt vmcnt(0)");
            __builtin_amdgcn_sched_barrier(0);
        }
        __builtin_amdgcn_s_barrier();

        const char* asb = (const char*)As[cur];
        const char* bsb = (const char*)Bs[cur];
        #pragma unroll
        for (int kc = 0; kc < 2; kc++) {
            short8v af[4], bfr[4];
            #pragma unroll
            for (int mf = 0; mf < 4; mf++) {
                int row = wr * 64 + mf * 16 + l15;
                int off = (row * 128 + kc * 64 + l4 * 16) ^ ((row & 7) << 4);
                af[mf] = *reinterpret_cast<const short8v*>(asb + off);
            }
            #pragma unroll
            for (int nf = 0; nf < 4; nf++) {
                int row = wc * 64 + nf * 16 + l15;
                int off = (row * 128 + kc * 64 + l4 * 16) ^ ((row & 7) << 4);
                bfr[nf] = *reinterpret_cast<const short8v*>(bsb + off);
            }
            #pragma unroll
            for (int mf = 0; mf < 4; mf++)
                #pragma unroll
                for (int nf = 0; nf < 4; nf++)
                    acc[mf][nf] = __builtin_amdgcn_mfma_f32_16x16x32_bf16(
                        af[mf], bfr[nf], acc[mf][nf], 0, 0, 0);
        }
        __builtin_amdgcn_s_barrier();
    }
    #undef STAGE

    #pragma unroll
    for (int mf = 0; mf < 4; mf++)
        #pragma unroll
        for (int nf = 0; nf < 4; nf++)
            #pragma unroll
            for (int r = 0; r < 4; r++) {
                int m = m0 + wr * 64 + mf * 16 + l4 * 4 + r;
                int n = n0 + wc * 64 + nf * 16 + l15;
                if (n < Nn) {
                    float v = acc[mf][nf][r];
                    if (HAS_BIAS) v += bias[n];
                    if (GELU) {
                        // tanh-form GELU: v * e / (e+1), e = exp2(K*(v + c*v^3))
                        float a = 0.044715f * v * v;
                        float u = fminf(fmaf(a, v, v) * 2.3022077f, 80.f);
                        float e = __builtin_amdgcn_exp2f(u);
                        v = v * e * __builtin_amdgcn_rcpf(e + 1.f);
                    }
                    if (RESID)    v += bf2f(resid[(size_t)m * Nn + n]);
                    if (QSCALE && n < DD) v *= C8;   // Q columns only
                    if (OMODE == 1)
                        ((unsigned short*)Cv)[(size_t)m * Nn + n] = f2bf(v);
                    else
                        ((float*)Cv)[(size_t)m * Nn + n] = v;
                }
            }
}

// ---------------------------------------------------------------------------
// Kernel 4: MFMA flash attention (bf16 qkv in, bf16 o out)
// 512 blocks (16 qtile x 8 head x 4 batch, XCD-swizzled) = 2 blocks/CU;
// 4 waves x 32 q-rows (two q-tiles A/B per wave), 256 threads. Shared K
// b128 reads and V tr-reads serve BOTH q-tiles (halved LDS read traffic)
// while 2 blocks/CU keep barriers covered (R13's 1-block/CU regression).
// KB=128 double-buffered via global_load_lds; swapped QK^T; Q pre-scaled
// by 0.125*log2e; K rows staged kappa-PERMUTED so the QK^T C-frag IS the
// PV A-frag after cvt_pk (no P LDS round-trip).
// ---------------------------------------------------------------------------
__global__ __launch_bounds__(256, 2)
void attn_mfma(const unsigned short* __restrict__ qkv, unsigned short* __restrict__ o)
{
    __shared__ unsigned short Kl[2][128 * 64];  // [row][d] swizzled, 16 KB each
    __shared__ unsigned short Vs[2][128 * 64];  // subtiled, 16 KB each
    __shared__ float Scl[4][2][16];             // per-wave per-qtile broadcast

    int t = threadIdx.x, w = t >> 6, lane = t & 63;   // w in [0,4)
    int l15 = lane & 15, l4 = lane >> 4;

    // XCD-swizzled block decode (512 = 8 XCD * 64)
    int flat = blockIdx.x;
    int swz = (flat & 7) * 64 + (flat >> 3);
    int qt = swz & 15, hh = (swz >> 4) & 7, b = swz >> 7;

    int q0 = qt * 128 + w * 32;
    const int RS = 3 * DD; // 1536

    // Q fragments for both q-tiles (B-operand of swapped QK^T); pre-scaled
    short8v qfA[2], qfB[2];
    #pragma unroll
    for (int dh = 0; dh < 2; dh++) {
        size_t addrA = (size_t)(b * LL + q0 + l15) * RS + hh * HDIM + dh * 32 + l4 * 8;
        qfA[dh] = *reinterpret_cast<const short8v*>(qkv + addrA);
        qfB[dh] = *reinterpret_cast<const short8v*>(qkv + addrA + 16 * RS);
    }

    float4v oA[4], oB[4];
    #pragma unroll
    for (int dt = 0; dt < 4; dt++) {
        oA[dt] = (float4v){0.f, 0.f, 0.f, 0.f};
        oB[dt] = (float4v){0.f, 0.f, 0.f, 0.f};
    }
    float lA = 0.f, lB = 0.f;   // per-lane partial over own keys

    // staging (256 threads): wave w stages K rows [w*16, w*16+16) of each
    // 64-key half (2 instr, kappa(rho+8)=kappa(rho)+16) and V chunks
    // {w*64+lane, +256} per half (chunk c -> vrow+32 at c+256, same seg).
    int lrow8 = lane >> 3;                       // 0..7
    int ksegp = (lane & 7) ^ lrow8;
    int rho0 = w * 16 + lrow8;                   // LDS K-row (i=0 slab)
    int kap0 = ((rho0 >> 5) << 5) | (((rho0 >> 4) & 1) << 2)
             | (((rho0 >> 2) & 3) << 3) | (rho0 & 3);
    int c0 = w * 64 + lane;                      // V chunk (j=0)
    int vr0 = ((c0 >> 5) << 2) | ((c0 >> 1) & 3);
    int vs0 = (((c0 >> 3) & 3) << 1) | (c0 & 1);
    const unsigned short* kgl = qkv + (size_t)(b * LL + kap0) * RS
                              + hh * HDIM + DD + ksegp * 8;
    const unsigned short* vgl = qkv + (size_t)(b * LL + vr0) * RS
                              + hh * HDIM + 2 * DD + vs0 * 8;
    const int step = 128 * RS;

    #define ASTAGE(buf) do {                                                      \
        __builtin_amdgcn_global_load_lds((glb_u32*)kgl,                           \
            (lds_u32*)(Kl[buf] + w * 1024), 16, 0, 0);                            \
        __builtin_amdgcn_global_load_lds((glb_u32*)(kgl + 16 * RS),               \
            (lds_u32*)(Kl[buf] + w * 1024 + 512), 16, 0, 0);                      \
        __builtin_amdgcn_global_load_lds((glb_u32*)(kgl + 64 * RS),               \
            (lds_u32*)(Kl[buf] + 4096 + w * 1024), 16, 0, 0);                     \
        __builtin_amdgcn_global_load_lds((glb_u32*)(kgl + 80 * RS),               \
            (lds_u32*)(Kl[buf] + 4096 + w * 1024 + 512), 16, 0, 0);               \
        __builtin_amdgcn_global_load_lds((glb_u32*)vgl,                           \
            (lds_u32*)(Vs[buf] + w * 512), 16, 0, 0);                             \
        __builtin_amdgcn_global_load_lds((glb_u32*)(vgl + 32 * RS),               \
            (lds_u32*)(Vs[buf] + 2048 + w * 512), 16, 0, 0);                      \
        __builtin_amdgcn_global_load_lds((glb_u32*)(vgl + 64 * RS),               \
            (lds_u32*)(Vs[buf] + 4096 + w * 512), 16, 0, 0);                      \
        __builtin_amdgcn_global_load_lds((glb_u32*)(vgl + 96 * RS),               \
            (lds_u32*)(Vs[buf] + 6144 + w * 512), 16, 0, 0);                      \
        kgl += step; vgl += step; } while (0)

    // per-lane tr-read base (bytes within one Vs 64-key half)
    unsigned vtrbase = lds_addr(Vs) + ((lane >> 4) << 10)
                     + (((lane >> 2) & 3) << 5) + ((lane & 3) << 3);

    // prologue: stage tile 0 into buf 0
    ASTAGE(0);
    asm volatile("s_waitcnt vmcnt(0)");
    __syncthreads();

    for (int kb = 0; kb < LL / 128; kb++) {
        int cur = kb & 1;
        if (kb + 1 < LL / 128) ASTAGE(cur ^ 1);   // async DMA into other buffer

        #pragma unroll
        for (int hf = 0; hf < 2; hf++) {
            const char* klc = (const char*)Kl[cur] + hf * 8192;
            unsigned vb = vtrbase + cur * 16384 + hf * 8192;

            // S^T = K Q^T for both q-tiles; K-frags shared
            float4v sA[4], sB[4];
            __builtin_amdgcn_s_setprio(1);
            #pragma unroll
            for (int nt = 0; nt < 4; nt++) {
                sA[nt] = (float4v){0.f, 0.f, 0.f, 0.f};
                sB[nt] = (float4v){0.f, 0.f, 0.f, 0.f};
                #pragma unroll
                for (int dh = 0; dh < 2; dh++) {
                    int row = nt * 16 + l15;
                    int off = (row * 128 + dh * 64 + l4 * 16) ^ ((row & 7) << 4);
                    short8v kf = *reinterpret_cast<const short8v*>(klc + off);
                    sA[nt] = __builtin_amdgcn_mfma_f32_16x16x32_bf16(kf, qfA[dh], sA[nt], 0, 0, 0);
                    sB[nt] = __builtin_amdgcn_mfma_f32_16x16x32_bf16(kf, qfB[dh], sB[nt], 0, 0, 0);
                }
            }
            __builtin_amdgcn_s_setprio(0);

            // issue all V tr-reads now; latency hides under the exp section
            unsigned long long a0, a1, a2, a3, a4, a5, a6, a7;
            unsigned long long b0, b1, b2, b3, b4, b5, b6, b7;
            unsigned ab0 = vb, ab1 = vb + 4096;
            asm volatile("ds_read_b64_tr_b16 %0, %1" : "=v"(a0) : "v"(ab0));
            asm volatile("ds_read_b64_tr_b16 %0, %1" : "=v"(a1) : "v"(ab0 + 512));
            asm volatile("ds_read_b64_tr_b16 %0, %1" : "=v"(a2) : "v"(ab0 + 128));
            asm volatile("ds_read_b64_tr_b16 %0, %1" : "=v"(a3) : "v"(ab0 + 640));
            asm volatile("ds_read_b64_tr_b16 %0, %1" : "=v"(a4) : "v"(ab0 + 256));
            asm volatile("ds_read_b64_tr_b16 %0, %1" : "=v"(a5) : "v"(ab0 + 768));
            asm volatile("ds_read_b64_tr_b16 %0, %1" : "=v"(a6) : "v"(ab0 + 384));
            asm volatile("ds_read_b64_tr_b16 %0, %1" : "=v"(a7) : "v"(ab0 + 896));
            asm volatile("ds_read_b64_tr_b16 %0, %1" : "=v"(b0) : "v"(ab1));
            asm volatile("ds_read_b64_tr_b16 %0, %1" : "=v"(b1) : "v"(ab1 + 512));
            asm volatile("ds_read_b64_tr_b16 %0, %1" : "=v"(b2) : "v"(ab1 + 128));
            asm volatile("ds_read_b64_tr_b16 %0, %1" : "=v"(b3) : "v"(ab1 + 640));
            asm volatile("ds_read_b64_tr_b16 %0, %1" : "=v"(b4) : "v"(ab1 + 256));
            asm volatile("ds_read_b64_tr_b16 %0, %1" : "=v"(b5) : "v"(ab1 + 768));
            asm volatile("ds_read_b64_tr_b16 %0, %1" : "=v"(b6) : "v"(ab1 + 384));
            asm volatile("ds_read_b64_tr_b16 %0, %1" : "=v"(b7) : "v"(ab1 + 896));

            // P = exp2(s); cvt_pk assembles the PV A-frags directly in-lane.
            union { unsigned u[4]; short8v v; } pf0A, pf1A, pf0B, pf1B;
            {
                float p0 = __builtin_amdgcn_exp2f(sA[0][0]);
                float p1 = __builtin_amdgcn_exp2f(sA[0][1]);
                float p2 = __builtin_amdgcn_exp2f(sA[0][2]);
                float p3 = __builtin_amdgcn_exp2f(sA[0][3]);
                float p4 = __builtin_amdgcn_exp2f(sA[1][0]);
                float p5 = __builtin_amdgcn_exp2f(sA[1][1]);
                float p6 = __builtin_amdgcn_exp2f(sA[1][2]);
                float p7 = __builtin_amdgcn_exp2f(sA[1][3]);
                asm("v_cvt_pk_bf16_f32 %0, %1, %2" : "=v"(pf0A.u[0]) : "v"(p0), "v"(p1));
                asm("v_cvt_pk_bf16_f32 %0, %1, %2" : "=v"(pf0A.u[1]) : "v"(p2), "v"(p3));
                asm("v_cvt_pk_bf16_f32 %0, %1, %2" : "=v"(pf0A.u[2]) : "v"(p4), "v"(p5));
                asm("v_cvt_pk_bf16_f32 %0, %1, %2" : "=v"(pf0A.u[3]) : "v"(p6), "v"(p7));
                float q0_ = __builtin_amdgcn_exp2f(sA[2][0]);
                float q1_ = __builtin_amdgcn_exp2f(sA[2][1]);
                float q2_ = __builtin_amdgcn_exp2f(sA[2][2]);
                float q3_ = __builtin_amdgcn_exp2f(sA[2][3]);
                float q4_ = __builtin_amdgcn_exp2f(sA[3][0]);
                float q5_ = __builtin_amdgcn_exp2f(sA[3][1]);
                float q6_ = __builtin_amdgcn_exp2f(sA[3][2]);
                float q7_ = __builtin_amdgcn_exp2f(sA[3][3]);
                asm("v_cvt_pk_bf16_f32 %0, %1, %2" : "=v"(pf1A.u[0]) : "v"(q0_), "v"(q1_));
                asm("v_cvt_pk_bf16_f32 %0, %1, %2" : "=v"(pf1A.u[1]) : "v"(q2_), "v"(q3_));
                asm("v_cvt_pk_bf16_f32 %0, %1, %2" : "=v"(pf1A.u[2]) : "v"(q4_), "v"(q5_));
                asm("v_cvt_pk_bf16_f32 %0, %1, %2" : "=v"(pf1A.u[3]) : "v"(q6_), "v"(q7_));
                lA += ((p0 + p1) + (p2 + p3)) + ((p4 + p5) + (p6 + p7))
                    + ((q0_ + q1_) + (q2_ + q3_)) + ((q4_ + q5_) + (q6_ + q7_));
            }
            {
                float p0 = __builtin_amdgcn_exp2f(sB[0][0]);
                float p1 = __builtin_amdgcn_exp2f(sB[0][1]);
                float p2 = __builtin_amdgcn_exp2f(sB[0][2]);
                float p3 = __builtin_amdgcn_exp2f(sB[0][3]);
                float p4 = __builtin_amdgcn_exp2f(sB[1][0]);
                float p5 = __builtin_amdgcn_exp2f(sB[1][1]);
                float p6 = __builtin_amdgcn_exp2f(sB[1][2]);
                float p7 = __builtin_amdgcn_exp2f(sB[1][3]);
                asm("v_cvt_pk_bf16_f32 %0, %1, %2" : "=v"(pf0B.u[0]) : "v"(p0), "v"(p1));
                asm("v_cvt_pk_bf16_f32 %0, %1, %2" : "=v"(pf0B.u[1]) : "v"(p2), "v"(p3));
                asm("v_cvt_pk_bf16_f32 %0, %1, %2" : "=v"(pf0B.u[2]) : "v"(p4), "v"(p5));
                asm("v_cvt_pk_bf16_f32 %0, %1, %2" : "=v"(pf0B.u[3]) : "v"(p6), "v"(p7));
                float q0_ = __builtin_amdgcn_exp2f(sB[2][0]);
                float q1_ = __builtin_amdgcn_exp2f(sB[2][1]);
                float q2_ = __builtin_amdgcn_exp2f(sB[2][2]);
                float q3_ = __builtin_amdgcn_exp2f(sB[2][3]);
                float q4_ = __builtin_amdgcn_exp2f(sB[3][0]);
                float q5_ = __builtin_amdgcn_exp2f(sB[3][1]);
                float q6_ = __builtin_amdgcn_exp2f(sB[3][2]);
                float q7_ = __builtin_amdgcn_exp2f(sB[3][3]);
                asm("v_cvt_pk_bf16_f32 %0, %1, %2" : "=v"(pf1B.u[0]) : "v"(q0_), "v"(q1_));
                asm("v_cvt_pk_bf16_f32 %0, %1, %2" : "=v"(pf1B.u[1]) : "v"(q2_), "v"(q3_));
                asm("v_cvt_pk_bf16_f32 %0, %1, %2" : "=v"(pf1B.u[2]) : "v"(q4_), "v"(q5_));
                asm("v_cvt_pk_bf16_f32 %0, %1, %2" : "=v"(pf1B.u[3]) : "v"(q6_), "v"(q7_));
                lB += ((p0 + p1) + (p2 + p3)) + ((p4 + p5) + (p6 + p7))
                    + ((q0_ + q1_) + (q2_ + q3_)) + ((q4_ + q5_) + (q6_ + q7_));
            }

            // O += P V : V-frags shared between both q-tiles
            union { unsigned long long q[2]; short8v v; } u0, u1, u2, u3;
            asm volatile("s_waitcnt lgkmcnt(8)");
            __builtin_amdgcn_sched_barrier(0);
            __builtin_amdgcn_s_setprio(1);
            u0.q[0] = a0; u0.q[1] = a1;
            u1.q[0] = a2; u1.q[1] = a3;
            oA[0] = __builtin_amdgcn_mfma_f32_16x16x32_bf16(pf0A.v, u0.v, oA[0], 0, 0, 0);
            oB[0] = __builtin_amdgcn_mfma_f32_16x16x32_bf16(pf0B.v, u0.v, oB[0], 0, 0, 0);
            oA[1] = __builtin_amdgcn_mfma_f32_16x16x32_bf16(pf0A.v, u1.v, oA[1], 0, 0, 0);
            oB[1] = __builtin_amdgcn_mfma_f32_16x16x32_bf16(pf0B.v, u1.v, oB[1], 0, 0, 0);
            asm volatile("s_waitcnt lgkmcnt(4)");
            __builtin_amdgcn_sched_barrier(0);
            u2.q[0] = a4; u2.q[1] = a5;
            u3.q[0] = a6; u3.q[1] = a7;
            oA[2] = __builtin_amdgcn_mfma_f32_16x16x32_bf16(pf0A.v, u2.v, oA[2], 0, 0, 0);
            oB[2] = __builtin_amdgcn_mfma_f32_16x16x32_bf16(pf0B.v, u2.v, oB[2], 0, 0, 0);
            oA[3] = __builtin_amdgcn_mfma_f32_16x16x32_bf16(pf0A.v, u3.v, oA[3], 0, 0, 0);
            oB[3] = __builtin_amdgcn_mfma_f32_16x16x32_bf16(pf0B.v, u3.v, oB[3], 0, 0, 0);
            asm volatile("s_waitcnt lgkmcnt(0)");
            __builtin_amdgcn_sched_barrier(0);
            u0.q[0] = b0; u0.q[1] = b1;
            u1.q[0] = b2; u1.q[1] = b3;
            u2.q[0] = b4; u2.q[1] = b5;
            u3.q[0] = b6; u3.q[1] = b7;
            oA[0] = __builtin_amdgcn_mfma_f32_16x16x32_bf16(pf1A.v, u0.v, oA[0], 0, 0, 0);
            oB[0] = __builtin_amdgcn_mfma_f32_16x16x32_bf16(pf1B.v, u0.v, oB[0], 0, 0, 0);
            oA[1] = __builtin_amdgcn_mfma_f32_16x16x32_bf16(pf1A.v, u1.v, oA[1], 0, 0, 0);
            oB[1] = __builtin_amdgcn_mfma_f32_16x16x32_bf16(pf1B.v, u1.v, oB[1], 0, 0, 0);
            oA[2] = __builtin_amdgcn_mfma_f32_16x16x32_bf16(pf1A.v, u2.v, oA[2], 0, 0, 0);
            oB[2] = __builtin_amdgcn_mfma_f32_16x16x32_bf16(pf1B.v, u2.v, oB[2], 0, 0, 0);
            oA[3] = __builtin_amdgcn_mfma_f32_16x16x32_bf16(pf1A.v, u3.v, oA[3], 0, 0, 0);
            oB[3] = __builtin_amdgcn_mfma_f32_16x16x32_bf16(pf1B.v, u3.v, oB[3], 0, 0, 0);
            __builtin_amdgcn_s_setprio(0);
        }

        // own DMAs for next tile must land before the barrier releases readers
        asm volatile("s_waitcnt vmcnt(0)");
        __syncthreads();
    }
    #undef ASTAGE

    // epilogue: reduce l across the 4 copies, broadcast 1/l per q-tile
    float ltA = lA, ltB = lB;
    ltA += __shfl_xor(ltA, 16); ltA += __shfl_xor(ltA, 32);
    ltB += __shfl_xor(ltB, 16); ltB += __shfl_xor(ltB, 32);
    if (l4 == 0) { Scl[w][0][l15] = 1.f / ltA; Scl[w][1][l15] = 1.f / ltB; }
    float4 ivA = *reinterpret_cast<const float4*>(&Scl[w][0][l4 * 4]);
    float4 ivB = *reinterpret_cast<const float4*>(&Scl[w][1][l4 * 4]);
    float invA[4] = {ivA.x, ivA.y, ivA.z, ivA.w};
    float invB[4] = {ivB.x, ivB.y, ivB.z, ivB.w};
    #pragma unroll
    for (int r = 0; r < 4; r++) {
        int qgA = q0 + l4 * 4 + r;
        #pragma unroll
        for (int dt = 0; dt < 4; dt++) {
            o[(size_t)(b * LL + qgA) * DD + hh * HDIM + dt * 16 + l15] =
                f2bf(oA[dt][r] * invA[r]);
            o[(size_t)(b * LL + qgA + 16) * DD + hh * HDIM + dt * 16 + l15] =
                f2bf(oB[dt][r] * invB[r]);
        }
    }
}

// ---------------------------------------------------------------------------
// Driver
// ---------------------------------------------------------------------------
extern "C" void kernel_launch(void* const* d_in, const int* in_sizes, int n_in,
                              void* d_out, int out_size, void* d_ws, size_t ws_size,
                              hipStream_t stream)
{
    const float* emb    = (const float*)d_in[0];
    const float* ent_w  = (const float*)d_in[1];
    const float* ent_b  = (const float*)d_in[2];
    const float* qkv_w  = (const float*)d_in[3];
    const float* qkv_b  = (const float*)d_in[4];
    const float* ao_w   = (const float*)d_in[5];
    const float* ao_b   = (const float*)d_in[6];
    const float* ln1_s  = (const float*)d_in[7];
    const float* ln1_b  = (const float*)d_in[8];
    const float* ln2_s  = (const float*)d_in[9];
    const float* ln2_b  = (const float*)d_in[10];
    const float* ff1_w  = (const float*)d_in[11];
    const float* ff1_b  = (const float*)d_in[12];
    const float* ff2_w  = (const float*)d_in[13];
    const float* ff2_b  = (const float*)d_in[14];
    const float* out_w  = (const float*)d_in[15];
    const int*   x      = (const int*)d_in[16];
    // d_in[17] = patch_lengths : dead code in the reference

    float* out = (float*)d_out;

    const int NQW = NLAYER * 3 * DD * DD;
    const int NAW = NLAYER * DD * DD;
    const int NF1 = NLAYER * 4 * DD * DD;
    const int NF2 = NLAYER * DD * 4 * DD;

    char* p = (char*)d_ws;
    unsigned short* wq  = (unsigned short*)p; p += (size_t)NQW * 2;
    unsigned short* wa  = (unsigned short*)p; p += (size_t)NAW * 2;
    unsigned short* w1  = (unsigned short*)p; p += (size_t)NF1 * 2;
    unsigned short* w2  = (unsigned short*)p; p += (size_t)NF2 * 2;
    unsigned short* wob = (unsigned short*)p; p += (size_t)VPAD * DD * 2;
    unsigned short* h   = (unsigned short*)p; p += (size_t)MM * DD * 2;   // bf16 residual
    unsigned short* gb  = (unsigned short*)p; p += (size_t)MM * DD * 2;
    unsigned short* ob  = (unsigned short*)p; p += (size_t)MM * DD * 2;
    unsigned short* bb  = (unsigned short*)p; p += (size_t)MM * 4 * DD * 2; // qkv / ffn

    dim3 blk(256);

    // all weight conversions in one dispatch (wq..wob contiguous)
    cvt_all_kernel<<<E4 / 1024, blk, 0, stream>>>(qkv_w, ao_w, ff1_w, ff2_w, out_w, wq);

    // fused embedding + entropy + LN1(layer 0): writes h (bf16) and gb
    embed_ln_kernel<<<MM / 4, blk, 0, stream>>>(x, emb, ent_w, ent_b,
                                                ln1_s, ln1_b, h, gb);

    for (int layer = 0; layer < NLAYER; layer++) {
        const unsigned short* qw = wq + (size_t)layer * 3 * DD * DD;
        const unsigned short* aw = wa + (size_t)layer * DD * DD;
        const unsigned short* f1 = w1 + (size_t)layer * 4 * DD * DD;
        const unsigned short* f2 = w2 + (size_t)layer * DD * 4 * DD;
        const float* qb  = qkv_b + (size_t)layer * 3 * DD;
        const float* ab  = ao_b  + (size_t)layer * DD;
        const float* l1s = ln1_s + (size_t)layer * DD;
        const float* l1b = ln1_b + (size_t)layer * DD;
        const float* l2s = ln2_s + (size_t)layer * DD;
        const float* l2b = ln2_b + (size_t)layer * DD;
        const float* f1b = ff1_b + (size_t)layer * 4 * DD;
        const float* f2b = ff2_b + (size_t)layer * DD;

        // LN1 (layer 0 fused into embed_ln_kernel)
        if (layer > 0)
            ln_kernel<<<MM / 4, blk, 0, stream>>>(h, l1s, l1b, gb);

        // qkv = gb @ qw^T + qb -> bb (bf16) [MM,1536], Q cols pre-scaled by C8
        {
            dim3 grid((3 * DD) / 128, MM / 128);
            gemm_mfma<true, false, false, true, 1, 128><<<grid, 256, 0, stream>>>(
                gb, qw, qb, nullptr, bb, 3 * DD, DD);
        }

        // attention: bb -> ob (bf16)
        attn_mfma<<<512, 256, 0, stream>>>(bb, ob);

        // h = h + ob @ aw^T + ab  (bf16 out; MT=64 -> 512 blocks)
        {
            dim3 grid(DD / 128, MM / 64);
            gemm_mfma<true, false, true, false, 1, 64><<<grid, 128, 0, stream>>>(
                ob, aw, ab, h, h, DD, DD);
        }

        // LN2: h -> gb
        ln_kernel<<<MM / 4, blk, 0, stream>>>(h, l2s, l2b, gb);

        // ffn1: bb = gelu(gb @ f1^T + f1b) (bf16) [MM,2048]
        {
            dim3 grid((4 * DD) / 128, MM / 128);
            gemm_mfma<true, true, false, false, 1, 128><<<grid, 256, 0, stream>>>(
                gb, f1, f1b, nullptr, bb, 4 * DD, DD);
        }

        // ffn2: h = h + bb @ f2^T + f2b  (bf16 out; MT=64)
        {
            dim3 grid(DD / 128, MM / 64);
            gemm_mfma<true, false, true, false, 1, 64><<<grid, 128, 0, stream>>>(
                bb, f2, f2b, h, h, DD, 4 * DD);
        }
    }

    // logits = h @ wob^T [MM, 258] via MFMA on padded weight (MT=64)
    {
        dim3 grid(VPAD / 128, MM / 64);
        gemm_mfma<false, false, false, false, 0, 64><<<grid, 128, 0, stream>>>(
            h, wob, nullptr, nullptr, out, VV, DD);
    }
}

// Round 15
// 700.892 us; speedup vs baseline: 1.0282x; 1.0175x over previous
//
#include <hip/hip_runtime.h>
#include <hip/hip_bf16.h>
#include <math.h>

// Problem constants
#define BB 4
#define LL 2048
#define DD 512
#define HH 8
#define NLAYER 4
#define VV 258
#define WW 8
#define HDIM 64
#define MM (BB * LL)   // 8192 rows
#define VPAD 384       // logits weight rows padded to tile multiple

// 0.125 * log2(e): QK^T scale, folded into Q at the qkv-GEMM epilogue
#define C8 0.18033688f

typedef __attribute__((ext_vector_type(8))) short short8v;
typedef __attribute__((ext_vector_type(4))) float float4v;

typedef __attribute__((address_space(3))) unsigned int lds_u32;
typedef const __attribute__((address_space(1))) unsigned int glb_u32;

__device__ __forceinline__ unsigned short f2bf(float x) {
    unsigned int u = __float_as_uint(x);
    unsigned int r = (u + 0x7fffu + ((u >> 16) & 1u)) >> 16;
    return (unsigned short)r;
}
__device__ __forceinline__ float bf2f(unsigned short u) {
    return __uint_as_float((unsigned)u << 16);
}

__device__ __forceinline__ unsigned lds_addr(const void* p) {
    return (unsigned)(size_t)(__attribute__((address_space(3))) const void*)p;
}

// ---------------------------------------------------------------------------
// Fused weight conversion: all four layer-weight arrays + padded out_w,
// one dispatch. Output regions are contiguous in ws: wq|wa|w1|w2|wob.
// ---------------------------------------------------------------------------
#define E0 (NLAYER * 3 * DD * DD)          // 3,145,728
#define E1 (E0 + NLAYER * DD * DD)         // 4,194,304
#define E2 (E1 + NLAYER * 4 * DD * DD)     // 8,388,608
#define E3 (E2 + NLAYER * 4 * DD * DD)     // 12,582,912
#define E4 (E3 + VPAD * DD)                // 12,779,520

__global__ __launch_bounds__(256)
void cvt_all_kernel(const float* __restrict__ qkv_w, const float* __restrict__ ao_w,
                    const float* __restrict__ ff1_w, const float* __restrict__ ff2_w,
                    const float* __restrict__ out_w, unsigned short* __restrict__ dst)
{
    int i = (blockIdx.x * 256 + threadIdx.x) * 4;
    float4 v;
    if (i < E0)      v = *reinterpret_cast<const float4*>(qkv_w + i);
    else if (i < E1) v = *reinterpret_cast<const float4*>(ao_w + (i - E0));
    else if (i < E2) v = *reinterpret_cast<const float4*>(ff1_w + (i - E1));
    else if (i < E3) v = *reinterpret_cast<const float4*>(ff2_w + (i - E2));
    else {
        int idx = i - E3;
        if ((idx >> 9) < VV) v = *reinterpret_cast<const float4*>(out_w + idx);
        else                 v = (float4){0.f, 0.f, 0.f, 0.f};
    }
    uint2 pk;
    pk.x = (unsigned)f2bf(v.x) | ((unsigned)f2bf(v.y) << 16);
    pk.y = (unsigned)f2bf(v.z) | ((unsigned)f2bf(v.w) << 16);
    *reinterpret_cast<uint2*>(dst + i) = pk;
}

// ---------------------------------------------------------------------------
// Kernel 1: fused token embedding + entropy feature + LN1(layer 0)
// One wave per row, 4 rows/block. Writes h (bf16 residual) and g (bf16 LN'd).
// Entropy: window x[b,l:l+8] for l <= L-W; values >= 256 contribute nothing.
// ---------------------------------------------------------------------------
__global__ __launch_bounds__(256)
void embed_ln_kernel(const int* __restrict__ x,
                     const float* __restrict__ emb,
                     const float* __restrict__ ent_w,
                     const float* __restrict__ ent_b,
                     const float* __restrict__ ln_s,
                     const float* __restrict__ ln_b,
                     unsigned short* __restrict__ h,
                     unsigned short* __restrict__ g)
{
    int w = threadIdx.x >> 6, lane = threadIdx.x & 63;
    int row = blockIdx.x * 4 + w;
    int b = row / LL, l = row % LL;

    float ent = 0.f;
    if (l <= LL - WW) {
        int win[WW];
        #pragma unroll
        for (int i = 0; i < WW; i++) win[i] = x[b * LL + l + i];
        float s = 0.f;
        #pragma unroll
        for (int i = 0; i < WW; i++) {
            if (win[i] < 256) {
                int c = 0;
                #pragma unroll
                for (int j = 0; j < WW; j++) c += (win[j] == win[i]) ? 1 : 0;
                s += log2f((float)c * 0.125f + 1e-10f);
            }
        }
        ent = -s * 0.125f;
    }

    int tok = x[row];
    const float* erow = emb + (size_t)tok * DD + lane * 8;
    float v[8], ew[8], eb[8];
    *reinterpret_cast<float4*>(v)      = *reinterpret_cast<const float4*>(erow);
    *reinterpret_cast<float4*>(v + 4)  = *reinterpret_cast<const float4*>(erow + 4);
    *reinterpret_cast<float4*>(ew)     = *reinterpret_cast<const float4*>(ent_w + lane * 8);
    *reinterpret_cast<float4*>(ew + 4) = *reinterpret_cast<const float4*>(ent_w + lane * 8 + 4);
    *reinterpret_cast<float4*>(eb)     = *reinterpret_cast<const float4*>(ent_b + lane * 8);
    *reinterpret_cast<float4*>(eb + 4) = *reinterpret_cast<const float4*>(ent_b + lane * 8 + 4);

    float sum = 0.f, sq = 0.f;
    #pragma unroll
    for (int i = 0; i < 8; i++) {
        v[i] = v[i] + ent * ew[i] + eb[i];
        sum += v[i]; sq += v[i] * v[i];
    }
    unsigned int hpk[4];
    #pragma unroll
    for (int i = 0; i < 4; i++)
        hpk[i] = (unsigned)f2bf(v[2*i]) | ((unsigned)f2bf(v[2*i+1]) << 16);
    *reinterpret_cast<uint4*>(h + (size_t)row * DD + lane * 8) =
        *reinterpret_cast<const uint4*>(hpk);

    #pragma unroll
    for (int off = 32; off > 0; off >>= 1) {
        sum += __shfl_xor(sum, off);
        sq  += __shfl_xor(sq, off);
    }
    float mu = sum * (1.f / DD);
    float var = sq * (1.f / DD) - mu * mu;
    float rstd = rsqrtf(var + 1e-5f);

    float s8[8], bi[8];
    *reinterpret_cast<float4*>(s8)     = *reinterpret_cast<const float4*>(ln_s + lane * 8);
    *reinterpret_cast<float4*>(s8 + 4) = *reinterpret_cast<const float4*>(ln_s + lane * 8 + 4);
    *reinterpret_cast<float4*>(bi)     = *reinterpret_cast<const float4*>(ln_b + lane * 8);
    *reinterpret_cast<float4*>(bi + 4) = *reinterpret_cast<const float4*>(ln_b + lane * 8 + 4);

    unsigned int pk[4];
    #pragma unroll
    for (int i = 0; i < 4; i++) {
        unsigned short lo = f2bf((v[2*i]   - mu) * rstd * s8[2*i]   + bi[2*i]);
        unsigned short hi = f2bf((v[2*i+1] - mu) * rstd * s8[2*i+1] + bi[2*i+1]);
        pk[i] = (unsigned)lo | ((unsigned)hi << 16);
    }
    *reinterpret_cast<uint4*>(g + (size_t)row * DD + lane * 8) =
        *reinterpret_cast<const uint4*>(pk);
}

// ---------------------------------------------------------------------------
// Kernel 2: LayerNorm (bf16 in, bf16 out). One wave per row, 4 rows/block.
// ---------------------------------------------------------------------------
__global__ __launch_bounds__(256)
void ln_kernel(const unsigned short* __restrict__ h,
               const float* __restrict__ scale,
               const float* __restrict__ bias,
               unsigned short* __restrict__ g)
{
    int w = threadIdx.x >> 6, lane = threadIdx.x & 63;
    int row = blockIdx.x * 4 + w;

    uint4 raw = *reinterpret_cast<const uint4*>(h + (size_t)row * DD + lane * 8);
    const unsigned* rw = reinterpret_cast<const unsigned*>(&raw);
    float v[8];
    #pragma unroll
    for (int i = 0; i < 4; i++) {
        v[2*i]   = __uint_as_float(rw[i] << 16);
        v[2*i+1] = __uint_as_float(rw[i] & 0xffff0000u);
    }

    float sum = 0.f, sq = 0.f;
    #pragma unroll
    for (int i = 0; i < 8; i++) { sum += v[i]; sq += v[i] * v[i]; }
    #pragma unroll
    for (int off = 32; off > 0; off >>= 1) {
        sum += __shfl_xor(sum, off);
        sq  += __shfl_xor(sq, off);
    }
    float mu = sum * (1.f / DD);
    float var = sq * (1.f / DD) - mu * mu;
    float rstd = rsqrtf(var + 1e-5f);

    float s[8], bi[8];
    *reinterpret_cast<float4*>(s)      = *reinterpret_cast<const float4*>(scale + lane * 8);
    *reinterpret_cast<float4*>(s + 4)  = *reinterpret_cast<const float4*>(scale + lane * 8 + 4);
    *reinterpret_cast<float4*>(bi)     = *reinterpret_cast<const float4*>(bias + lane * 8);
    *reinterpret_cast<float4*>(bi + 4) = *reinterpret_cast<const float4*>(bias + lane * 8 + 4);

    unsigned int pk[4];
    #pragma unroll
    for (int i = 0; i < 4; i++) {
        unsigned short lo = f2bf((v[2*i]   - mu) * rstd * s[2*i]   + bi[2*i]);
        unsigned short hi = f2bf((v[2*i+1] - mu) * rstd * s[2*i+1] + bi[2*i+1]);
        pk[i] = (unsigned)lo | ((unsigned)hi << 16);
    }
    *reinterpret_cast<uint4*>(g + (size_t)row * DD + lane * 8) =
        *reinterpret_cast<const uint4*>(pk);
}

// ---------------------------------------------------------------------------
// Kernel 3: MFMA GEMM  C[M,N] = A[M,K](bf16) * W[N,K]^T(bf16)
// Tile MT x 128 (MT=128: 256 thr / 4 waves; MT=64: 128 thr / 2 waves).
// Double-buffered LDS + global_load_lds with counted vmcnt. Pre-swizzled
// source (seg^row) pairs with read XOR swizzle. Epilogue: +bias, tanh-GELU
// (exp2+rcp form, |err| < 4e-4 vs exact erf), +resid(bf16); QSCALE
// multiplies cols n<DD by C8. OMODE: 0 = f32 out, 1 = bf16 out.
// ---------------------------------------------------------------------------
template<bool HAS_BIAS, bool GELU, bool RESID, bool QSCALE, int OMODE, int MT>
__global__ __launch_bounds__(MT * 2)
void gemm_mfma(const unsigned short* __restrict__ A,
               const unsigned short* __restrict__ W,
               const float* __restrict__ bias,
               const unsigned short* __restrict__ resid,
               void* __restrict__ Cv,
               int Nn, int Kk)
{
    constexpr int NW = MT / 32;          // waves per block (4 or 2)
    constexpr int BLOADS = 512 / MT;     // B-stage loads per thread (4 or 8)
    constexpr int VMN = 4 + BLOADS;      // outstanding loads for one buffer

    __shared__ unsigned short As[2][MT * 64];
    __shared__ unsigned short Bs[2][128 * 64];

    int t = threadIdx.x;
    int w = t >> 6, lane = t & 63;
    int wr = (MT == 128) ? (w >> 1) : 0;
    int wc = (MT == 128) ? (w & 1) : w;
    int l15 = lane & 15, l4 = lane >> 4;
    int m0 = blockIdx.y * MT, n0 = blockIdx.x * 128;

    int lrow = lane >> 3;              // 0..7 : row within the wave's 8-row slab
    int segp = (lane & 7) ^ lrow;      // pre-swizzled 16B-segment for global fetch

    float4v acc[4][4];
    #pragma unroll
    for (int i = 0; i < 4; i++)
        #pragma unroll
        for (int j = 0; j < 4; j++)
            acc[i][j] = (float4v){0.f, 0.f, 0.f, 0.f};

    #define STAGE(buf, k0) do {                                                   \
        _Pragma("unroll")                                                         \
        for (int i_ = 0; i_ < 4; i_++) {                                          \
            int r_ = i_ * (NW * 8) + w * 8 + lrow;                                \
            __builtin_amdgcn_global_load_lds(                                     \
                (glb_u32*)(A + (size_t)(m0 + r_) * Kk + (k0) + segp * 8),         \
                (lds_u32*)(As[buf] + i_ * (NW * 512) + w * 512), 16, 0, 0);       \
        }                                                                         \
        _Pragma("unroll")                                                         \
        for (int i_ = 0; i_ < BLOADS; i_++) {                                     \
            int r_ = i_ * (NW * 8) + w * 8 + lrow;                                \
            __builtin_amdgcn_global_load_lds(                                     \
                (glb_u32*)(W + (size_t)(n0 + r_) * Kk + (k0) + segp * 8),         \
                (lds_u32*)(Bs[buf] + i_ * (NW * 512) + w * 512), 16, 0, 0);       \
        } } while (0)

    int nk = Kk >> 6;
    STAGE(0, 0);
    for (int kt = 0; kt < nk; kt++) {
        int cur = kt & 1;
        if (kt + 1 < nk) {
            STAGE(cur ^ 1, (kt + 1) << 6);
            __builtin_amdgcn_sched_barrier(0);
            if constexpr (VMN == 8)  asm volatile("s_waitcnt vmcnt(8)");
            else                     asm volatile("s_waitcnt vmcnt(12)");
            __builtin_amdgcn_sched_barrier(0);
        } else {
            __builtin_amdgcn_sched_barrier(0);
            asm volatile("s_waitcnt vmcnt(0)");
            __builtin_amdgcn_sched_barrier(0);
        }
        __builtin_amdgcn_s_barrier();

        const char* asb = (const char*)As[cur];
        const char* bsb = (const char*)Bs[cur];
        #pragma unroll
        for (int kc = 0; kc < 2; kc++) {
            short8v af[4], bfr[4];
            #pragma unroll
            for (int mf = 0; mf < 4; mf++) {
                int row = wr * 64 + mf * 16 + l15;
                int off = (row * 128 + kc * 64 + l4 * 16) ^ ((row & 7) << 4);
                af[mf] = *reinterpret_cast<const short8v*>(asb + off);
            }
            #pragma unroll
            for (int nf = 0; nf < 4; nf++) {
                int row = wc * 64 + nf * 16 + l15;
                int off = (row * 128 + kc * 64 + l4 * 16) ^ ((row & 7) << 4);
                bfr[nf] = *reinterpret_cast<const short8v*>(bsb + off);
            }
            #pragma unroll
            for (int mf = 0; mf < 4; mf++)
                #pragma unroll
                for (int nf = 0; nf < 4; nf++)
                    acc[mf][nf] = __builtin_amdgcn_mfma_f32_16x16x32_bf16(
                        af[mf], bfr[nf], acc[mf][nf], 0, 0, 0);
        }
        __builtin_amdgcn_s_barrier();
    }
    #undef STAGE

    #pragma unroll
    for (int mf = 0; mf < 4; mf++)
        #pragma unroll
        for (int nf = 0; nf < 4; nf++)
            #pragma unroll
            for (int r = 0; r < 4; r++) {
                int m = m0 + wr * 64 + mf * 16 + l4 * 4 + r;
                int n = n0 + wc * 64 + nf * 16 + l15;
                if (n < Nn) {
                    float v = acc[mf][nf][r];
                    if (HAS_BIAS) v += bias[n];
                    if (GELU) {
                        // tanh-form GELU: v * e / (e+1), e = exp2(K*(v + c*v^3))
                        float a = 0.044715f * v * v;
                        float u = fminf(fmaf(a, v, v) * 2.3022077f, 80.f);
                        float e = __builtin_amdgcn_exp2f(u);
                        v = v * e * __builtin_amdgcn_rcpf(e + 1.f);
                    }
                    if (RESID)    v += bf2f(resid[(size_t)m * Nn + n]);
                    if (QSCALE && n < DD) v *= C8;   // Q columns only
                    if (OMODE == 1)
                        ((unsigned short*)Cv)[(size_t)m * Nn + n] = f2bf(v);
                    else
                        ((float*)Cv)[(size_t)m * Nn + n] = v;
                }
            }
}

// ---------------------------------------------------------------------------
// Kernel 4: MFMA flash attention (bf16 qkv in, bf16 o out)
// 512 blocks (16 qtile x 8 head x 4 batch, XCD-swizzled); 8 waves x 16 q-rows.
// KB=128 key tiles processed as two 64-key halves sharing ONE stage + vmcnt +
// barrier per 128 keys. K/V double-buffered via global_load_lds. Swapped QK^T
// (S^T = mfma(K,Q)); Q pre-scaled by 0.125*log2e so P = exp2(s); K rows staged
// kappa-PERMUTED so the QK^T C-frag IS the PV A-frag after cvt_pk (no P LDS
// round-trip). PV B-frags via ds_read_b64_tr_b16 issued before exp section.
// [R12 configuration: measured best, 46.5 us/dispatch.]
// ---------------------------------------------------------------------------
__global__ __launch_bounds__(512, 2)
void attn_mfma(const unsigned short* __restrict__ qkv, unsigned short* __restrict__ o)
{
    __shared__ unsigned short Kl[2][128 * 64];  // [row][d] swizzled, 16 KB each
    __shared__ unsigned short Vs[2][128 * 64];  // subtiled, 16 KB each
    __shared__ float Scl[8][16];                // per-wave per-q broadcast slot

    int t = threadIdx.x, w = t >> 6, lane = t & 63;
    int l15 = lane & 15, l4 = lane >> 4;

    // XCD-swizzled block decode (512 = 8 XCD * 64)
    int flat = blockIdx.x;
    int swz = (flat & 7) * 64 + (flat >> 3);
    int qt = swz & 15, hh = (swz >> 4) & 7, b = swz >> 7;

    int q0 = qt * 128 + w * 16;
    const int RS = 3 * DD; // 1536

    // Q fragments (B-operand of swapped QK^T); Q already scaled by C8
    short8v qf[2];
    #pragma unroll
    for (int dh = 0; dh < 2; dh++) {
        size_t addr = (size_t)(b * LL + q0 + l15) * RS + hh * HDIM + dh * 32 + l4 * 8;
        qf[dh] = *reinterpret_cast<const short8v*>(qkv + addr);
    }

    float4v o_acc[4];
    #pragma unroll
    for (int dt = 0; dt < 4; dt++) o_acc[dt] = (float4v){0.f, 0.f, 0.f, 0.f};
    float l_run = 0.f;   // per-lane partial over own keys

    // staging: K rows permuted (LDS row rho holds key kappa(rho)) so that
    // lane (q=l15, l4) ends up holding keys {8*l4+0..7, 32+8*l4+0..7} --
    // exactly the PV A-fragment layout. V staging subtiled (linear dest).
    int lrow8 = lane >> 3;                       // 0..7
    int ksegp = (lane & 7) ^ lrow8;
    int rho = w * 8 + lrow8;                     // LDS K-row this lane fills
    int kappa = ((rho >> 5) << 5) | (((rho >> 4) & 1) << 2)
              | (((rho >> 2) & 3) << 3) | (rho & 3);
    int vrow = ((t >> 5) << 2) | ((t >> 1) & 3);
    int vseg = (((t >> 3) & 3) << 1) | (t & 1);
    const unsigned short* kgl = qkv + (size_t)(b * LL + kappa) * RS
                              + hh * HDIM + DD + ksegp * 8;
    const unsigned short* vgl = qkv + (size_t)(b * LL + vrow) * RS
                              + hh * HDIM + 2 * DD + vseg * 8;
    const int halfstep = 64 * RS;   // +64 keys (second half of the 128-tile)
    const int step = 128 * RS;

    #define ASTAGE(buf) do {                                                      \
        __builtin_amdgcn_global_load_lds((glb_u32*)kgl,                           \
            (lds_u32*)(Kl[buf] + w * 512), 16, 0, 0);                             \
        __builtin_amdgcn_global_load_lds((glb_u32*)(kgl + halfstep),              \
            (lds_u32*)(Kl[buf] + 4096 + w * 512), 16, 0, 0);                      \
        __builtin_amdgcn_global_load_lds((glb_u32*)vgl,                           \
            (lds_u32*)(Vs[buf] + w * 512), 16, 0, 0);                             \
        __builtin_amdgcn_global_load_lds((glb_u32*)(vgl + halfstep),              \
            (lds_u32*)(Vs[buf] + 4096 + w * 512), 16, 0, 0);                      \
        kgl += step; vgl += step; } while (0)

    // per-lane tr-read base (bytes within one Vs 64-key half)
    unsigned vtrbase = lds_addr(Vs) + ((lane >> 4) << 10)
                     + (((lane >> 2) & 3) << 5) + ((lane & 3) << 3);

    // prologue: stage tile 0 into buf 0
    ASTAGE(0);
    asm volatile("s_waitcnt vmcnt(0)");
    __syncthreads();

    for (int kb = 0; kb < LL / 128; kb++) {
        int cur = kb & 1;
        if (kb + 1 < LL / 128) ASTAGE(cur ^ 1);   // async DMA into other buffer

        #pragma unroll
        for (int hf = 0; hf < 2; hf++) {
            const char* klc = (const char*)Kl[cur] + hf * 8192;
            unsigned vb = vtrbase + cur * 16384 + hf * 8192;

            // S^T = K Q^T : lane (q=l15,l4) gets scores for permuted keys
            float4v s_acc[4];
            __builtin_amdgcn_s_setprio(1);
            #pragma unroll
            for (int nt = 0; nt < 4; nt++) {
                s_acc[nt] = (float4v){0.f, 0.f, 0.f, 0.f};
                #pragma unroll
                for (int dh = 0; dh < 2; dh++) {
                    int row = nt * 16 + l15;
                    int off = (row * 128 + dh * 64 + l4 * 16) ^ ((row & 7) << 4);
                    short8v kf = *reinterpret_cast<const short8v*>(klc + off);
                    s_acc[nt] = __builtin_amdgcn_mfma_f32_16x16x32_bf16(kf, qf[dh], s_acc[nt], 0, 0, 0);
                }
            }
            __builtin_amdgcn_s_setprio(0);

            // issue all V tr-reads now; latency hides under the exp section
            unsigned long long a0, a1, a2, a3, a4, a5, a6, a7;
            unsigned long long b0, b1, b2, b3, b4, b5, b6, b7;
            unsigned ab0 = vb, ab1 = vb + 4096;
            asm volatile("ds_read_b64_tr_b16 %0, %1" : "=v"(a0) : "v"(ab0));
            asm volatile("ds_read_b64_tr_b16 %0, %1" : "=v"(a1) : "v"(ab0 + 512));
            asm volatile("ds_read_b64_tr_b16 %0, %1" : "=v"(a2) : "v"(ab0 + 128));
            asm volatile("ds_read_b64_tr_b16 %0, %1" : "=v"(a3) : "v"(ab0 + 640));
            asm volatile("ds_read_b64_tr_b16 %0, %1" : "=v"(a4) : "v"(ab0 + 256));
            asm volatile("ds_read_b64_tr_b16 %0, %1" : "=v"(a5) : "v"(ab0 + 768));
            asm volatile("ds_read_b64_tr_b16 %0, %1" : "=v"(a6) : "v"(ab0 + 384));
            asm volatile("ds_read_b64_tr_b16 %0, %1" : "=v"(a7) : "v"(ab0 + 896));
            asm volatile("ds_read_b64_tr_b16 %0, %1" : "=v"(b0) : "v"(ab1));
            asm volatile("ds_read_b64_tr_b16 %0, %1" : "=v"(b1) : "v"(ab1 + 512));
            asm volatile("ds_read_b64_tr_b16 %0, %1" : "=v"(b2) : "v"(ab1 + 128));
            asm volatile("ds_read_b64_tr_b16 %0, %1" : "=v"(b3) : "v"(ab1 + 640));
            asm volatile("ds_read_b64_tr_b16 %0, %1" : "=v"(b4) : "v"(ab1 + 256));
            asm volatile("ds_read_b64_tr_b16 %0, %1" : "=v"(b5) : "v"(ab1 + 768));
            asm volatile("ds_read_b64_tr_b16 %0, %1" : "=v"(b6) : "v"(ab1 + 384));
            asm volatile("ds_read_b64_tr_b16 %0, %1" : "=v"(b7) : "v"(ab1 + 896));

            // P = exp2(s); cvt_pk assembles the PV A-frags directly in-lane.
            union { unsigned u[4]; short8v v; } pf0u, pf1u;
            float ps;
            {
                float p0 = __builtin_amdgcn_exp2f(s_acc[0][0]);
                float p1 = __builtin_amdgcn_exp2f(s_acc[0][1]);
                float p2 = __builtin_amdgcn_exp2f(s_acc[0][2]);
                float p3 = __builtin_amdgcn_exp2f(s_acc[0][3]);
                float p4 = __builtin_amdgcn_exp2f(s_acc[1][0]);
                float p5 = __builtin_amdgcn_exp2f(s_acc[1][1]);
                float p6 = __builtin_amdgcn_exp2f(s_acc[1][2]);
                float p7 = __builtin_amdgcn_exp2f(s_acc[1][3]);
                asm("v_cvt_pk_bf16_f32 %0, %1, %2" : "=v"(pf0u.u[0]) : "v"(p0), "v"(p1));
                asm("v_cvt_pk_bf16_f32 %0, %1, %2" : "=v"(pf0u.u[1]) : "v"(p2), "v"(p3));
                asm("v_cvt_pk_bf16_f32 %0, %1, %2" : "=v"(pf0u.u[2]) : "v"(p4), "v"(p5));
                asm("v_cvt_pk_bf16_f32 %0, %1, %2" : "=v"(pf0u.u[3]) : "v"(p6), "v"(p7));
                ps = ((p0 + p1) + (p2 + p3)) + ((p4 + p5) + (p6 + p7));
            }
            {
                float p0 = __builtin_amdgcn_exp2f(s_acc[2][0]);
                float p1 = __builtin_amdgcn_exp2f(s_acc[2][1]);
                float p2 = __builtin_amdgcn_exp2f(s_acc[2][2]);
                float p3 = __builtin_amdgcn_exp2f(s_acc[2][3]);
                float p4 = __builtin_amdgcn_exp2f(s_acc[3][0]);
                float p5 = __builtin_amdgcn_exp2f(s_acc[3][1]);
                float p6 = __builtin_amdgcn_exp2f(s_acc[3][2]);
                float p7 = __builtin_amdgcn_exp2f(s_acc[3][3]);
                asm("v_cvt_pk_bf16_f32 %0, %1, %2" : "=v"(pf1u.u[0]) : "v"(p0), "v"(p1));
                asm("v_cvt_pk_bf16_f32 %0, %1, %2" : "=v"(pf1u.u[1]) : "v"(p2), "v"(p3));
                asm("v_cvt_pk_bf16_f32 %0, %1, %2" : "=v"(pf1u.u[2]) : "v"(p4), "v"(p5));
                asm("v_cvt_pk_bf16_f32 %0, %1, %2" : "=v"(pf1u.u[3]) : "v"(p6), "v"(p7));
                ps += ((p0 + p1) + (p2 + p3)) + ((p4 + p5) + (p6 + p7));
            }
            l_run += ps;

            // O += P V
            union { unsigned long long q[2]; short8v v; } u0, u1, u2, u3;
            asm volatile("s_waitcnt lgkmcnt(8)");
            __builtin_amdgcn_sched_barrier(0);
            __builtin_amdgcn_s_setprio(1);
            u0.q[0] = a0; u0.q[1] = a1;
            u1.q[0] = a2; u1.q[1] = a3;
            o_acc[0] = __builtin_amdgcn_mfma_f32_16x16x32_bf16(pf0u.v, u0.v, o_acc[0], 0, 0, 0);
            o_acc[1] = __builtin_amdgcn_mfma_f32_16x16x32_bf16(pf0u.v, u1.v, o_acc[1], 0, 0, 0);
            asm volatile("s_waitcnt lgkmcnt(4)");
            __builtin_amdgcn_sched_barrier(0);
            u2.q[0] = a4; u2.q[1] = a5;
            u3.q[0] = a6; u3.q[1] = a7;
            o_acc[2] = __builtin_amdgcn_mfma_f32_16x16x32_bf16(pf0u.v, u2.v, o_acc[2], 0, 0, 0);
            o_acc[3] = __builtin_amdgcn_mfma_f32_16x16x32_bf16(pf0u.v, u3.v, o_acc[3], 0, 0, 0);
            asm volatile("s_waitcnt lgkmcnt(0)");
            __builtin_amdgcn_sched_barrier(0);
            u0.q[0] = b0; u0.q[1] = b1;
            u1.q[0] = b2; u1.q[1] = b3;
            u2.q[0] = b4; u2.q[1] = b5;
            u3.q[0] = b6; u3.q[1] = b7;
            o_acc[0] = __builtin_amdgcn_mfma_f32_16x16x32_bf16(pf1u.v, u0.v, o_acc[0], 0, 0, 0);
            o_acc[1] = __builtin_amdgcn_mfma_f32_16x16x32_bf16(pf1u.v, u1.v, o_acc[1], 0, 0, 0);
            o_acc[2] = __builtin_amdgcn_mfma_f32_16x16x32_bf16(pf1u.v, u2.v, o_acc[2], 0, 0, 0);
            o_acc[3] = __builtin_amdgcn_mfma_f32_16x16x32_bf16(pf1u.v, u3.v, o_acc[3], 0, 0, 0);
            __builtin_amdgcn_s_setprio(0);
        }

        // own DMAs for next tile must land before the barrier releases readers
        asm volatile("s_waitcnt vmcnt(0)");
        __syncthreads();
    }
    #undef ASTAGE

    // epilogue: reduce l across the 4 copies, broadcast 1/l into o_acc domain
    float lt = l_run;
    lt += __shfl_xor(lt, 16);
    lt += __shfl_xor(lt, 32);
    if (l4 == 0) Scl[w][l15] = 1.f / lt;
    float4 iv = *reinterpret_cast<const float4*>(&Scl[w][l4 * 4]);
    float invs[4] = {iv.x, iv.y, iv.z, iv.w};
    #pragma unroll
    for (int r = 0; r < 4; r++) {
        int qg = q0 + l4 * 4 + r;
        #pragma unroll
        for (int dt = 0; dt < 4; dt++) {
            o[(size_t)(b * LL + qg) * DD + hh * HDIM + dt * 16 + l15] =
                f2bf(o_acc[dt][r] * invs[r]);
        }
    }
}

// ---------------------------------------------------------------------------
// Driver
// ---------------------------------------------------------------------------
extern "C" void kernel_launch(void* const* d_in, const int* in_sizes, int n_in,
                              void* d_out, int out_size, void* d_ws, size_t ws_size,
                              hipStream_t stream)
{
    const float* emb    = (const float*)d_in[0];
    const float* ent_w  = (const float*)d_in[1];
    const float* ent_b  = (const float*)d_in[2];
    const float* qkv_w  = (const float*)d_in[3];
    const float* qkv_b  = (const float*)d_in[4];
    const float* ao_w   = (const float*)d_in[5];
    const float* ao_b   = (const float*)d_in[6];
    const float* ln1_s  = (const float*)d_in[7];
    const float* ln1_b  = (const float*)d_in[8];
    const float* ln2_s  = (const float*)d_in[9];
    const float* ln2_b  = (const float*)d_in[10];
    const float* ff1_w  = (const float*)d_in[11];
    const float* ff1_b  = (const float*)d_in[12];
    const float* ff2_w  = (const float*)d_in[13];
    const float* ff2_b  = (const float*)d_in[14];
    const float* out_w  = (const float*)d_in[15];
    const int*   x      = (const int*)d_in[16];
    // d_in[17] = patch_lengths : dead code in the reference

    float* out = (float*)d_out;

    const int NQW = NLAYER * 3 * DD * DD;
    const int NAW = NLAYER * DD * DD;
    const int NF1 = NLAYER * 4 * DD * DD;
    const int NF2 = NLAYER * DD * 4 * DD;

    char* p = (char*)d_ws;
    unsigned short* wq  = (unsigned short*)p; p += (size_t)NQW * 2;
    unsigned short* wa  = (unsigned short*)p; p += (size_t)NAW * 2;
    unsigned short* w1  = (unsigned short*)p; p += (size_t)NF1 * 2;
    unsigned short* w2  = (unsigned short*)p; p += (size_t)NF2 * 2;
    unsigned short* wob = (unsigned short*)p; p += (size_t)VPAD * DD * 2;
    unsigned short* h   = (unsigned short*)p; p += (size_t)MM * DD * 2;   // bf16 residual
    unsigned short* gb  = (unsigned short*)p; p += (size_t)MM * DD * 2;
    unsigned short* ob  = (unsigned short*)p; p += (size_t)MM * DD * 2;
    unsigned short* bb  = (unsigned short*)p; p += (size_t)MM * 4 * DD * 2; // qkv / ffn

    dim3 blk(256);

    // all weight conversions in one dispatch (wq..wob contiguous)
    cvt_all_kernel<<<E4 / 1024, blk, 0, stream>>>(qkv_w, ao_w, ff1_w, ff2_w, out_w, wq);

    // fused embedding + entropy + LN1(layer 0): writes h (bf16) and gb
    embed_ln_kernel<<<MM / 4, blk, 0, stream>>>(x, emb, ent_w, ent_b,
                                                ln1_s, ln1_b, h, gb);

    for (int layer = 0; layer < NLAYER; layer++) {
        const unsigned short* qw = wq + (size_t)layer * 3 * DD * DD;
        const unsigned short* aw = wa + (size_t)layer * DD * DD;
        const unsigned short* f1 = w1 + (size_t)layer * 4 * DD * DD;
        const unsigned short* f2 = w2 + (size_t)layer * DD * 4 * DD;
        const float* qb  = qkv_b + (size_t)layer * 3 * DD;
        const float* ab  = ao_b  + (size_t)layer * DD;
        const float* l1s = ln1_s + (size_t)layer * DD;
        const float* l1b = ln1_b + (size_t)layer * DD;
        const float* l2s = ln2_s + (size_t)layer * DD;
        const float* l2b = ln2_b + (size_t)layer * DD;
        const float* f1b = ff1_b + (size_t)layer * 4 * DD;
        const float* f2b = ff2_b + (size_t)layer * DD;

        // LN1 (layer 0 fused into embed_ln_kernel)
        if (layer > 0)
            ln_kernel<<<MM / 4, blk, 0, stream>>>(h, l1s, l1b, gb);

        // qkv = gb @ qw^T + qb -> bb (bf16) [MM,1536], Q cols pre-scaled by C8
        {
            dim3 grid((3 * DD) / 128, MM / 128);
            gemm_mfma<true, false, false, true, 1, 128><<<grid, 256, 0, stream>>>(
                gb, qw, qb, nullptr, bb, 3 * DD, DD);
        }

        // attention: bb -> ob (bf16)
        attn_mfma<<<512, 512, 0, stream>>>(bb, ob);

        // h = h + ob @ aw^T + ab  (bf16 out; MT=64 -> 512 blocks)
        {
            dim3 grid(DD / 128, MM / 64);
            gemm_mfma<true, false, true, false, 1, 64><<<grid, 128, 0, stream>>>(
                ob, aw, ab, h, h, DD, DD);
        }

        // LN2: h -> gb
        ln_kernel<<<MM / 4, blk, 0, stream>>>(h, l2s, l2b, gb);

        // ffn1: bb = gelu(gb @ f1^T + f1b) (bf16) [MM,2048]
        {
            dim3 grid((4 * DD) / 128, MM / 128);
            gemm_mfma<true, true, false, false, 1, 128><<<grid, 256, 0, stream>>>(
                gb, f1, f1b, nullptr, bb, 4 * DD, DD);
        }

        // ffn2: h = h + bb @ f2^T + f2b  (bf16 out; MT=64)
        {
            dim3 grid(DD / 128, MM / 64);
            gemm_mfma<true, false, true, false, 1, 64><<<grid, 128, 0, stream>>>(
                bb, f2, f2b, h, h, DD, 4 * DD);
        }
    }

    // logits = h @ wob^T [MM, 258] via MFMA on padded weight (MT=64)
    {
        dim3 grid(VPAD / 128, MM / 64);
        gemm_mfma<false, false, false, false, 0, 64><<<grid, 128, 0, stream>>>(
            h, wob, nullptr, nullptr, out, VV, DD);
    }
}

// Round 17
// 673.812 us; speedup vs baseline: 1.0695x; 1.0402x over previous
//
#include <hip/hip_runtime.h>
#include <hip/hip_bf16.h>
#include <math.h>

// Problem constants
#define BB 4
#define LL 2048
#define DD 512
#define HH 8
#define NLAYER 4
#define VV 258
#define WW 8
#define HDIM 64
#define MM (BB * LL)   // 8192 rows
#define VPAD 384       // logits weight rows padded to tile multiple

// 0.125 * log2(e): QK^T scale, folded into Q at the qkv-GEMM epilogue
#define C8 0.18033688f

typedef __attribute__((ext_vector_type(8))) short short8v;
typedef __attribute__((ext_vector_type(4))) float float4v;

typedef __attribute__((address_space(3))) unsigned int lds_u32;
typedef const __attribute__((address_space(1))) unsigned int glb_u32;

__device__ __forceinline__ unsigned short f2bf(float x) {
    unsigned int u = __float_as_uint(x);
    unsigned int r = (u + 0x7fffu + ((u >> 16) & 1u)) >> 16;
    return (unsigned short)r;
}
__device__ __forceinline__ float bf2f(unsigned short u) {
    return __uint_as_float((unsigned)u << 16);
}

__device__ __forceinline__ unsigned lds_addr(const void* p) {
    return (unsigned)(size_t)(__attribute__((address_space(3))) const void*)p;
}

__device__ __forceinline__ float gelu_tanh(float v) {
    float a = 0.044715f * v * v;
    float u = fminf(fmaf(a, v, v) * 2.3022077f, 80.f);
    float e = __builtin_amdgcn_exp2f(u);
    return v * e * __builtin_amdgcn_rcpf(e + 1.f);
}

// ---------------------------------------------------------------------------
// Fused weight conversion: all four layer-weight arrays + padded out_w.
// ---------------------------------------------------------------------------
#define E0 (NLAYER * 3 * DD * DD)          // 3,145,728
#define E1 (E0 + NLAYER * DD * DD)         // 4,194,304
#define E2 (E1 + NLAYER * 4 * DD * DD)     // 8,388,608
#define E3 (E2 + NLAYER * 4 * DD * DD)     // 12,582,912
#define E4 (E3 + VPAD * DD)                // 12,779,520

__global__ __launch_bounds__(256)
void cvt_all_kernel(const float* __restrict__ qkv_w, const float* __restrict__ ao_w,
                    const float* __restrict__ ff1_w, const float* __restrict__ ff2_w,
                    const float* __restrict__ out_w, unsigned short* __restrict__ dst)
{
    int i = (blockIdx.x * 256 + threadIdx.x) * 4;
    float4 v;
    if (i < E0)      v = *reinterpret_cast<const float4*>(qkv_w + i);
    else if (i < E1) v = *reinterpret_cast<const float4*>(ao_w + (i - E0));
    else if (i < E2) v = *reinterpret_cast<const float4*>(ff1_w + (i - E1));
    else if (i < E3) v = *reinterpret_cast<const float4*>(ff2_w + (i - E2));
    else {
        int idx = i - E3;
        if ((idx >> 9) < VV) v = *reinterpret_cast<const float4*>(out_w + idx);
        else                 v = (float4){0.f, 0.f, 0.f, 0.f};
    }
    uint2 pk;
    pk.x = (unsigned)f2bf(v.x) | ((unsigned)f2bf(v.y) << 16);
    pk.y = (unsigned)f2bf(v.z) | ((unsigned)f2bf(v.w) << 16);
    *reinterpret_cast<uint2*>(dst + i) = pk;
}

// ---------------------------------------------------------------------------
// Kernel 1: fused token embedding + entropy feature + LN1(layer 0)
// ---------------------------------------------------------------------------
__global__ __launch_bounds__(256)
void embed_ln_kernel(const int* __restrict__ x,
                     const float* __restrict__ emb,
                     const float* __restrict__ ent_w,
                     const float* __restrict__ ent_b,
                     const float* __restrict__ ln_s,
                     const float* __restrict__ ln_b,
                     unsigned short* __restrict__ h,
                     unsigned short* __restrict__ g)
{
    int w = threadIdx.x >> 6, lane = threadIdx.x & 63;
    int row = blockIdx.x * 4 + w;
    int b = row / LL, l = row % LL;

    float ent = 0.f;
    if (l <= LL - WW) {
        int win[WW];
        #pragma unroll
        for (int i = 0; i < WW; i++) win[i] = x[b * LL + l + i];
        float s = 0.f;
        #pragma unroll
        for (int i = 0; i < WW; i++) {
            if (win[i] < 256) {
                int c = 0;
                #pragma unroll
                for (int j = 0; j < WW; j++) c += (win[j] == win[i]) ? 1 : 0;
                s += log2f((float)c * 0.125f + 1e-10f);
            }
        }
        ent = -s * 0.125f;
    }

    int tok = x[row];
    const float* erow = emb + (size_t)tok * DD + lane * 8;
    float v[8], ew[8], eb[8];
    *reinterpret_cast<float4*>(v)      = *reinterpret_cast<const float4*>(erow);
    *reinterpret_cast<float4*>(v + 4)  = *reinterpret_cast<const float4*>(erow + 4);
    *reinterpret_cast<float4*>(ew)     = *reinterpret_cast<const float4*>(ent_w + lane * 8);
    *reinterpret_cast<float4*>(ew + 4) = *reinterpret_cast<const float4*>(ent_w + lane * 8 + 4);
    *reinterpret_cast<float4*>(eb)     = *reinterpret_cast<const float4*>(ent_b + lane * 8);
    *reinterpret_cast<float4*>(eb + 4) = *reinterpret_cast<const float4*>(ent_b + lane * 8 + 4);

    float sum = 0.f, sq = 0.f;
    #pragma unroll
    for (int i = 0; i < 8; i++) {
        v[i] = v[i] + ent * ew[i] + eb[i];
        sum += v[i]; sq += v[i] * v[i];
    }
    unsigned int hpk[4];
    #pragma unroll
    for (int i = 0; i < 4; i++)
        hpk[i] = (unsigned)f2bf(v[2*i]) | ((unsigned)f2bf(v[2*i+1]) << 16);
    *reinterpret_cast<uint4*>(h + (size_t)row * DD + lane * 8) =
        *reinterpret_cast<const uint4*>(hpk);

    #pragma unroll
    for (int off = 32; off > 0; off >>= 1) {
        sum += __shfl_xor(sum, off);
        sq  += __shfl_xor(sq, off);
    }
    float mu = sum * (1.f / DD);
    float var = sq * (1.f / DD) - mu * mu;
    float rstd = rsqrtf(var + 1e-5f);

    float s8[8], bi[8];
    *reinterpret_cast<float4*>(s8)     = *reinterpret_cast<const float4*>(ln_s + lane * 8);
    *reinterpret_cast<float4*>(s8 + 4) = *reinterpret_cast<const float4*>(ln_s + lane * 8 + 4);
    *reinterpret_cast<float4*>(bi)     = *reinterpret_cast<const float4*>(ln_b + lane * 8);
    *reinterpret_cast<float4*>(bi + 4) = *reinterpret_cast<const float4*>(ln_b + lane * 8 + 4);

    unsigned int pk[4];
    #pragma unroll
    for (int i = 0; i < 4; i++) {
        unsigned short lo = f2bf((v[2*i]   - mu) * rstd * s8[2*i]   + bi[2*i]);
        unsigned short hi = f2bf((v[2*i+1] - mu) * rstd * s8[2*i+1] + bi[2*i+1]);
        pk[i] = (unsigned)lo | ((unsigned)hi << 16);
    }
    *reinterpret_cast<uint4*>(g + (size_t)row * DD + lane * 8) =
        *reinterpret_cast<const uint4*>(pk);
}

// ---------------------------------------------------------------------------
// Kernel 2: LayerNorm (bf16 in, bf16 out). One wave per row, 4 rows/block.
// ---------------------------------------------------------------------------
__global__ __launch_bounds__(256)
void ln_kernel(const unsigned short* __restrict__ h,
               const float* __restrict__ scale,
               const float* __restrict__ bias,
               unsigned short* __restrict__ g)
{
    int w = threadIdx.x >> 6, lane = threadIdx.x & 63;
    int row = blockIdx.x * 4 + w;

    uint4 raw = *reinterpret_cast<const uint4*>(h + (size_t)row * DD + lane * 8);
    const unsigned* rw = reinterpret_cast<const unsigned*>(&raw);
    float v[8];
    #pragma unroll
    for (int i = 0; i < 4; i++) {
        v[2*i]   = __uint_as_float(rw[i] << 16);
        v[2*i+1] = __uint_as_float(rw[i] & 0xffff0000u);
    }

    float sum = 0.f, sq = 0.f;
    #pragma unroll
    for (int i = 0; i < 8; i++) { sum += v[i]; sq += v[i] * v[i]; }
    #pragma unroll
    for (int off = 32; off > 0; off >>= 1) {
        sum += __shfl_xor(sum, off);
        sq  += __shfl_xor(sq, off);
    }
    float mu = sum * (1.f / DD);
    float var = sq * (1.f / DD) - mu * mu;
    float rstd = rsqrtf(var + 1e-5f);

    float s[8], bi[8];
    *reinterpret_cast<float4*>(s)      = *reinterpret_cast<const float4*>(scale + lane * 8);
    *reinterpret_cast<float4*>(s + 4)  = *reinterpret_cast<const float4*>(scale + lane * 8 + 4);
    *reinterpret_cast<float4*>(bi)     = *reinterpret_cast<const float4*>(bias + lane * 8);
    *reinterpret_cast<float4*>(bi + 4) = *reinterpret_cast<const float4*>(bias + lane * 8 + 4);

    unsigned int pk[4];
    #pragma unroll
    for (int i = 0; i < 4; i++) {
        unsigned short lo = f2bf((v[2*i]   - mu) * rstd * s[2*i]   + bi[2*i]);
        unsigned short hi = f2bf((v[2*i+1] - mu) * rstd * s[2*i+1] + bi[2*i+1]);
        pk[i] = (unsigned)lo | ((unsigned)hi << 16);
    }
    *reinterpret_cast<uint4*>(g + (size_t)row * DD + lane * 8) =
        *reinterpret_cast<const uint4*>(pk);
}

// ---------------------------------------------------------------------------
// Kernel 3: MFMA GEMM (2-phase) C[M,N] = A[M,K](bf16) * W[N,K]^T(bf16)
// [unchanged champion path: qkv / ao / ffn2 / logits]
// ---------------------------------------------------------------------------
template<bool HAS_BIAS, bool GELU, bool RESID, bool QSCALE, int OMODE, int MT>
__global__ __launch_bounds__(MT * 2)
void gemm_mfma(const unsigned short* __restrict__ A,
               const unsigned short* __restrict__ W,
               const float* __restrict__ bias,
               const unsigned short* __restrict__ resid,
               void* __restrict__ Cv,
               int Nn, int Kk)
{
    constexpr int NW = MT / 32;          // waves per block (4 or 2)
    constexpr int BLOADS = 512 / MT;     // B-stage loads per thread (4 or 8)
    constexpr int VMN = 4 + BLOADS;      // outstanding loads for one buffer

    __shared__ unsigned short As[2][MT * 64];
    __shared__ unsigned short Bs[2][128 * 64];

    int t = threadIdx.x;
    int w = t >> 6, lane = t & 63;
    int wr = (MT == 128) ? (w >> 1) : 0;
    int wc = (MT == 128) ? (w & 1) : w;
    int l15 = lane & 15, l4 = lane >> 4;
    int m0 = blockIdx.y * MT, n0 = blockIdx.x * 128;

    int lrow = lane >> 3;              // 0..7 : row within the wave's 8-row slab
    int segp = (lane & 7) ^ lrow;      // pre-swizzled 16B-segment for global fetch

    float4v acc[4][4];
    #pragma unroll
    for (int i = 0; i < 4; i++)
        #pragma unroll
        for (int j = 0; j < 4; j++)
            acc[i][j] = (float4v){0.f, 0.f, 0.f, 0.f};

    #define STAGE(buf, k0) do {                                                   \
        _Pragma("unroll")                                                         \
        for (int i_ = 0; i_ < 4; i_++) {                                          \
            int r_ = i_ * (NW * 8) + w * 8 + lrow;                                \
            __builtin_amdgcn_global_load_lds(                                     \
                (glb_u32*)(A + (size_t)(m0 + r_) * Kk + (k0) + segp * 8),         \
                (lds_u32*)(As[buf] + i_ * (NW * 512) + w * 512), 16, 0, 0);       \
        }                                                                         \
        _Pragma("unroll")                                                         \
        for (int i_ = 0; i_ < BLOADS; i_++) {                                     \
            int r_ = i_ * (NW * 8) + w * 8 + lrow;                                \
            __builtin_amdgcn_global_load_lds(                                     \
                (glb_u32*)(W + (size_t)(n0 + r_) * Kk + (k0) + segp * 8),         \
                (lds_u32*)(Bs[buf] + i_ * (NW * 512) + w * 512), 16, 0, 0);       \
        } } while (0)

    int nk = Kk >> 6;
    STAGE(0, 0);
    for (int kt = 0; kt < nk; kt++) {
        int cur = kt & 1;
        if (kt + 1 < nk) {
            STAGE(cur ^ 1, (kt + 1) << 6);
            __builtin_amdgcn_sched_barrier(0);
            if constexpr (VMN == 8)  asm volatile("s_waitcnt vmcnt(8)");
            else                     asm volatile("s_waitcnt vmcnt(12)");
            __builtin_amdgcn_sched_barrier(0);
        } else {
            __builtin_amdgcn_sched_barrier(0);
            asm volatile("s_waitcnt vmcnt(0)");
            __builtin_amdgcn_sched_barrier(0);
        }
        __builtin_amdgcn_s_barrier();

        const char* asb = (const char*)As[cur];
        const char* bsb = (const char*)Bs[cur];
        #pragma unroll
        for (int kc = 0; kc < 2; kc++) {
            short8v af[4], bfr[4];
            #pragma unroll
            for (int mf = 0; mf < 4; mf++) {
                int row = wr * 64 + mf * 16 + l15;
                int off = (row * 128 + kc * 64 + l4 * 16) ^ ((row & 7) << 4);
                af[mf] = *reinterpret_cast<const short8v*>(asb + off);
            }
            #pragma unroll
            for (int nf = 0; nf < 4; nf++) {
                int row = wc * 64 + nf * 16 + l15;
                int off = (row * 128 + kc * 64 + l4 * 16) ^ ((row & 7) << 4);
                bfr[nf] = *reinterpret_cast<const short8v*>(bsb + off);
            }
            #pragma unroll
            for (int mf = 0; mf < 4; mf++)
                #pragma unroll
                for (int nf = 0; nf < 4; nf++)
                    acc[mf][nf] = __builtin_amdgcn_mfma_f32_16x16x32_bf16(
                        af[mf], bfr[nf], acc[mf][nf], 0, 0, 0);
        }
        __builtin_amdgcn_s_barrier();
    }
    #undef STAGE

    #pragma unroll
    for (int mf = 0; mf < 4; mf++)
        #pragma unroll
        for (int nf = 0; nf < 4; nf++)
            #pragma unroll
            for (int r = 0; r < 4; r++) {
                int m = m0 + wr * 64 + mf * 16 + l4 * 4 + r;
                int n = n0 + wc * 64 + nf * 16 + l15;
                if (n < Nn) {
                    float v = acc[mf][nf][r];
                    if (HAS_BIAS) v += bias[n];
                    if (GELU)     v = gelu_tanh(v);
                    if (RESID)    v += bf2f(resid[(size_t)m * Nn + n]);
                    if (QSCALE && n < DD) v *= C8;   // Q columns only
                    if (OMODE == 1)
                        ((unsigned short*)Cv)[(size_t)m * Nn + n] = f2bf(v);
                    else
                        ((float*)Cv)[(size_t)m * Nn + n] = v;
                }
            }
}

// ---------------------------------------------------------------------------
// Kernel 3b: deep-pipelined 256x256 MFMA GEMM (ffn1: M=8192, N=2048, K=512).
// 8 waves (2M x 4N), per-wave output 128x64 (acc 8x4). 2-buffer LDS (128 KB),
// stage-ahead of 1 K-tile with counted wait: at the top of iteration kt the
// 8 loads for tile kt+1 are issued FIRST (the target buffer's readers were
// fenced by kt-1's end barrier), then vmcnt(8) -- in-order retirement means
// this waits only for tile kt's 8 loads, issued a full tile of MFMA earlier,
// while kt+1's loads stay in flight (never drain to 0 mid-loop). One publish
// barrier, 4 phases x 16 MFMA (setprio-wrapped), one end barrier.
// Pre-swizzled source (seg^row) pairs with read-side XOR swizzle.
// Grid 1-D 256 (1 block/CU): bx=flat>>5, by=flat&31 so the 8 blocks sharing
// an A-panel satisfy flat%8 == by%8 -> same XCD -> A L2-resident; 32
// consecutive blocks share each W panel.
// Epilogue: +bias, tanh-GELU, bf16 out.
// ---------------------------------------------------------------------------
__global__ __launch_bounds__(512, 1)
void gemm_mfma_256(const unsigned short* __restrict__ A,
                   const unsigned short* __restrict__ W,
                   const float* __restrict__ bias,
                   unsigned short* __restrict__ C,
                   int Nn, int Kk)
{
    __shared__ unsigned short As2[2][256 * 64];   // 64 KB
    __shared__ unsigned short Bs2[2][256 * 64];   // 64 KB

    int t = threadIdx.x;
    int w = t >> 6, lane = t & 63;                // w in [0,8)
    int wr = w >> 2, wc = w & 3;                  // 2M x 4N wave grid
    int l15 = lane & 15, l4 = lane >> 4;

    int flat = blockIdx.x;
    int bx = flat >> 5, by = flat & 31;           // flat%8 == by%8 (XCD co-locate)
    int m0 = by * 256, n0 = bx * 256;

    int lrow8 = lane >> 3;                        // 0..7
    int grow = w * 8 + lrow8;                     // 0..63: row within 64-row group
    int segp = (lane & 7) ^ lrow8;                // pre-swizzled 16B segment

    float4v acc[8][4];
    #pragma unroll
    for (int i = 0; i < 8; i++)
        #pragma unroll
        for (int j = 0; j < 4; j++)
            acc[i][j] = (float4v){0.f, 0.f, 0.f, 0.f};

    // stage one 128-row half (rows [RB, RB+128)) of matrix P at k0 into L
    #define STG_HALF(P, RB, K0, L) do {                                           \
        __builtin_amdgcn_global_load_lds(                                         \
            (glb_u32*)(P + (size_t)((RB) + grow) * Kk + (K0) + segp * 8),         \
            (lds_u32*)((L) + w * 512), 16, 0, 0);                                 \
        __builtin_amdgcn_global_load_lds(                                         \
            (glb_u32*)(P + (size_t)((RB) + 64 + grow) * Kk + (K0) + segp * 8),    \
            (lds_u32*)((L) + 4096 + w * 512), 16, 0, 0);                          \
    } while (0)

    #define STG_TILE(buf, K0) do {                                               \
        STG_HALF(A, m0,       (K0), As2[buf]);                                   \
        STG_HALF(A, m0 + 128, (K0), As2[buf] + 8192);                            \
        STG_HALF(W, n0,       (K0), Bs2[buf]);                                   \
        STG_HALF(W, n0 + 128, (K0), Bs2[buf] + 8192);                            \
    } while (0)

    int nk = Kk >> 6;                             // 8 for K=512
    STG_TILE(0, 0);                               // prologue: tile 0 -> buf0

    for (int kt = 0; kt < nk; kt++) {
        int cur = kt & 1;
        if (kt + 1 < nk) {
            STG_TILE(cur ^ 1, (kt + 1) << 6);     // issue next tile's 8 loads
            __builtin_amdgcn_sched_barrier(0);
            asm volatile("s_waitcnt vmcnt(8)");   // wait only tile kt's 8 loads
            __builtin_amdgcn_sched_barrier(0);
        } else {
            __builtin_amdgcn_sched_barrier(0);
            asm volatile("s_waitcnt vmcnt(0)");
            __builtin_amdgcn_sched_barrier(0);
        }
        __builtin_amdgcn_s_barrier();             // publish tile kt

        const char* asb = (const char*)As2[cur];
        const char* bsb = (const char*)Bs2[cur];
        short8v af[4], bfr[4];

        #pragma unroll
        for (int ph = 0; ph < 4; ph++) {
            int kc = ph >> 1;                     // 0,0,1,1
            int mh = ph & 1;                      // 0,1,0,1
            if (mh == 0) {
                #pragma unroll
                for (int nf = 0; nf < 4; nf++) {
                    int row = wc * 64 + nf * 16 + l15;
                    int off = (row * 128 + kc * 64 + l4 * 16) ^ ((row & 7) << 4);
                    bfr[nf] = *reinterpret_cast<const short8v*>(bsb + off);
                }
            }
            #pragma unroll
            for (int mf = 0; mf < 4; mf++) {
                int row = wr * 128 + (mh * 4 + mf) * 16 + l15;
                int off = (row * 128 + kc * 64 + l4 * 16) ^ ((row & 7) << 4);
                af[mf] = *reinterpret_cast<const short8v*>(asb + off);
            }
            __builtin_amdgcn_s_setprio(1);
            #pragma unroll
            for (int mf = 0; mf < 4; mf++)
                #pragma unroll
                for (int nf = 0; nf < 4; nf++)
                    acc[mh * 4 + mf][nf] = __builtin_amdgcn_mfma_f32_16x16x32_bf16(
                        af[mf], bfr[nf], acc[mh * 4 + mf][nf], 0, 0, 0);
            __builtin_amdgcn_s_setprio(0);
        }
        __builtin_amdgcn_s_barrier();             // fence readers before overwrite
    }
    #undef STG_TILE
    #undef STG_HALF

    // epilogue: bias + tanh-GELU, bf16 out
    #pragma unroll
    for (int mf = 0; mf < 8; mf++)
        #pragma unroll
        for (int nf = 0; nf < 4; nf++)
            #pragma unroll
            for (int r = 0; r < 4; r++) {
                int m = m0 + wr * 128 + mf * 16 + l4 * 4 + r;
                int n = n0 + wc * 64 + nf * 16 + l15;
                float v = acc[mf][nf][r] + bias[n];
                v = gelu_tanh(v);
                C[(size_t)m * Nn + n] = f2bf(v);
            }
}

// ---------------------------------------------------------------------------
// Kernel 4: MFMA flash attention (R12 champion configuration, unchanged)
// ---------------------------------------------------------------------------
__global__ __launch_bounds__(512, 2)
void attn_mfma(const unsigned short* __restrict__ qkv, unsigned short* __restrict__ o)
{
    __shared__ unsigned short Kl[2][128 * 64];
    __shared__ unsigned short Vs[2][128 * 64];
    __shared__ float Scl[8][16];

    int t = threadIdx.x, w = t >> 6, lane = t & 63;
    int l15 = lane & 15, l4 = lane >> 4;

    int flat = blockIdx.x;
    int swz = (flat & 7) * 64 + (flat >> 3);
    int qt = swz & 15, hh = (swz >> 4) & 7, b = swz >> 7;

    int q0 = qt * 128 + w * 16;
    const int RS = 3 * DD; // 1536

    short8v qf[2];
    #pragma unroll
    for (int dh = 0; dh < 2; dh++) {
        size_t addr = (size_t)(b * LL + q0 + l15) * RS + hh * HDIM + dh * 32 + l4 * 8;
        qf[dh] = *reinterpret_cast<const short8v*>(qkv + addr);
    }

    float4v o_acc[4];
    #pragma unroll
    for (int dt = 0; dt < 4; dt++) o_acc[dt] = (float4v){0.f, 0.f, 0.f, 0.f};
    float l_run = 0.f;

    int lrow8 = lane >> 3;
    int ksegp = (lane & 7) ^ lrow8;
    int rho = w * 8 + lrow8;
    int kappa = ((rho >> 5) << 5) | (((rho >> 4) & 1) << 2)
              | (((rho >> 2) & 3) << 3) | (rho & 3);
    int vrow = ((t >> 5) << 2) | ((t >> 1) & 3);
    int vseg = (((t >> 3) & 3) << 1) | (t & 1);
    const unsigned short* kgl = qkv + (size_t)(b * LL + kappa) * RS
                              + hh * HDIM + DD + ksegp * 8;
    const unsigned short* vgl = qkv + (size_t)(b * LL + vrow) * RS
                              + hh * HDIM + 2 * DD + vseg * 8;
    const int halfstep = 64 * RS;
    const int step = 128 * RS;

    #define ASTAGE(buf) do {                                                      \
        __builtin_amdgcn_global_load_lds((glb_u32*)kgl,                           \
            (lds_u32*)(Kl[buf] + w * 512), 16, 0, 0);                             \
        __builtin_amdgcn_global_load_lds((glb_u32*)(kgl + halfstep),              \
            (lds_u32*)(Kl[buf] + 4096 + w * 512), 16, 0, 0);                      \
        __builtin_amdgcn_global_load_lds((glb_u32*)vgl,                           \
            (lds_u32*)(Vs[buf] + w * 512), 16, 0, 0);                             \
        __builtin_amdgcn_global_load_lds((glb_u32*)(vgl + halfstep),              \
            (lds_u32*)(Vs[buf] + 4096 + w * 512), 16, 0, 0);                      \
        kgl += step; vgl += step; } while (0)

    unsigned vtrbase = lds_addr(Vs) + ((lane >> 4) << 10)
                     + (((lane >> 2) & 3) << 5) + ((lane & 3) << 3);

    ASTAGE(0);
    asm volatile("s_waitcnt vmcnt(0)");
    __syncthreads();

    for (int kb = 0; kb < LL / 128; kb++) {
        int cur = kb & 1;
        if (kb + 1 < LL / 128) ASTAGE(cur ^ 1);

        #pragma unroll
        for (int hf = 0; hf < 2; hf++) {
            const char* klc = (const char*)Kl[cur] + hf * 8192;
            unsigned vb = vtrbase + cur * 16384 + hf * 8192;

            float4v s_acc[4];
            __builtin_amdgcn_s_setprio(1);
            #pragma unroll
            for (int nt = 0; nt < 4; nt++) {
                s_acc[nt] = (float4v){0.f, 0.f, 0.f, 0.f};
                #pragma unroll
                for (int dh = 0; dh < 2; dh++) {
                    int row = nt * 16 + l15;
                    int off = (row * 128 + dh * 64 + l4 * 16) ^ ((row & 7) << 4);
                    short8v kf = *reinterpret_cast<const short8v*>(klc + off);
                    s_acc[nt] = __builtin_amdgcn_mfma_f32_16x16x32_bf16(kf, qf[dh], s_acc[nt], 0, 0, 0);
                }
            }
            __builtin_amdgcn_s_setprio(0);

            unsigned long long a0, a1, a2, a3, a4, a5, a6, a7;
            unsigned long long b0, b1, b2, b3, b4, b5, b6, b7;
            unsigned ab0 = vb, ab1 = vb + 4096;
            asm volatile("ds_read_b64_tr_b16 %0, %1" : "=v"(a0) : "v"(ab0));
            asm volatile("ds_read_b64_tr_b16 %0, %1" : "=v"(a1) : "v"(ab0 + 512));
            asm volatile("ds_read_b64_tr_b16 %0, %1" : "=v"(a2) : "v"(ab0 + 128));
            asm volatile("ds_read_b64_tr_b16 %0, %1" : "=v"(a3) : "v"(ab0 + 640));
            asm volatile("ds_read_b64_tr_b16 %0, %1" : "=v"(a4) : "v"(ab0 + 256));
            asm volatile("ds_read_b64_tr_b16 %0, %1" : "=v"(a5) : "v"(ab0 + 768));
            asm volatile("ds_read_b64_tr_b16 %0, %1" : "=v"(a6) : "v"(ab0 + 384));
            asm volatile("ds_read_b64_tr_b16 %0, %1" : "=v"(a7) : "v"(ab0 + 896));
            asm volatile("ds_read_b64_tr_b16 %0, %1" : "=v"(b0) : "v"(ab1));
            asm volatile("ds_read_b64_tr_b16 %0, %1" : "=v"(b1) : "v"(ab1 + 512));
            asm volatile("ds_read_b64_tr_b16 %0, %1" : "=v"(b2) : "v"(ab1 + 128));
            asm volatile("ds_read_b64_tr_b16 %0, %1" : "=v"(b3) : "v"(ab1 + 640));
            asm volatile("ds_read_b64_tr_b16 %0, %1" : "=v"(b4) : "v"(ab1 + 256));
            asm volatile("ds_read_b64_tr_b16 %0, %1" : "=v"(b5) : "v"(ab1 + 768));
            asm volatile("ds_read_b64_tr_b16 %0, %1" : "=v"(b6) : "v"(ab1 + 384));
            asm volatile("ds_read_b64_tr_b16 %0, %1" : "=v"(b7) : "v"(ab1 + 896));

            union { unsigned u[4]; short8v v; } pf0u, pf1u;
            float ps;
            {
                float p0 = __builtin_amdgcn_exp2f(s_acc[0][0]);
                float p1 = __builtin_amdgcn_exp2f(s_acc[0][1]);
                float p2 = __builtin_amdgcn_exp2f(s_acc[0][2]);
                float p3 = __builtin_amdgcn_exp2f(s_acc[0][3]);
                float p4 = __builtin_amdgcn_exp2f(s_acc[1][0]);
                float p5 = __builtin_amdgcn_exp2f(s_acc[1][1]);
                float p6 = __builtin_amdgcn_exp2f(s_acc[1][2]);
                float p7 = __builtin_amdgcn_exp2f(s_acc[1][3]);
                asm("v_cvt_pk_bf16_f32 %0, %1, %2" : "=v"(pf0u.u[0]) : "v"(p0), "v"(p1));
                asm("v_cvt_pk_bf16_f32 %0, %1, %2" : "=v"(pf0u.u[1]) : "v"(p2), "v"(p3));
                asm("v_cvt_pk_bf16_f32 %0, %1, %2" : "=v"(pf0u.u[2]) : "v"(p4), "v"(p5));
                asm("v_cvt_pk_bf16_f32 %0, %1, %2" : "=v"(pf0u.u[3]) : "v"(p6), "v"(p7));
                ps = ((p0 + p1) + (p2 + p3)) + ((p4 + p5) + (p6 + p7));
            }
            {
                float p0 = __builtin_amdgcn_exp2f(s_acc[2][0]);
                float p1 = __builtin_amdgcn_exp2f(s_acc[2][1]);
                float p2 = __builtin_amdgcn_exp2f(s_acc[2][2]);
                float p3 = __builtin_amdgcn_exp2f(s_acc[2][3]);
                float p4 = __builtin_amdgcn_exp2f(s_acc[3][0]);
                float p5 = __builtin_amdgcn_exp2f(s_acc[3][1]);
                float p6 = __builtin_amdgcn_exp2f(s_acc[3][2]);
                float p7 = __builtin_amdgcn_exp2f(s_acc[3][3]);
                asm("v_cvt_pk_bf16_f32 %0, %1, %2" : "=v"(pf1u.u[0]) : "v"(p0), "v"(p1));
                asm("v_cvt_pk_bf16_f32 %0, %1, %2" : "=v"(pf1u.u[1]) : "v"(p2), "v"(p3));
                asm("v_cvt_pk_bf16_f32 %0, %1, %2" : "=v"(pf1u.u[2]) : "v"(p4), "v"(p5));
                asm("v_cvt_pk_bf16_f32 %0, %1, %2" : "=v"(pf1u.u[3]) : "v"(p6), "v"(p7));
                ps += ((p0 + p1) + (p2 + p3)) + ((p4 + p5) + (p6 + p7));
            }
            l_run += ps;

            union { unsigned long long q[2]; short8v v; } u0, u1, u2, u3;
            asm volatile("s_waitcnt lgkmcnt(8)");
            __builtin_amdgcn_sched_barrier(0);
            __builtin_amdgcn_s_setprio(1);
            u0.q[0] = a0; u0.q[1] = a1;
            u1.q[0] = a2; u1.q[1] = a3;
            o_acc[0] = __builtin_amdgcn_mfma_f32_16x16x32_bf16(pf0u.v, u0.v, o_acc[0], 0, 0, 0);
            o_acc[1] = __builtin_amdgcn_mfma_f32_16x16x32_bf16(pf0u.v, u1.v, o_acc[1], 0, 0, 0);
            asm volatile("s_waitcnt lgkmcnt(4)");
            __builtin_amdgcn_sched_barrier(0);
            u2.q[0] = a4; u2.q[1] = a5;
            u3.q[0] = a6; u3.q[1] = a7;
            o_acc[2] = __builtin_amdgcn_mfma_f32_16x16x32_bf16(pf0u.v, u2.v, o_acc[2], 0, 0, 0);
            o_acc[3] = __builtin_amdgcn_mfma_f32_16x16x32_bf16(pf0u.v, u3.v, o_acc[3], 0, 0, 0);
            asm volatile("s_waitcnt lgkmcnt(0)");
            __builtin_amdgcn_sched_barrier(0);
            u0.q[0] = b0; u0.q[1] = b1;
            u1.q[0] = b2; u1.q[1] = b3;
            u2.q[0] = b4; u2.q[1] = b5;
            u3.q[0] = b6; u3.q[1] = b7;
            o_acc[0] = __builtin_amdgcn_mfma_f32_16x16x32_bf16(pf1u.v, u0.v, o_acc[0], 0, 0, 0);
            o_acc[1] = __builtin_amdgcn_mfma_f32_16x16x32_bf16(pf1u.v, u1.v, o_acc[1], 0, 0, 0);
            o_acc[2] = __builtin_amdgcn_mfma_f32_16x16x32_bf16(pf1u.v, u2.v, o_acc[2], 0, 0, 0);
            o_acc[3] = __builtin_amdgcn_mfma_f32_16x16x32_bf16(pf1u.v, u3.v, o_acc[3], 0, 0, 0);
            __builtin_amdgcn_s_setprio(0);
        }

        asm volatile("s_waitcnt vmcnt(0)");
        __syncthreads();
    }
    #undef ASTAGE

    float lt = l_run;
    lt += __shfl_xor(lt, 16);
    lt += __shfl_xor(lt, 32);
    if (l4 == 0) Scl[w][l15] = 1.f / lt;
    float4 iv = *reinterpret_cast<const float4*>(&Scl[w][l4 * 4]);
    float invs[4] = {iv.x, iv.y, iv.z, iv.w};
    #pragma unroll
    for (int r = 0; r < 4; r++) {
        int qg = q0 + l4 * 4 + r;
        #pragma unroll
        for (int dt = 0; dt < 4; dt++) {
            o[(size_t)(b * LL + qg) * DD + hh * HDIM + dt * 16 + l15] =
                f2bf(o_acc[dt][r] * invs[r]);
        }
    }
}

// ---------------------------------------------------------------------------
// Driver
// ---------------------------------------------------------------------------
extern "C" void kernel_launch(void* const* d_in, const int* in_sizes, int n_in,
                              void* d_out, int out_size, void* d_ws, size_t ws_size,
                              hipStream_t stream)
{
    const float* emb    = (const float*)d_in[0];
    const float* ent_w  = (const float*)d_in[1];
    const float* ent_b  = (const float*)d_in[2];
    const float* qkv_w  = (const float*)d_in[3];
    const float* qkv_b  = (const float*)d_in[4];
    const float* ao_w   = (const float*)d_in[5];
    const float* ao_b   = (const float*)d_in[6];
    const float* ln1_s  = (const float*)d_in[7];
    const float* ln1_b  = (const float*)d_in[8];
    const float* ln2_s  = (const float*)d_in[9];
    const float* ln2_b  = (const float*)d_in[10];
    const float* ff1_w  = (const float*)d_in[11];
    const float* ff1_b  = (const float*)d_in[12];
    const float* ff2_w  = (const float*)d_in[13];
    const float* ff2_b  = (const float*)d_in[14];
    const float* out_w  = (const float*)d_in[15];
    const int*   x      = (const int*)d_in[16];
    // d_in[17] = patch_lengths : dead code in the reference

    float* out = (float*)d_out;

    const int NQW = NLAYER * 3 * DD * DD;
    const int NAW = NLAYER * DD * DD;
    const int NF1 = NLAYER * 4 * DD * DD;
    const int NF2 = NLAYER * DD * 4 * DD;

    char* p = (char*)d_ws;
    unsigned short* wq  = (unsigned short*)p; p += (size_t)NQW * 2;
    unsigned short* wa  = (unsigned short*)p; p += (size_t)NAW * 2;
    unsigned short* w1  = (unsigned short*)p; p += (size_t)NF1 * 2;
    unsigned short* w2  = (unsigned short*)p; p += (size_t)NF2 * 2;
    unsigned short* wob = (unsigned short*)p; p += (size_t)VPAD * DD * 2;
    unsigned short* h   = (unsigned short*)p; p += (size_t)MM * DD * 2;   // bf16 residual
    unsigned short* gb  = (unsigned short*)p; p += (size_t)MM * DD * 2;
    unsigned short* ob  = (unsigned short*)p; p += (size_t)MM * DD * 2;
    unsigned short* bb  = (unsigned short*)p; p += (size_t)MM * 4 * DD * 2; // qkv / ffn

    dim3 blk(256);

    cvt_all_kernel<<<E4 / 1024, blk, 0, stream>>>(qkv_w, ao_w, ff1_w, ff2_w, out_w, wq);

    embed_ln_kernel<<<MM / 4, blk, 0, stream>>>(x, emb, ent_w, ent_b,
                                                ln1_s, ln1_b, h, gb);

    for (int layer = 0; layer < NLAYER; layer++) {
        const unsigned short* qw = wq + (size_t)layer * 3 * DD * DD;
        const unsigned short* aw = wa + (size_t)layer * DD * DD;
        const unsigned short* f1 = w1 + (size_t)layer * 4 * DD * DD;
        const unsigned short* f2 = w2 + (size_t)layer * DD * 4 * DD;
        const float* qb  = qkv_b + (size_t)layer * 3 * DD;
        const float* ab  = ao_b  + (size_t)layer * DD;
        const float* l1s = ln1_s + (size_t)layer * DD;
        const float* l1b = ln1_b + (size_t)layer * DD;
        const float* l2s = ln2_s + (size_t)layer * DD;
        const float* l2b = ln2_b + (size_t)layer * DD;
        const float* f1b = ff1_b + (size_t)layer * 4 * DD;
        const float* f2b = ff2_b + (size_t)layer * DD;

        // LN1 (layer 0 fused into embed_ln_kernel)
        if (layer > 0)
            ln_kernel<<<MM / 4, blk, 0, stream>>>(h, l1s, l1b, gb);

        // qkv = gb @ qw^T + qb -> bb (bf16) [MM,1536], Q cols pre-scaled by C8
        {
            dim3 grid((3 * DD) / 128, MM / 128);
            gemm_mfma<true, false, false, true, 1, 128><<<grid, 256, 0, stream>>>(
                gb, qw, qb, nullptr, bb, 3 * DD, DD);
        }

        // attention: bb -> ob (bf16)
        attn_mfma<<<512, 512, 0, stream>>>(bb, ob);

        // h = h + ob @ aw^T + ab  (bf16 out; MT=64 -> 512 blocks)
        {
            dim3 grid(DD / 128, MM / 64);
            gemm_mfma<true, false, true, false, 1, 64><<<grid, 128, 0, stream>>>(
                ob, aw, ab, h, h, DD, DD);
        }

        // LN2: h -> gb
        ln_kernel<<<MM / 4, blk, 0, stream>>>(h, l2s, l2b, gb);

        // ffn1: bb = gelu(gb @ f1^T + f1b) (bf16) [MM,2048] -- deep-pipelined 256^2
        gemm_mfma_256<<<(MM / 256) * ((4 * DD) / 256), 512, 0, stream>>>(
            gb, f1, f1b, bb, 4 * DD, DD);

        // ffn2: h = h + bb @ f2^T + f2b  (bf16 out; MT=64)
        {
            dim3 grid(DD / 128, MM / 64);
            gemm_mfma<true, false, true, false, 1, 64><<<grid, 128, 0, stream>>>(
                bb, f2, f2b, h, h, DD, 4 * DD);
        }
    }

    // logits = h @ wob^T [MM, 258] via MFMA on padded weight (MT=64)
    {
        dim3 grid(VPAD / 128, MM / 64);
        gemm_mfma<false, false, false, false, 0, 64><<<grid, 128, 0, stream>>>(
            h, wob, nullptr, nullptr, out, VV, DD);
    }
}

// Round 18
// 668.695 us; speedup vs baseline: 1.0777x; 1.0077x over previous
//
#include <hip/hip_runtime.h>
#include <hip/hip_bf16.h>
#include <math.h>

// Problem constants
#define BB 4
#define LL 2048
#define DD 512
#define HH 8
#define NLAYER 4
#define VV 258
#define WW 8
#define HDIM 64
#define MM (BB * LL)   // 8192 rows
#define VPAD 384       // logits weight rows padded to tile multiple

// 0.125 * log2(e): QK^T scale, folded into Q at the qkv-GEMM epilogue
#define C8 0.18033688f

typedef __attribute__((ext_vector_type(8))) short short8v;
typedef __attribute__((ext_vector_type(4))) float float4v;

typedef __attribute__((address_space(3))) unsigned int lds_u32;
typedef const __attribute__((address_space(1))) unsigned int glb_u32;

__device__ __forceinline__ unsigned short f2bf(float x) {
    unsigned int u = __float_as_uint(x);
    unsigned int r = (u + 0x7fffu + ((u >> 16) & 1u)) >> 16;
    return (unsigned short)r;
}
__device__ __forceinline__ float bf2f(unsigned short u) {
    return __uint_as_float((unsigned)u << 16);
}

__device__ __forceinline__ unsigned lds_addr(const void* p) {
    return (unsigned)(size_t)(__attribute__((address_space(3))) const void*)p;
}

__device__ __forceinline__ float gelu_tanh(float v) {
    float a = 0.044715f * v * v;
    float u = fminf(fmaf(a, v, v) * 2.3022077f, 80.f);
    float e = __builtin_amdgcn_exp2f(u);
    return v * e * __builtin_amdgcn_rcpf(e + 1.f);
}

// ---------------------------------------------------------------------------
// Fused weight conversion: all four layer-weight arrays + padded out_w.
// ---------------------------------------------------------------------------
#define E0 (NLAYER * 3 * DD * DD)          // 3,145,728
#define E1 (E0 + NLAYER * DD * DD)         // 4,194,304
#define E2 (E1 + NLAYER * 4 * DD * DD)     // 8,388,608
#define E3 (E2 + NLAYER * 4 * DD * DD)     // 12,582,912
#define E4 (E3 + VPAD * DD)                // 12,779,520

__global__ __launch_bounds__(256)
void cvt_all_kernel(const float* __restrict__ qkv_w, const float* __restrict__ ao_w,
                    const float* __restrict__ ff1_w, const float* __restrict__ ff2_w,
                    const float* __restrict__ out_w, unsigned short* __restrict__ dst)
{
    int i = (blockIdx.x * 256 + threadIdx.x) * 4;
    float4 v;
    if (i < E0)      v = *reinterpret_cast<const float4*>(qkv_w + i);
    else if (i < E1) v = *reinterpret_cast<const float4*>(ao_w + (i - E0));
    else if (i < E2) v = *reinterpret_cast<const float4*>(ff1_w + (i - E1));
    else if (i < E3) v = *reinterpret_cast<const float4*>(ff2_w + (i - E2));
    else {
        int idx = i - E3;
        if ((idx >> 9) < VV) v = *reinterpret_cast<const float4*>(out_w + idx);
        else                 v = (float4){0.f, 0.f, 0.f, 0.f};
    }
    uint2 pk;
    pk.x = (unsigned)f2bf(v.x) | ((unsigned)f2bf(v.y) << 16);
    pk.y = (unsigned)f2bf(v.z) | ((unsigned)f2bf(v.w) << 16);
    *reinterpret_cast<uint2*>(dst + i) = pk;
}

// ---------------------------------------------------------------------------
// Kernel 1: fused token embedding + entropy feature + LN1(layer 0)
// ---------------------------------------------------------------------------
__global__ __launch_bounds__(256)
void embed_ln_kernel(const int* __restrict__ x,
                     const float* __restrict__ emb,
                     const float* __restrict__ ent_w,
                     const float* __restrict__ ent_b,
                     const float* __restrict__ ln_s,
                     const float* __restrict__ ln_b,
                     unsigned short* __restrict__ h,
                     unsigned short* __restrict__ g)
{
    int w = threadIdx.x >> 6, lane = threadIdx.x & 63;
    int row = blockIdx.x * 4 + w;
    int b = row / LL, l = row % LL;

    float ent = 0.f;
    if (l <= LL - WW) {
        int win[WW];
        #pragma unroll
        for (int i = 0; i < WW; i++) win[i] = x[b * LL + l + i];
        float s = 0.f;
        #pragma unroll
        for (int i = 0; i < WW; i++) {
            if (win[i] < 256) {
                int c = 0;
                #pragma unroll
                for (int j = 0; j < WW; j++) c += (win[j] == win[i]) ? 1 : 0;
                s += log2f((float)c * 0.125f + 1e-10f);
            }
        }
        ent = -s * 0.125f;
    }

    int tok = x[row];
    const float* erow = emb + (size_t)tok * DD + lane * 8;
    float v[8], ew[8], eb[8];
    *reinterpret_cast<float4*>(v)      = *reinterpret_cast<const float4*>(erow);
    *reinterpret_cast<float4*>(v + 4)  = *reinterpret_cast<const float4*>(erow + 4);
    *reinterpret_cast<float4*>(ew)     = *reinterpret_cast<const float4*>(ent_w + lane * 8);
    *reinterpret_cast<float4*>(ew + 4) = *reinterpret_cast<const float4*>(ent_w + lane * 8 + 4);
    *reinterpret_cast<float4*>(eb)     = *reinterpret_cast<const float4*>(ent_b + lane * 8);
    *reinterpret_cast<float4*>(eb + 4) = *reinterpret_cast<const float4*>(ent_b + lane * 8 + 4);

    float sum = 0.f, sq = 0.f;
    #pragma unroll
    for (int i = 0; i < 8; i++) {
        v[i] = v[i] + ent * ew[i] + eb[i];
        sum += v[i]; sq += v[i] * v[i];
    }
    unsigned int hpk[4];
    #pragma unroll
    for (int i = 0; i < 4; i++)
        hpk[i] = (unsigned)f2bf(v[2*i]) | ((unsigned)f2bf(v[2*i+1]) << 16);
    *reinterpret_cast<uint4*>(h + (size_t)row * DD + lane * 8) =
        *reinterpret_cast<const uint4*>(hpk);

    #pragma unroll
    for (int off = 32; off > 0; off >>= 1) {
        sum += __shfl_xor(sum, off);
        sq  += __shfl_xor(sq, off);
    }
    float mu = sum * (1.f / DD);
    float var = sq * (1.f / DD) - mu * mu;
    float rstd = rsqrtf(var + 1e-5f);

    float s8[8], bi[8];
    *reinterpret_cast<float4*>(s8)     = *reinterpret_cast<const float4*>(ln_s + lane * 8);
    *reinterpret_cast<float4*>(s8 + 4) = *reinterpret_cast<const float4*>(ln_s + lane * 8 + 4);
    *reinterpret_cast<float4*>(bi)     = *reinterpret_cast<const float4*>(ln_b + lane * 8);
    *reinterpret_cast<float4*>(bi + 4) = *reinterpret_cast<const float4*>(ln_b + lane * 8 + 4);

    unsigned int pk[4];
    #pragma unroll
    for (int i = 0; i < 4; i++) {
        unsigned short lo = f2bf((v[2*i]   - mu) * rstd * s8[2*i]   + bi[2*i]);
        unsigned short hi = f2bf((v[2*i+1] - mu) * rstd * s8[2*i+1] + bi[2*i+1]);
        pk[i] = (unsigned)lo | ((unsigned)hi << 16);
    }
    *reinterpret_cast<uint4*>(g + (size_t)row * DD + lane * 8) =
        *reinterpret_cast<const uint4*>(pk);
}

// ---------------------------------------------------------------------------
// Kernel 2: LayerNorm (bf16 in, bf16 out). One wave per row, 4 rows/block.
// ---------------------------------------------------------------------------
__global__ __launch_bounds__(256)
void ln_kernel(const unsigned short* __restrict__ h,
               const float* __restrict__ scale,
               const float* __restrict__ bias,
               unsigned short* __restrict__ g)
{
    int w = threadIdx.x >> 6, lane = threadIdx.x & 63;
    int row = blockIdx.x * 4 + w;

    uint4 raw = *reinterpret_cast<const uint4*>(h + (size_t)row * DD + lane * 8);
    const unsigned* rw = reinterpret_cast<const unsigned*>(&raw);
    float v[8];
    #pragma unroll
    for (int i = 0; i < 4; i++) {
        v[2*i]   = __uint_as_float(rw[i] << 16);
        v[2*i+1] = __uint_as_float(rw[i] & 0xffff0000u);
    }

    float sum = 0.f, sq = 0.f;
    #pragma unroll
    for (int i = 0; i < 8; i++) { sum += v[i]; sq += v[i] * v[i]; }
    #pragma unroll
    for (int off = 32; off > 0; off >>= 1) {
        sum += __shfl_xor(sum, off);
        sq  += __shfl_xor(sq, off);
    }
    float mu = sum * (1.f / DD);
    float var = sq * (1.f / DD) - mu * mu;
    float rstd = rsqrtf(var + 1e-5f);

    float s[8], bi[8];
    *reinterpret_cast<float4*>(s)      = *reinterpret_cast<const float4*>(scale + lane * 8);
    *reinterpret_cast<float4*>(s + 4)  = *reinterpret_cast<const float4*>(scale + lane * 8 + 4);
    *reinterpret_cast<float4*>(bi)     = *reinterpret_cast<const float4*>(bias + lane * 8);
    *reinterpret_cast<float4*>(bi + 4) = *reinterpret_cast<const float4*>(bias + lane * 8 + 4);

    unsigned int pk[4];
    #pragma unroll
    for (int i = 0; i < 4; i++) {
        unsigned short lo = f2bf((v[2*i]   - mu) * rstd * s[2*i]   + bi[2*i]);
        unsigned short hi = f2bf((v[2*i+1] - mu) * rstd * s[2*i+1] + bi[2*i+1]);
        pk[i] = (unsigned)lo | ((unsigned)hi << 16);
    }
    *reinterpret_cast<uint4*>(g + (size_t)row * DD + lane * 8) =
        *reinterpret_cast<const uint4*>(pk);
}

// ---------------------------------------------------------------------------
// Kernel 3: MFMA GEMM (2-phase, MT=128) — champion path for qkv.
// ---------------------------------------------------------------------------
template<bool HAS_BIAS, bool GELU, bool RESID, bool QSCALE, int OMODE>
__global__ __launch_bounds__(256)
void gemm_mfma(const unsigned short* __restrict__ A,
               const unsigned short* __restrict__ W,
               const float* __restrict__ bias,
               const unsigned short* __restrict__ resid,
               void* __restrict__ Cv,
               int Nn, int Kk)
{
    __shared__ unsigned short As[2][128 * 64];
    __shared__ unsigned short Bs[2][128 * 64];

    int t = threadIdx.x;
    int w = t >> 6, lane = t & 63;
    int wr = w >> 1, wc = w & 1;
    int l15 = lane & 15, l4 = lane >> 4;
    int m0 = blockIdx.y * 128, n0 = blockIdx.x * 128;

    int lrow = lane >> 3;
    int segp = (lane & 7) ^ lrow;

    float4v acc[4][4];
    #pragma unroll
    for (int i = 0; i < 4; i++)
        #pragma unroll
        for (int j = 0; j < 4; j++)
            acc[i][j] = (float4v){0.f, 0.f, 0.f, 0.f};

    #define STAGE(buf, k0) do {                                                   \
        _Pragma("unroll")                                                         \
        for (int i_ = 0; i_ < 4; i_++) {                                          \
            int r_ = i_ * 32 + w * 8 + lrow;                                      \
            __builtin_amdgcn_global_load_lds(                                     \
                (glb_u32*)(A + (size_t)(m0 + r_) * Kk + (k0) + segp * 8),         \
                (lds_u32*)(As[buf] + i_ * 2048 + w * 512), 16, 0, 0);             \
            __builtin_amdgcn_global_load_lds(                                     \
                (glb_u32*)(W + (size_t)(n0 + r_) * Kk + (k0) + segp * 8),         \
                (lds_u32*)(Bs[buf] + i_ * 2048 + w * 512), 16, 0, 0);             \
        } } while (0)

    int nk = Kk >> 6;
    STAGE(0, 0);
    for (int kt = 0; kt < nk; kt++) {
        int cur = kt & 1;
        if (kt + 1 < nk) {
            STAGE(cur ^ 1, (kt + 1) << 6);
            __builtin_amdgcn_sched_barrier(0);
            asm volatile("s_waitcnt vmcnt(8)");
            __builtin_amdgcn_sched_barrier(0);
        } else {
            __builtin_amdgcn_sched_barrier(0);
            asm volatile("s_waitcnt vmcnt(0)");
            __builtin_amdgcn_sched_barrier(0);
        }
        __builtin_amdgcn_s_barrier();

        const char* asb = (const char*)As[cur];
        const char* bsb = (const char*)Bs[cur];
        #pragma unroll
        for (int kc = 0; kc < 2; kc++) {
            short8v af[4], bfr[4];
            #pragma unroll
            for (int mf = 0; mf < 4; mf++) {
                int row = wr * 64 + mf * 16 + l15;
                int off = (row * 128 + kc * 64 + l4 * 16) ^ ((row & 7) << 4);
                af[mf] = *reinterpret_cast<const short8v*>(asb + off);
            }
            #pragma unroll
            for (int nf = 0; nf < 4; nf++) {
                int row = wc * 64 + nf * 16 + l15;
                int off = (row * 128 + kc * 64 + l4 * 16) ^ ((row & 7) << 4);
                bfr[nf] = *reinterpret_cast<const short8v*>(bsb + off);
            }
            #pragma unroll
            for (int mf = 0; mf < 4; mf++)
                #pragma unroll
                for (int nf = 0; nf < 4; nf++)
                    acc[mf][nf] = __builtin_amdgcn_mfma_f32_16x16x32_bf16(
                        af[mf], bfr[nf], acc[mf][nf], 0, 0, 0);
        }
        __builtin_amdgcn_s_barrier();
    }
    #undef STAGE

    #pragma unroll
    for (int mf = 0; mf < 4; mf++)
        #pragma unroll
        for (int nf = 0; nf < 4; nf++)
            #pragma unroll
            for (int r = 0; r < 4; r++) {
                int m = m0 + wr * 64 + mf * 16 + l4 * 4 + r;
                int n = n0 + wc * 64 + nf * 16 + l15;
                if (n < Nn) {
                    float v = acc[mf][nf][r];
                    if (HAS_BIAS) v += bias[n];
                    if (GELU)     v = gelu_tanh(v);
                    if (RESID)    v += bf2f(resid[(size_t)m * Nn + n]);
                    if (QSCALE && n < DD) v *= C8;
                    if (OMODE == 1)
                        ((unsigned short*)Cv)[(size_t)m * Nn + n] = f2bf(v);
                    else
                        ((float*)Cv)[(size_t)m * Nn + n] = v;
                }
            }
}

// ---------------------------------------------------------------------------
// Kernel 3c: MT=64 GEMM with 3-buffer ring + stage-ahead-2 (ao/ffn2/logits).
// 128 threads, 2 waves (64x64 each), tile 64x128. LDS 3 x 24 KB = 72 KB ->
// 2 blocks/CU. At iteration kt: issue tile kt+2's 12 loads into ring slot
// (kt+2)%3 (its previous occupant kt-1's readers were fenced at kt-1's end
// barrier), then vmcnt(24): in-order retirement => tile kt's 12 loads (issued
// two K-tiles of MFMA ago) are drained, kt+1/kt+2's stay in flight. Wait
// ladder 24/12/0 by remaining tiles. One publish barrier, 32 MFMA, end barrier.
// ---------------------------------------------------------------------------
template<bool HAS_BIAS, bool GELU, bool RESID, int OMODE>
__global__ __launch_bounds__(128)
void gemm_mfma64_d3(const unsigned short* __restrict__ A,
                    const unsigned short* __restrict__ W,
                    const float* __restrict__ bias,
                    const unsigned short* __restrict__ resid,
                    void* __restrict__ Cv,
                    int Nn, int Kk)
{
    __shared__ unsigned short As[3][64 * 64];    // 8 KB each
    __shared__ unsigned short Bs[3][128 * 64];   // 16 KB each

    int t = threadIdx.x;
    int w = t >> 6, lane = t & 63;               // w in [0,2)
    int wc = w;                                  // wave n-half; wr = 0
    int l15 = lane & 15, l4 = lane >> 4;
    int m0 = blockIdx.y * 64, n0 = blockIdx.x * 128;

    int lrow = lane >> 3;
    int segp = (lane & 7) ^ lrow;

    float4v acc[4][4];
    #pragma unroll
    for (int i = 0; i < 4; i++)
        #pragma unroll
        for (int j = 0; j < 4; j++)
            acc[i][j] = (float4v){0.f, 0.f, 0.f, 0.f};

    #define STAGE64(buf, k0) do {                                                 \
        _Pragma("unroll")                                                         \
        for (int i_ = 0; i_ < 4; i_++) {                                          \
            int r_ = i_ * 16 + w * 8 + lrow;                                      \
            __builtin_amdgcn_global_load_lds(                                     \
                (glb_u32*)(A + (size_t)(m0 + r_) * Kk + (k0) + segp * 8),         \
                (lds_u32*)(As[buf] + i_ * 1024 + w * 512), 16, 0, 0);             \
        }                                                                         \
        _Pragma("unroll")                                                         \
        for (int i_ = 0; i_ < 8; i_++) {                                          \
            int r_ = i_ * 16 + w * 8 + lrow;                                      \
            __builtin_amdgcn_global_load_lds(                                     \
                (glb_u32*)(W + (size_t)(n0 + r_) * Kk + (k0) + segp * 8),         \
                (lds_u32*)(Bs[buf] + i_ * 1024 + w * 512), 16, 0, 0);             \
        } } while (0)

    int nk = Kk >> 6;                            // >= 8 for all uses
    STAGE64(0, 0);
    STAGE64(1, 64);

    int cur = 0;
    for (int kt = 0; kt < nk; kt++) {
        if (kt + 2 < nk) {
            int sb = cur + 2; if (sb >= 3) sb -= 3;
            STAGE64(sb, (kt + 2) << 6);
        }
        __builtin_amdgcn_sched_barrier(0);
        int rem = nk - 1 - kt;
        if (rem >= 2)      asm volatile("s_waitcnt vmcnt(24)");
        else if (rem == 1) asm volatile("s_waitcnt vmcnt(12)");
        else               asm volatile("s_waitcnt vmcnt(0)");
        __builtin_amdgcn_sched_barrier(0);
        __builtin_amdgcn_s_barrier();            // publish tile kt

        const char* asb = (const char*)As[cur];
        const char* bsb = (const char*)Bs[cur];
        #pragma unroll
        for (int kc = 0; kc < 2; kc++) {
            short8v af[4], bfr[4];
            #pragma unroll
            for (int mf = 0; mf < 4; mf++) {
                int row = mf * 16 + l15;
                int off = (row * 128 + kc * 64 + l4 * 16) ^ ((row & 7) << 4);
                af[mf] = *reinterpret_cast<const short8v*>(asb + off);
            }
            #pragma unroll
            for (int nf = 0; nf < 4; nf++) {
                int row = wc * 64 + nf * 16 + l15;
                int off = (row * 128 + kc * 64 + l4 * 16) ^ ((row & 7) << 4);
                bfr[nf] = *reinterpret_cast<const short8v*>(bsb + off);
            }
            __builtin_amdgcn_s_setprio(1);
            #pragma unroll
            for (int mf = 0; mf < 4; mf++)
                #pragma unroll
                for (int nf = 0; nf < 4; nf++)
                    acc[mf][nf] = __builtin_amdgcn_mfma_f32_16x16x32_bf16(
                        af[mf], bfr[nf], acc[mf][nf], 0, 0, 0);
            __builtin_amdgcn_s_setprio(0);
        }
        __builtin_amdgcn_s_barrier();            // fence readers before overwrite
        cur = cur + 1; if (cur >= 3) cur -= 3;
    }
    #undef STAGE64

    #pragma unroll
    for (int mf = 0; mf < 4; mf++)
        #pragma unroll
        for (int nf = 0; nf < 4; nf++)
            #pragma unroll
            for (int r = 0; r < 4; r++) {
                int m = m0 + mf * 16 + l4 * 4 + r;
                int n = n0 + wc * 64 + nf * 16 + l15;
                if (n < Nn) {
                    float v = acc[mf][nf][r];
                    if (HAS_BIAS) v += bias[n];
                    if (GELU)     v = gelu_tanh(v);
                    if (RESID)    v += bf2f(resid[(size_t)m * Nn + n]);
                    if (OMODE == 1)
                        ((unsigned short*)Cv)[(size_t)m * Nn + n] = f2bf(v);
                    else
                        ((float*)Cv)[(size_t)m * Nn + n] = v;
                }
            }
}

// ---------------------------------------------------------------------------
// Kernel 3b: deep-pipelined 256x256 MFMA GEMM (ffn1) — unchanged from R17.
// ---------------------------------------------------------------------------
__global__ __launch_bounds__(512, 1)
void gemm_mfma_256(const unsigned short* __restrict__ A,
                   const unsigned short* __restrict__ W,
                   const float* __restrict__ bias,
                   unsigned short* __restrict__ C,
                   int Nn, int Kk)
{
    __shared__ unsigned short As2[2][256 * 64];   // 64 KB
    __shared__ unsigned short Bs2[2][256 * 64];   // 64 KB

    int t = threadIdx.x;
    int w = t >> 6, lane = t & 63;                // w in [0,8)
    int wr = w >> 2, wc = w & 3;                  // 2M x 4N wave grid
    int l15 = lane & 15, l4 = lane >> 4;

    int flat = blockIdx.x;
    int bx = flat >> 5, by = flat & 31;           // flat%8 == by%8 (XCD co-locate)
    int m0 = by * 256, n0 = bx * 256;

    int lrow8 = lane >> 3;
    int grow = w * 8 + lrow8;
    int segp = (lane & 7) ^ lrow8;

    float4v acc[8][4];
    #pragma unroll
    for (int i = 0; i < 8; i++)
        #pragma unroll
        for (int j = 0; j < 4; j++)
            acc[i][j] = (float4v){0.f, 0.f, 0.f, 0.f};

    #define STG_HALF(P, RB, K0, L) do {                                           \
        __builtin_amdgcn_global_load_lds(                                         \
            (glb_u32*)(P + (size_t)((RB) + grow) * Kk + (K0) + segp * 8),         \
            (lds_u32*)((L) + w * 512), 16, 0, 0);                                 \
        __builtin_amdgcn_global_load_lds(                                         \
            (glb_u32*)(P + (size_t)((RB) + 64 + grow) * Kk + (K0) + segp * 8),    \
            (lds_u32*)((L) + 4096 + w * 512), 16, 0, 0);                          \
    } while (0)

    #define STG_TILE(buf, K0) do {                                               \
        STG_HALF(A, m0,       (K0), As2[buf]);                                   \
        STG_HALF(A, m0 + 128, (K0), As2[buf] + 8192);                            \
        STG_HALF(W, n0,       (K0), Bs2[buf]);                                   \
        STG_HALF(W, n0 + 128, (K0), Bs2[buf] + 8192);                            \
    } while (0)

    int nk = Kk >> 6;
    STG_TILE(0, 0);

    for (int kt = 0; kt < nk; kt++) {
        int cur = kt & 1;
        if (kt + 1 < nk) {
            STG_TILE(cur ^ 1, (kt + 1) << 6);
            __builtin_amdgcn_sched_barrier(0);
            asm volatile("s_waitcnt vmcnt(8)");
            __builtin_amdgcn_sched_barrier(0);
        } else {
            __builtin_amdgcn_sched_barrier(0);
            asm volatile("s_waitcnt vmcnt(0)");
            __builtin_amdgcn_sched_barrier(0);
        }
        __builtin_amdgcn_s_barrier();

        const char* asb = (const char*)As2[cur];
        const char* bsb = (const char*)Bs2[cur];
        short8v af[4], bfr[4];

        #pragma unroll
        for (int ph = 0; ph < 4; ph++) {
            int kc = ph >> 1;
            int mh = ph & 1;
            if (mh == 0) {
                #pragma unroll
                for (int nf = 0; nf < 4; nf++) {
                    int row = wc * 64 + nf * 16 + l15;
                    int off = (row * 128 + kc * 64 + l4 * 16) ^ ((row & 7) << 4);
                    bfr[nf] = *reinterpret_cast<const short8v*>(bsb + off);
                }
            }
            #pragma unroll
            for (int mf = 0; mf < 4; mf++) {
                int row = wr * 128 + (mh * 4 + mf) * 16 + l15;
                int off = (row * 128 + kc * 64 + l4 * 16) ^ ((row & 7) << 4);
                af[mf] = *reinterpret_cast<const short8v*>(asb + off);
            }
            __builtin_amdgcn_s_setprio(1);
            #pragma unroll
            for (int mf = 0; mf < 4; mf++)
                #pragma unroll
                for (int nf = 0; nf < 4; nf++)
                    acc[mh * 4 + mf][nf] = __builtin_amdgcn_mfma_f32_16x16x32_bf16(
                        af[mf], bfr[nf], acc[mh * 4 + mf][nf], 0, 0, 0);
            __builtin_amdgcn_s_setprio(0);
        }
        __builtin_amdgcn_s_barrier();
    }
    #undef STG_TILE
    #undef STG_HALF

    #pragma unroll
    for (int mf = 0; mf < 8; mf++)
        #pragma unroll
        for (int nf = 0; nf < 4; nf++)
            #pragma unroll
            for (int r = 0; r < 4; r++) {
                int m = m0 + wr * 128 + mf * 16 + l4 * 4 + r;
                int n = n0 + wc * 64 + nf * 16 + l15;
                float v = acc[mf][nf][r] + bias[n];
                v = gelu_tanh(v);
                C[(size_t)m * Nn + n] = f2bf(v);
            }
}

// ---------------------------------------------------------------------------
// Kernel 4: MFMA flash attention (R12 champion configuration, unchanged)
// ---------------------------------------------------------------------------
__global__ __launch_bounds__(512, 2)
void attn_mfma(const unsigned short* __restrict__ qkv, unsigned short* __restrict__ o)
{
    __shared__ unsigned short Kl[2][128 * 64];
    __shared__ unsigned short Vs[2][128 * 64];
    __shared__ float Scl[8][16];

    int t = threadIdx.x, w = t >> 6, lane = t & 63;
    int l15 = lane & 15, l4 = lane >> 4;

    int flat = blockIdx.x;
    int swz = (flat & 7) * 64 + (flat >> 3);
    int qt = swz & 15, hh = (swz >> 4) & 7, b = swz >> 7;

    int q0 = qt * 128 + w * 16;
    const int RS = 3 * DD; // 1536

    short8v qf[2];
    #pragma unroll
    for (int dh = 0; dh < 2; dh++) {
        size_t addr = (size_t)(b * LL + q0 + l15) * RS + hh * HDIM + dh * 32 + l4 * 8;
        qf[dh] = *reinterpret_cast<const short8v*>(qkv + addr);
    }

    float4v o_acc[4];
    #pragma unroll
    for (int dt = 0; dt < 4; dt++) o_acc[dt] = (float4v){0.f, 0.f, 0.f, 0.f};
    float l_run = 0.f;

    int lrow8 = lane >> 3;
    int ksegp = (lane & 7) ^ lrow8;
    int rho = w * 8 + lrow8;
    int kappa = ((rho >> 5) << 5) | (((rho >> 4) & 1) << 2)
              | (((rho >> 2) & 3) << 3) | (rho & 3);
    int vrow = ((t >> 5) << 2) | ((t >> 1) & 3);
    int vseg = (((t >> 3) & 3) << 1) | (t & 1);
    const unsigned short* kgl = qkv + (size_t)(b * LL + kappa) * RS
                              + hh * HDIM + DD + ksegp * 8;
    const unsigned short* vgl = qkv + (size_t)(b * LL + vrow) * RS
                              + hh * HDIM + 2 * DD + vseg * 8;
    const int halfstep = 64 * RS;
    const int step = 128 * RS;

    #define ASTAGE(buf) do {                                                      \
        __builtin_amdgcn_global_load_lds((glb_u32*)kgl,                           \
            (lds_u32*)(Kl[buf] + w * 512), 16, 0, 0);                             \
        __builtin_amdgcn_global_load_lds((glb_u32*)(kgl + halfstep),              \
            (lds_u32*)(Kl[buf] + 4096 + w * 512), 16, 0, 0);                      \
        __builtin_amdgcn_global_load_lds((glb_u32*)vgl,                           \
            (lds_u32*)(Vs[buf] + w * 512), 16, 0, 0);                             \
        __builtin_amdgcn_global_load_lds((glb_u32*)(vgl + halfstep),              \
            (lds_u32*)(Vs[buf] + 4096 + w * 512), 16, 0, 0);                      \
        kgl += step; vgl += step; } while (0)

    unsigned vtrbase = lds_addr(Vs) + ((lane >> 4) << 10)
                     + (((lane >> 2) & 3) << 5) + ((lane & 3) << 3);

    ASTAGE(0);
    asm volatile("s_waitcnt vmcnt(0)");
    __syncthreads();

    for (int kb = 0; kb < LL / 128; kb++) {
        int cur = kb & 1;
        if (kb + 1 < LL / 128) ASTAGE(cur ^ 1);

        #pragma unroll
        for (int hf = 0; hf < 2; hf++) {
            const char* klc = (const char*)Kl[cur] + hf * 8192;
            unsigned vb = vtrbase + cur * 16384 + hf * 8192;

            float4v s_acc[4];
            __builtin_amdgcn_s_setprio(1);
            #pragma unroll
            for (int nt = 0; nt < 4; nt++) {
                s_acc[nt] = (float4v){0.f, 0.f, 0.f, 0.f};
                #pragma unroll
                for (int dh = 0; dh < 2; dh++) {
                    int row = nt * 16 + l15;
                    int off = (row * 128 + dh * 64 + l4 * 16) ^ ((row & 7) << 4);
                    short8v kf = *reinterpret_cast<const short8v*>(klc + off);
                    s_acc[nt] = __builtin_amdgcn_mfma_f32_16x16x32_bf16(kf, qf[dh], s_acc[nt], 0, 0, 0);
                }
            }
            __builtin_amdgcn_s_setprio(0);

            unsigned long long a0, a1, a2, a3, a4, a5, a6, a7;
            unsigned long long b0, b1, b2, b3, b4, b5, b6, b7;
            unsigned ab0 = vb, ab1 = vb + 4096;
            asm volatile("ds_read_b64_tr_b16 %0, %1" : "=v"(a0) : "v"(ab0));
            asm volatile("ds_read_b64_tr_b16 %0, %1" : "=v"(a1) : "v"(ab0 + 512));
            asm volatile("ds_read_b64_tr_b16 %0, %1" : "=v"(a2) : "v"(ab0 + 128));
            asm volatile("ds_read_b64_tr_b16 %0, %1" : "=v"(a3) : "v"(ab0 + 640));
            asm volatile("ds_read_b64_tr_b16 %0, %1" : "=v"(a4) : "v"(ab0 + 256));
            asm volatile("ds_read_b64_tr_b16 %0, %1" : "=v"(a5) : "v"(ab0 + 768));
            asm volatile("ds_read_b64_tr_b16 %0, %1" : "=v"(a6) : "v"(ab0 + 384));
            asm volatile("ds_read_b64_tr_b16 %0, %1" : "=v"(a7) : "v"(ab0 + 896));
            asm volatile("ds_read_b64_tr_b16 %0, %1" : "=v"(b0) : "v"(ab1));
            asm volatile("ds_read_b64_tr_b16 %0, %1" : "=v"(b1) : "v"(ab1 + 512));
            asm volatile("ds_read_b64_tr_b16 %0, %1" : "=v"(b2) : "v"(ab1 + 128));
            asm volatile("ds_read_b64_tr_b16 %0, %1" : "=v"(b3) : "v"(ab1 + 640));
            asm volatile("ds_read_b64_tr_b16 %0, %1" : "=v"(b4) : "v"(ab1 + 256));
            asm volatile("ds_read_b64_tr_b16 %0, %1" : "=v"(b5) : "v"(ab1 + 768));
            asm volatile("ds_read_b64_tr_b16 %0, %1" : "=v"(b6) : "v"(ab1 + 384));
            asm volatile("ds_read_b64_tr_b16 %0, %1" : "=v"(b7) : "v"(ab1 + 896));

            union { unsigned u[4]; short8v v; } pf0u, pf1u;
            float ps;
            {
                float p0 = __builtin_amdgcn_exp2f(s_acc[0][0]);
                float p1 = __builtin_amdgcn_exp2f(s_acc[0][1]);
                float p2 = __builtin_amdgcn_exp2f(s_acc[0][2]);
                float p3 = __builtin_amdgcn_exp2f(s_acc[0][3]);
                float p4 = __builtin_amdgcn_exp2f(s_acc[1][0]);
                float p5 = __builtin_amdgcn_exp2f(s_acc[1][1]);
                float p6 = __builtin_amdgcn_exp2f(s_acc[1][2]);
                float p7 = __builtin_amdgcn_exp2f(s_acc[1][3]);
                asm("v_cvt_pk_bf16_f32 %0, %1, %2" : "=v"(pf0u.u[0]) : "v"(p0), "v"(p1));
                asm("v_cvt_pk_bf16_f32 %0, %1, %2" : "=v"(pf0u.u[1]) : "v"(p2), "v"(p3));
                asm("v_cvt_pk_bf16_f32 %0, %1, %2" : "=v"(pf0u.u[2]) : "v"(p4), "v"(p5));
                asm("v_cvt_pk_bf16_f32 %0, %1, %2" : "=v"(pf0u.u[3]) : "v"(p6), "v"(p7));
                ps = ((p0 + p1) + (p2 + p3)) + ((p4 + p5) + (p6 + p7));
            }
            {
                float p0 = __builtin_amdgcn_exp2f(s_acc[2][0]);
                float p1 = __builtin_amdgcn_exp2f(s_acc[2][1]);
                float p2 = __builtin_amdgcn_exp2f(s_acc[2][2]);
                float p3 = __builtin_amdgcn_exp2f(s_acc[2][3]);
                float p4 = __builtin_amdgcn_exp2f(s_acc[3][0]);
                float p5 = __builtin_amdgcn_exp2f(s_acc[3][1]);
                float p6 = __builtin_amdgcn_exp2f(s_acc[3][2]);
                float p7 = __builtin_amdgcn_exp2f(s_acc[3][3]);
                asm("v_cvt_pk_bf16_f32 %0, %1, %2" : "=v"(pf1u.u[0]) : "v"(p0), "v"(p1));
                asm("v_cvt_pk_bf16_f32 %0, %1, %2" : "=v"(pf1u.u[1]) : "v"(p2), "v"(p3));
                asm("v_cvt_pk_bf16_f32 %0, %1, %2" : "=v"(pf1u.u[2]) : "v"(p4), "v"(p5));
                asm("v_cvt_pk_bf16_f32 %0, %1, %2" : "=v"(pf1u.u[3]) : "v"(p6), "v"(p7));
                ps += ((p0 + p1) + (p2 + p3)) + ((p4 + p5) + (p6 + p7));
            }
            l_run += ps;

            union { unsigned long long q[2]; short8v v; } u0, u1, u2, u3;
            asm volatile("s_waitcnt lgkmcnt(8)");
            __builtin_amdgcn_sched_barrier(0);
            __builtin_amdgcn_s_setprio(1);
            u0.q[0] = a0; u0.q[1] = a1;
            u1.q[0] = a2; u1.q[1] = a3;
            o_acc[0] = __builtin_amdgcn_mfma_f32_16x16x32_bf16(pf0u.v, u0.v, o_acc[0], 0, 0, 0);
            o_acc[1] = __builtin_amdgcn_mfma_f32_16x16x32_bf16(pf0u.v, u1.v, o_acc[1], 0, 0, 0);
            asm volatile("s_waitcnt lgkmcnt(4)");
            __builtin_amdgcn_sched_barrier(0);
            u2.q[0] = a4; u2.q[1] = a5;
            u3.q[0] = a6; u3.q[1] = a7;
            o_acc[2] = __builtin_amdgcn_mfma_f32_16x16x32_bf16(pf0u.v, u2.v, o_acc[2], 0, 0, 0);
            o_acc[3] = __builtin_amdgcn_mfma_f32_16x16x32_bf16(pf0u.v, u3.v, o_acc[3], 0, 0, 0);
            asm volatile("s_waitcnt lgkmcnt(0)");
            __builtin_amdgcn_sched_barrier(0);
            u0.q[0] = b0; u0.q[1] = b1;
            u1.q[0] = b2; u1.q[1] = b3;
            u2.q[0] = b4; u2.q[1] = b5;
            u3.q[0] = b6; u3.q[1] = b7;
            o_acc[0] = __builtin_amdgcn_mfma_f32_16x16x32_bf16(pf1u.v, u0.v, o_acc[0], 0, 0, 0);
            o_acc[1] = __builtin_amdgcn_mfma_f32_16x16x32_bf16(pf1u.v, u1.v, o_acc[1], 0, 0, 0);
            o_acc[2] = __builtin_amdgcn_mfma_f32_16x16x32_bf16(pf1u.v, u2.v, o_acc[2], 0, 0, 0);
            o_acc[3] = __builtin_amdgcn_mfma_f32_16x16x32_bf16(pf1u.v, u3.v, o_acc[3], 0, 0, 0);
            __builtin_amdgcn_s_setprio(0);
        }

        asm volatile("s_waitcnt vmcnt(0)");
        __syncthreads();
    }
    #undef ASTAGE

    float lt = l_run;
    lt += __shfl_xor(lt, 16);
    lt += __shfl_xor(lt, 32);
    if (l4 == 0) Scl[w][l15] = 1.f / lt;
    float4 iv = *reinterpret_cast<const float4*>(&Scl[w][l4 * 4]);
    float invs[4] = {iv.x, iv.y, iv.z, iv.w};
    #pragma unroll
    for (int r = 0; r < 4; r++) {
        int qg = q0 + l4 * 4 + r;
        #pragma unroll
        for (int dt = 0; dt < 4; dt++) {
            o[(size_t)(b * LL + qg) * DD + hh * HDIM + dt * 16 + l15] =
                f2bf(o_acc[dt][r] * invs[r]);
        }
    }
}

// ---------------------------------------------------------------------------
// Driver
// ---------------------------------------------------------------------------
extern "C" void kernel_launch(void* const* d_in, const int* in_sizes, int n_in,
                              void* d_out, int out_size, void* d_ws, size_t ws_size,
                              hipStream_t stream)
{
    const float* emb    = (const float*)d_in[0];
    const float* ent_w  = (const float*)d_in[1];
    const float* ent_b  = (const float*)d_in[2];
    const float* qkv_w  = (const float*)d_in[3];
    const float* qkv_b  = (const float*)d_in[4];
    const float* ao_w   = (const float*)d_in[5];
    const float* ao_b   = (const float*)d_in[6];
    const float* ln1_s  = (const float*)d_in[7];
    const float* ln1_b  = (const float*)d_in[8];
    const float* ln2_s  = (const float*)d_in[9];
    const float* ln2_b  = (const float*)d_in[10];
    const float* ff1_w  = (const float*)d_in[11];
    const float* ff1_b  = (const float*)d_in[12];
    const float* ff2_w  = (const float*)d_in[13];
    const float* ff2_b  = (const float*)d_in[14];
    const float* out_w  = (const float*)d_in[15];
    const int*   x      = (const int*)d_in[16];
    // d_in[17] = patch_lengths : dead code in the reference

    float* out = (float*)d_out;

    const int NQW = NLAYER * 3 * DD * DD;
    const int NAW = NLAYER * DD * DD;
    const int NF1 = NLAYER * 4 * DD * DD;
    const int NF2 = NLAYER * DD * 4 * DD;

    char* p = (char*)d_ws;
    unsigned short* wq  = (unsigned short*)p; p += (size_t)NQW * 2;
    unsigned short* wa  = (unsigned short*)p; p += (size_t)NAW * 2;
    unsigned short* w1  = (unsigned short*)p; p += (size_t)NF1 * 2;
    unsigned short* w2  = (unsigned short*)p; p += (size_t)NF2 * 2;
    unsigned short* wob = (unsigned short*)p; p += (size_t)VPAD * DD * 2;
    unsigned short* h   = (unsigned short*)p; p += (size_t)MM * DD * 2;   // bf16 residual
    unsigned short* gb  = (unsigned short*)p; p += (size_t)MM * DD * 2;
    unsigned short* ob  = (unsigned short*)p; p += (size_t)MM * DD * 2;
    unsigned short* bb  = (unsigned short*)p; p += (size_t)MM * 4 * DD * 2; // qkv / ffn

    dim3 blk(256);

    cvt_all_kernel<<<E4 / 1024, blk, 0, stream>>>(qkv_w, ao_w, ff1_w, ff2_w, out_w, wq);

    embed_ln_kernel<<<MM / 4, blk, 0, stream>>>(x, emb, ent_w, ent_b,
                                                ln1_s, ln1_b, h, gb);

    for (int layer = 0; layer < NLAYER; layer++) {
        const unsigned short* qw = wq + (size_t)layer * 3 * DD * DD;
        const unsigned short* aw = wa + (size_t)layer * DD * DD;
        const unsigned short* f1 = w1 + (size_t)layer * 4 * DD * DD;
        const unsigned short* f2 = w2 + (size_t)layer * DD * 4 * DD;
        const float* qb  = qkv_b + (size_t)layer * 3 * DD;
        const float* ab  = ao_b  + (size_t)layer * DD;
        const float* l1s = ln1_s + (size_t)layer * DD;
        const float* l1b = ln1_b + (size_t)layer * DD;
        const float* l2s = ln2_s + (size_t)layer * DD;
        const float* l2b = ln2_b + (size_t)layer * DD;
        const float* f1b = ff1_b + (size_t)layer * 4 * DD;
        const float* f2b = ff2_b + (size_t)layer * DD;

        // LN1 (layer 0 fused into embed_ln_kernel)
        if (layer > 0)
            ln_kernel<<<MM / 4, blk, 0, stream>>>(h, l1s, l1b, gb);

        // qkv = gb @ qw^T + qb -> bb (bf16) [MM,1536], Q cols pre-scaled by C8
        {
            dim3 grid((3 * DD) / 128, MM / 128);
            gemm_mfma<true, false, false, true, 1><<<grid, 256, 0, stream>>>(
                gb, qw, qb, nullptr, bb, 3 * DD, DD);
        }

        // attention: bb -> ob (bf16)
        attn_mfma<<<512, 512, 0, stream>>>(bb, ob);

        // h = h + ob @ aw^T + ab  (bf16 out; MT=64 3-buffer deep pipe)
        {
            dim3 grid(DD / 128, MM / 64);
            gemm_mfma64_d3<true, false, true, 1><<<grid, 128, 0, stream>>>(
                ob, aw, ab, h, h, DD, DD);
        }

        // LN2: h -> gb
        ln_kernel<<<MM / 4, blk, 0, stream>>>(h, l2s, l2b, gb);

        // ffn1: bb = gelu(gb @ f1^T + f1b) (bf16) [MM,2048] -- deep-pipelined 256^2
        gemm_mfma_256<<<(MM / 256) * ((4 * DD) / 256), 512, 0, stream>>>(
            gb, f1, f1b, bb, 4 * DD, DD);

        // ffn2: h = h + bb @ f2^T + f2b  (bf16 out; MT=64 3-buffer deep pipe)
        {
            dim3 grid(DD / 128, MM / 64);
            gemm_mfma64_d3<true, false, true, 1><<<grid, 128, 0, stream>>>(
                bb, f2, f2b, h, h, DD, 4 * DD);
        }
    }

    // logits = h @ wob^T [MM, 258] via MFMA on padded weight (MT=64 3-buffer)
    {
        dim3 grid(VPAD / 128, MM / 64);
        gemm_mfma64_d3<false, false, false, 0><<<grid, 128, 0, stream>>>(
            h, wob, nullptr, nullptr, out, VV, DD);
    }
}